// Round 1
// baseline (5484.829 us; speedup 1.0000x reference)
//
#include <hip/hip_runtime.h>
#include <hip/hip_bf16.h>
#include <cmath>

// ---------------------------------------------------------------------------
// Problem constants (fixed shapes)
// ---------------------------------------------------------------------------
constexpr int cNE = 100000, cNT = 1024, cNC = 128, cD = 128, cNR = 500;
constexpr int cB = 512, cDEG = 8, cNSRC = 4096, cT = 1024, cE = 4;
constexpr int cNNZ_E2T = 1000000, cNNZ_T2C = 50000, cNNZ_E2C = 500000;
constexpr float cDECAY = 1e-4f, cCLW = 0.1f;
// 1/tau = 2.0

// Workspace layout (offsets in floats)
constexpr size_t F_S1   = 0;                                  // 4096x128
constexpr size_t F_S2   = F_S1 + (size_t)cNSRC * cD;
constexpr size_t F_PT   = F_S2 + (size_t)cNSRC * cD;          // proj tmp
constexpr size_t F_Z1   = F_PT + (size_t)cNSRC * cD;
constexpr size_t F_Z2   = F_Z1 + (size_t)cNSRC * cD;
constexpr size_t F_MSG  = F_Z2 + (size_t)cNSRC * cD;          // 4096x256
constexpr size_t F_GATE = F_MSG + (size_t)cNSRC * 2 * cD;     // 4096x4
constexpr size_t F_SCAL = F_GATE + (size_t)cNSRC * cE;        // [0]=cl_sum [1]=emb_sum
constexpr size_t F_U    = F_SCAL + 64;
constexpr size_t BIGB   = (size_t)cNSRC * cT;                 // 4194304
constexpr size_t F_P    = F_U;
constexpr size_t F_Q    = F_U + BIGB;
constexpr size_t F_K    = F_U + 2 * BIGB;
constexpr size_t F_V    = F_U + 3 * BIGB;
// GCN aliases inside the same union region (dead once S1/S2 are built)
constexpr size_t F_X1F  = F_U;                                 // 101024*128
constexpr size_t F_X2C  = F_U + (size_t)101024 * 128;          // 4096*128
constexpr size_t F_SLOT = F_X2C + (size_t)cNSRC * cD;          // 101024 ints
constexpr size_t F_X1T  = F_SLOT + 101024;                     // 1152*128
constexpr size_t F_X2T  = F_X1T + (size_t)1152 * 128;
constexpr size_t F_END  = F_U + 4 * BIGB;

// ---------------------------------------------------------------------------
// Helpers
// ---------------------------------------------------------------------------
__device__ __forceinline__ void atomAdd(float* p, float v) {
  __hip_atomic_fetch_add(p, v, __ATOMIC_RELAXED, __HIP_MEMORY_SCOPE_AGENT);
}

// node mapping for each (gcn, node1/node2) combination; -1 = not this gcn
__device__ __forceinline__ int mapNode(int mode, int id) {
  switch (mode) {
    case 0:  return (id < cNE + cNT) ? id : -1;                        // e2t -> node1
    case 1:  return (id >= cNE + cNT) ? (id - cNE) : -1;               // t2c -> node1 (cluster)
    case 2:  return (id >= cNE && id < cNE + cNT) ? (id - cNE) : -1;   // t2c -> node2 (type)
    default: return (id < cNE) ? id
                   : ((id >= cNE + cNT) ? (id - cNT) : -1);            // e2c -> node2
  }
}

__device__ __forceinline__ float blockReduce128(float v, float* sh, int tid) {
  sh[tid] = v; __syncthreads();
  if (tid < 64) sh[tid] += sh[tid + 64]; __syncthreads();
  if (tid < 32) sh[tid] += sh[tid + 32]; __syncthreads();
  if (tid < 16) sh[tid] += sh[tid + 16]; __syncthreads();
  if (tid < 8)  sh[tid] += sh[tid + 8];  __syncthreads();
  if (tid < 4)  sh[tid] += sh[tid + 4];  __syncthreads();
  if (tid < 2)  sh[tid] += sh[tid + 2];  __syncthreads();
  if (tid < 1)  sh[tid] += sh[tid + 1];  __syncthreads();
  float r = sh[0]; __syncthreads();
  return r;
}

__device__ __forceinline__ float blockReduce256(float v, float* sh, int tid) {
  sh[tid] = v; __syncthreads();
  for (int s = 128; s > 0; s >>= 1) {
    if (tid < s) sh[tid] += sh[tid + s];
    __syncthreads();
  }
  float r = sh[0]; __syncthreads();
  return r;
}

// ---------------------------------------------------------------------------
// GCN kernels
// ---------------------------------------------------------------------------
// layer-1 scatter: out[row] += val * x0[col]; x0 = virtual concat(ea[na], eb)
__global__ __launch_bounds__(256) void spmv_scatter(
    const int* __restrict__ row, const int* __restrict__ col, const float* __restrict__ val,
    int nnz, const float* __restrict__ ea, const float* __restrict__ eb, int na,
    float* __restrict__ out)
{
  long long gid = (long long)blockIdx.x * blockDim.x + threadIdx.x;
  int e = (int)(gid >> 5);
  if (e >= nnz) return;
  int d4 = ((int)gid & 31) * 4;
  int c = col[e]; int r = row[e]; float v = val[e];
  const float* src = (c < na) ? (ea + (size_t)c * cD) : (eb + (size_t)(c - na) * cD);
  float4 x = *reinterpret_cast<const float4*>(src + d4);
  float* dst = out + (size_t)r * cD + d4;
  atomAdd(dst + 0, v * x.x);
  atomAdd(dst + 1, v * x.y);
  atomAdd(dst + 2, v * x.z);
  atomAdd(dst + 3, v * x.w);
}

// layer-2 scatter restricted to gathered rows: outc[slot[row]] += val * x1[col]
__global__ __launch_bounds__(256) void spmv_scatter_slot(
    const int* __restrict__ row, const int* __restrict__ col, const float* __restrict__ val,
    int nnz, const float* __restrict__ x1, const int* __restrict__ slot,
    float* __restrict__ outc)
{
  long long gid = (long long)blockIdx.x * blockDim.x + threadIdx.x;
  int e = (int)(gid >> 5);
  if (e >= nnz) return;
  int r = row[e];
  int s = slot[r];
  if (s >= cNSRC) return;           // 0x7f7f7f7f sentinel
  int d4 = ((int)gid & 31) * 4;
  int c = col[e]; float v = val[e];
  float4 x = *reinterpret_cast<const float4*>(x1 + (size_t)c * cD + d4);
  float* dst = outc + (size_t)s * cD + d4;
  atomAdd(dst + 0, v * x.x);
  atomAdd(dst + 1, v * x.y);
  atomAdd(dst + 2, v * x.z);
  atomAdd(dst + 3, v * x.w);
}

__global__ __launch_bounds__(256) void slot_build(
    const int* __restrict__ ids, int* __restrict__ slot, int mode)
{
  int i = blockIdx.x * blockDim.x + threadIdx.x;
  if (i >= cNSRC) return;
  int node = mapNode(mode, ids[i]);
  if (node >= 0) atomicMin(&slot[node], i);
}

// acc = (x0 + x1 + x2)/3 at gathered rows, then LayerNorm, write to dst[i]
__global__ __launch_bounds__(128) void gather_ln(
    const int* __restrict__ ids, int mode,
    const float* __restrict__ ea, const float* __restrict__ eb, int na,
    const float* __restrict__ x1, const float* __restrict__ x2, const int* __restrict__ slot,
    const float* __restrict__ g, const float* __restrict__ bia, float* __restrict__ dst)
{
  __shared__ float sh[128];
  int i = blockIdx.x;
  int tid = threadIdx.x;
  int id = ids[i];
  int node = mapNode(mode, id);
  if (node < 0) return;   // uniform across block
  const float* x0 = (node < na) ? (ea + (size_t)node * cD) : (eb + (size_t)(node - na) * cD);
  int xi2 = slot ? slot[node] : node;
  float a = (x0[tid] + x1[(size_t)node * cD + tid] + x2[(size_t)xi2 * cD + tid]) * (1.0f / 3.0f);
  float s  = blockReduce128(a, sh, tid);
  float ss = blockReduce128(a * a, sh, tid);
  float mu = s * (1.0f / 128.0f);
  float var = ss * (1.0f / 128.0f) - mu * mu;
  float y = (a - mu) * rsqrtf(var + 1e-5f) * g[tid] + bia[tid];
  dst[(size_t)i * cD + tid] = y;
}

// ---------------------------------------------------------------------------
// Generic fp32 GEMM: C[M,N] = A[M,K] @ B[K,N] (+bias) (+epilogue)
// epi: 0 = store; 1 = store with ELU; 2 = C += rowscale[r*rs_stride]*(acc+bias)
// ---------------------------------------------------------------------------
__global__ __launch_bounds__(256) void gemm64(
    const float* __restrict__ A, const float* __restrict__ B, float* __restrict__ C,
    int M, int N, int K, const float* __restrict__ bias,
    const float* __restrict__ rowscale, int rs_stride, int epi)
{
  __shared__ __align__(16) float As[16][68];
  __shared__ __align__(16) float Bs[16][68];
  const int bx = blockIdx.x;
  const int by = blockIdx.y;
  const int tx = threadIdx.x & 15;
  const int ty = threadIdx.x >> 4;
  const int la_r = threadIdx.x >> 2;        // 0..63
  const int la_k = (threadIdx.x & 3) * 4;   // 0,4,8,12
  const int lb_k = threadIdx.x >> 4;        // 0..15
  const int lb_c = (threadIdx.x & 15) * 4;  // 0..60
  float acc[4][4] = {};
  for (int kt = 0; kt < K; kt += 16) {
    __syncthreads();
    float4 av = *reinterpret_cast<const float4*>(A + (size_t)(by * 64 + la_r) * K + kt + la_k);
    As[la_k + 0][la_r] = av.x;
    As[la_k + 1][la_r] = av.y;
    As[la_k + 2][la_r] = av.z;
    As[la_k + 3][la_r] = av.w;
    *reinterpret_cast<float4*>(&Bs[lb_k][lb_c]) =
        *reinterpret_cast<const float4*>(B + (size_t)(kt + lb_k) * N + bx * 64 + lb_c);
    __syncthreads();
#pragma unroll
    for (int kk = 0; kk < 16; ++kk) {
      float4 a = *reinterpret_cast<const float4*>(&As[kk][ty * 4]);
      float4 b = *reinterpret_cast<const float4*>(&Bs[kk][tx * 4]);
      acc[0][0] += a.x * b.x; acc[0][1] += a.x * b.y; acc[0][2] += a.x * b.z; acc[0][3] += a.x * b.w;
      acc[1][0] += a.y * b.x; acc[1][1] += a.y * b.y; acc[1][2] += a.y * b.z; acc[1][3] += a.y * b.w;
      acc[2][0] += a.z * b.x; acc[2][1] += a.z * b.y; acc[2][2] += a.z * b.z; acc[2][3] += a.z * b.w;
      acc[3][0] += a.w * b.x; acc[3][1] += a.w * b.y; acc[3][2] += a.w * b.z; acc[3][3] += a.w * b.w;
    }
  }
  const int row0 = by * 64 + ty * 4;
  const int col0 = bx * 64 + tx * 4;
#pragma unroll
  for (int i = 0; i < 4; ++i) {
#pragma unroll
    for (int j = 0; j < 4; ++j) {
      int r = row0 + i, c = col0 + j;
      float v = acc[i][j] + (bias ? bias[c] : 0.0f);
      if (epi == 1) v = (v > 0.0f) ? v : expm1f(v);
      size_t idx = (size_t)r * N + c;
      if (epi == 2) C[idx] += rowscale[(size_t)r * rs_stride] * v;
      else C[idx] = v;
    }
  }
}

// ---------------------------------------------------------------------------
// Contrastive-loss kernels
// ---------------------------------------------------------------------------
__global__ __launch_bounds__(128) void rownorm(float* __restrict__ z) {
  __shared__ float sh[128];
  int i = blockIdx.x, tid = threadIdx.x;
  float v = z[(size_t)i * cD + tid];
  float ss = blockReduce128(v * v, sh, tid);
  float n = sqrtf(ss);
  z[(size_t)i * cD + tid] = v / fmaxf(n, 1e-12f);
}

// per-row i: r11,r12,r21,r22 sums + diag terms -> per-row loss -> atomicAdd
__global__ __launch_bounds__(256) void cl_sums(
    const float* __restrict__ z1, const float* __restrict__ z2, float* __restrict__ cl_sum)
{
  __shared__ float z1i[16][128], z2i[16][128];
  __shared__ float z1j[32][128], z2j[32][128];
  __shared__ float red[4][16][16];
  __shared__ float dd[3][16];
  const int i0 = blockIdx.x * 16;
  const int tx = threadIdx.x;
  for (int idx = tx; idx < 16 * 128; idx += 256) {
    int r = idx >> 7, c = idx & 127;
    z1i[r][c] = z1[(size_t)(i0 + r) * cD + c];
    z2i[r][c] = z2[(size_t)(i0 + r) * cD + c];
  }
  const int ti = tx & 15, tj = tx >> 4;
  float r11 = 0, r12 = 0, r21 = 0, r22 = 0;
  float d12 = 0, diag11 = 0, diag22 = 0;
  for (int j0 = 0; j0 < cNSRC; j0 += 32) {
    __syncthreads();
    for (int idx = tx; idx < 32 * 128; idx += 256) {
      int r = idx >> 7, c = idx & 127;
      z1j[r][c] = z1[(size_t)(j0 + r) * cD + c];
      z2j[r][c] = z2[(size_t)(j0 + r) * cD + c];
    }
    __syncthreads();
    float a11[2] = {0, 0}, a12[2] = {0, 0}, a21[2] = {0, 0}, a22[2] = {0, 0};
#pragma unroll 8
    for (int kk = 0; kk < 128; ++kk) {
      float x1 = z1i[ti][kk], x2 = z2i[ti][kk];
#pragma unroll
      for (int rr = 0; rr < 2; ++rr) {
        float y1 = z1j[tj + 16 * rr][kk], y2 = z2j[tj + 16 * rr][kk];
        a11[rr] += x1 * y1; a12[rr] += x1 * y2;
        a21[rr] += x2 * y1; a22[rr] += x2 * y2;
      }
    }
#pragma unroll
    for (int rr = 0; rr < 2; ++rr) {
      float e11 = expf(2.0f * a11[rr]), e12 = expf(2.0f * a12[rr]);
      float e21 = expf(2.0f * a21[rr]), e22 = expf(2.0f * a22[rr]);
      r11 += e11; r12 += e12; r21 += e21; r22 += e22;
      if (j0 + tj + 16 * rr == i0 + ti) { d12 = e12; diag11 = e11; diag22 = e22; }
    }
  }
  red[0][ti][tj] = r11; red[1][ti][tj] = r12; red[2][ti][tj] = r21; red[3][ti][tj] = r22;
  if (d12 != 0.0f) { dd[0][ti] = d12; dd[1][ti] = diag11; dd[2][ti] = diag22; }
  __syncthreads();
  if (tj == 0) {
    float R11 = 0, R12 = 0, R21 = 0, R22 = 0;
    for (int t = 0; t < 16; ++t) {
      R11 += red[0][ti][t]; R12 += red[1][ti][t];
      R21 += red[2][ti][t]; R22 += red[3][ti][t];
    }
    float denA = R11 + R12 - dd[1][ti];
    float denB = R22 + R21 - dd[2][ti];
    float l = 0.5f * (logf(denA) + logf(denB)) - logf(dd[0][ti]);
    atomAdd(cl_sum, l);
  }
}

// ---------------------------------------------------------------------------
// message / losses / MHA / MoE
// ---------------------------------------------------------------------------
__global__ __launch_bounds__(256) void emb_sum_k(
    const float* __restrict__ s1, const float* __restrict__ s2,
    const float* __restrict__ relation, const int* __restrict__ etype, float* __restrict__ out)
{
  __shared__ float sh[256];
  int idx = blockIdx.x * 256 + threadIdx.x;  // exactly 4096*256
  int i = idx >> 8, j = idx & 255;
  float a = (j < 128) ? s1[(size_t)i * 128 + j] : s2[(size_t)i * 128 + j - 128];
  int et = etype[i];
  float r = relation[(size_t)(et % cNR) * 256 + j];
  float t = blockReduce256(a * a + r * r, sh, threadIdx.x);
  if (threadIdx.x == 0) atomAdd(out, t);
}

__global__ __launch_bounds__(256) void msg_build(
    const float* __restrict__ s1, const float* __restrict__ s2,
    const float* __restrict__ relation, const int* __restrict__ etype, float* __restrict__ msg)
{
  int idx = blockIdx.x * 256 + threadIdx.x;
  int i = idx >> 8, j = idx & 255;
  int et = etype[i];
  float sign = (et >= cNR) ? -1.0f : 1.0f;
  float r = relation[(size_t)(et % cNR) * 256 + j] * sign;
  float s = (j < 128) ? s1[(size_t)i * 128 + j] : s2[(size_t)i * 128 + j - 128];
  msg[idx] = fmaxf(s + r, 0.0f);
}

__global__ __launch_bounds__(64) void mha_attn(
    const float* __restrict__ q, const float* __restrict__ k,
    const float* __restrict__ v, float* __restrict__ o)
{
  __shared__ float qs[8][128], ks[8][128], vs[8][128], att[8][8];
  int bh = blockIdx.x;
  int b = bh >> 3, h = bh & 7;
  int tid = threadIdx.x;
  for (int idx = tid; idx < 1024; idx += 64) {
    int l = idx >> 7, d = idx & 127;
    size_t src = (size_t)(b * 8 + l) * cT + h * 128 + d;
    qs[l][d] = q[src]; ks[l][d] = k[src]; vs[l][d] = v[src];
  }
  __syncthreads();
  int l = tid >> 3, m = tid & 7;
  float s = 0;
#pragma unroll 16
  for (int d = 0; d < 128; ++d) s += qs[l][d] * ks[m][d];
  s *= 0.08838834764831845f;  // 1/sqrt(128)
  float mx = s;
  for (int off = 1; off < 8; off <<= 1) mx = fmaxf(mx, __shfl_xor(mx, off, 8));
  float p = expf(s - mx);
  float sum = p;
  for (int off = 1; off < 8; off <<= 1) sum += __shfl_xor(sum, off, 8);
  att[l][m] = p / sum;
  __syncthreads();
  for (int idx = tid; idx < 1024; idx += 64) {
    int ll = idx >> 7, d = idx & 127;
    float acc = 0;
#pragma unroll
    for (int mm = 0; mm < 8; ++mm) acc += att[ll][mm] * vs[mm][d];
    o[(size_t)(b * 8 + ll) * cT + h * 128 + d] = acc;
  }
}

__global__ __launch_bounds__(64) void gate_k(
    const float* __restrict__ o, const float* __restrict__ gw, float* __restrict__ gate)
{
  int i = blockIdx.x;
  int lane = threadIdx.x;
  float g[4] = {0, 0, 0, 0};
  for (int d = lane; d < cT; d += 64) {
    float ov = o[(size_t)i * cT + d];
    g[0] += ov * gw[d * 4 + 0];
    g[1] += ov * gw[d * 4 + 1];
    g[2] += ov * gw[d * 4 + 2];
    g[3] += ov * gw[d * 4 + 3];
  }
#pragma unroll
  for (int off = 32; off > 0; off >>= 1) {
#pragma unroll
    for (int e = 0; e < 4; ++e) g[e] += __shfl_down(g[e], off);
  }
  if (lane == 0) {
    float mx = fmaxf(fmaxf(g[0], g[1]), fmaxf(g[2], g[3]));
    float ex[4], sum = 0;
#pragma unroll
    for (int e = 0; e < 4; ++e) { ex[e] = expf(g[e] - mx); sum += ex[e]; }
#pragma unroll
    for (int e = 0; e < 4; ++e) gate[(size_t)i * 4 + e] = ex[e] / sum;
  }
}

__global__ __launch_bounds__(256) void mean_sigmoid(
    const float* __restrict__ moe, float* __restrict__ out)
{
  int idx = blockIdx.x * 256 + threadIdx.x;  // exactly 512*1024
  int b = idx >> 10, t = idx & 1023;
  float s = 0;
#pragma unroll
  for (int l = 0; l < 8; ++l) s += moe[(size_t)(b * 8 + l) * cT + t];
  s *= (1.0f / 8.0f);
  out[idx] = 1.0f / (1.0f + expf(-s));
}

__global__ void finalize_k(const float* __restrict__ scal, float* __restrict__ out_aux) {
  float cl = scal[0] * (1.0f / cNSRC);
  float emb = cDECAY * 0.5f * scal[1] * (1.0f / cNSRC);
  out_aux[0] = cCLW * cl + emb;
}

// ---------------------------------------------------------------------------
// Launch
// ---------------------------------------------------------------------------
extern "C" void kernel_launch(void* const* d_in, const int* in_sizes, int n_in,
                              void* d_out, int out_size, void* d_ws, size_t ws_size,
                              hipStream_t stream) {
  (void)in_sizes; (void)n_in; (void)out_size; (void)ws_size;
  const float* entity   = (const float*)d_in[0];
  const float* type_e   = (const float*)d_in[1];
  const float* cluster  = (const float*)d_in[2];
  const float* relation = (const float*)d_in[3];
  const float* ln_g  = (const float*)d_in[4];
  const float* ln_b  = (const float*)d_in[5];
  const float* cl_w1 = (const float*)d_in[6];
  const float* cl_b1 = (const float*)d_in[7];
  const float* cl_w2 = (const float*)d_in[8];
  const float* cl_b2 = (const float*)d_in[9];
  const float* fc_w  = (const float*)d_in[10];
  const float* fc_b  = (const float*)d_in[11];
  const float* wq = (const float*)d_in[12];
  const float* bq = (const float*)d_in[13];
  const float* wk = (const float*)d_in[14];
  const float* bk = (const float*)d_in[15];
  const float* wv = (const float*)d_in[16];
  const float* bv = (const float*)d_in[17];
  const float* wo = (const float*)d_in[18];
  const float* bo = (const float*)d_in[19];
  const float* gate_w = (const float*)d_in[20];
  const float* exp_w  = (const float*)d_in[21];
  const float* exp_b  = (const float*)d_in[22];
  const float* e2t_val = (const float*)d_in[23];
  const float* t2c_val = (const float*)d_in[24];
  const float* e2c_val = (const float*)d_in[25];
  const int* e2t_row = (const int*)d_in[26];
  const int* e2t_col = (const int*)d_in[27];
  const int* t2c_row = (const int*)d_in[28];
  const int* t2c_col = (const int*)d_in[29];
  const int* e2c_row = (const int*)d_in[30];
  const int* e2c_col = (const int*)d_in[31];
  const int* src_ids = (const int*)d_in[32];
  const int* etype   = (const int*)d_in[33];

  float* ws = (float*)d_ws;
  float* S1 = ws + F_S1;
  float* S2 = ws + F_S2;
  float* PT = ws + F_PT;
  float* Z1 = ws + F_Z1;
  float* Z2 = ws + F_Z2;
  float* MSG = ws + F_MSG;
  float* GATE = ws + F_GATE;
  float* SCAL = ws + F_SCAL;
  float* Pb = ws + F_P;
  float* Qb = ws + F_Q;
  float* Kb = ws + F_K;
  float* Vb = ws + F_V;
  float* X1F = ws + F_X1F;
  float* X2C = ws + F_X2C;
  int*   SLOT = (int*)(ws + F_SLOT);
  float* X1T = ws + F_X1T;
  float* X2T = ws + F_X2T;

  hipMemsetAsync(SCAL, 0, 2 * sizeof(float), stream);

  // ---- GCN e2t -> src1 for ids < NE+NT ----
  hipMemsetAsync(X1F, 0, (size_t)(cNE + cNT) * cD * sizeof(float), stream);
  spmv_scatter<<<(cNNZ_E2T * 32 + 255) / 256, 256, 0, stream>>>(
      e2t_row, e2t_col, e2t_val, cNNZ_E2T, entity, type_e, cNE, X1F);
  hipMemsetAsync(SLOT, 0x7F, (size_t)(cNE + cNT) * sizeof(int), stream);
  slot_build<<<16, 256, 0, stream>>>(src_ids, SLOT, 0);
  hipMemsetAsync(X2C, 0, (size_t)cNSRC * cD * sizeof(float), stream);
  spmv_scatter_slot<<<(cNNZ_E2T * 32 + 255) / 256, 256, 0, stream>>>(
      e2t_row, e2t_col, e2t_val, cNNZ_E2T, X1F, SLOT, X2C);
  gather_ln<<<cNSRC, 128, 0, stream>>>(src_ids, 0, entity, type_e, cNE, X1F, X2C, SLOT,
                                       ln_g, ln_b, S1);

  // ---- GCN e2c -> src2 for ids < NE or >= NE+NT ----
  hipMemsetAsync(X1F, 0, (size_t)(cNE + cNC) * cD * sizeof(float), stream);
  spmv_scatter<<<(cNNZ_E2C * 32 + 255) / 256, 256, 0, stream>>>(
      e2c_row, e2c_col, e2c_val, cNNZ_E2C, entity, cluster, cNE, X1F);
  hipMemsetAsync(SLOT, 0x7F, (size_t)(cNE + cNC) * sizeof(int), stream);
  slot_build<<<16, 256, 0, stream>>>(src_ids, SLOT, 3);
  hipMemsetAsync(X2C, 0, (size_t)cNSRC * cD * sizeof(float), stream);
  spmv_scatter_slot<<<(cNNZ_E2C * 32 + 255) / 256, 256, 0, stream>>>(
      e2c_row, e2c_col, e2c_val, cNNZ_E2C, X1F, SLOT, X2C);
  gather_ln<<<cNSRC, 128, 0, stream>>>(src_ids, 3, entity, cluster, cNE, X1F, X2C, SLOT,
                                       ln_g, ln_b, S2);

  // ---- GCN t2c (small, full) -> src1 clusters, src2 types ----
  hipMemsetAsync(X1T, 0, (size_t)1152 * cD * sizeof(float), stream);
  hipMemsetAsync(X2T, 0, (size_t)1152 * cD * sizeof(float), stream);
  spmv_scatter<<<(cNNZ_T2C * 32 + 255) / 256, 256, 0, stream>>>(
      t2c_row, t2c_col, t2c_val, cNNZ_T2C, type_e, cluster, cNT, X1T);
  spmv_scatter<<<(cNNZ_T2C * 32 + 255) / 256, 256, 0, stream>>>(
      t2c_row, t2c_col, t2c_val, cNNZ_T2C, X1T, X1T, 1152, X2T);
  gather_ln<<<cNSRC, 128, 0, stream>>>(src_ids, 1, type_e, cluster, cNT, X1T, X2T, nullptr,
                                       ln_g, ln_b, S1);
  gather_ln<<<cNSRC, 128, 0, stream>>>(src_ids, 2, type_e, cluster, cNT, X1T, X2T, nullptr,
                                       ln_g, ln_b, S2);

  // ---- contrastive loss ----
  dim3 g128(cD / 64, cNSRC / 64);
  gemm64<<<g128, 256, 0, stream>>>(S1, cl_w1, PT, cNSRC, cD, cD, cl_b1, nullptr, 0, 1);
  gemm64<<<g128, 256, 0, stream>>>(PT, cl_w2, Z1, cNSRC, cD, cD, cl_b2, nullptr, 0, 0);
  gemm64<<<g128, 256, 0, stream>>>(S2, cl_w1, PT, cNSRC, cD, cD, cl_b1, nullptr, 0, 1);
  gemm64<<<g128, 256, 0, stream>>>(PT, cl_w2, Z2, cNSRC, cD, cD, cl_b2, nullptr, 0, 0);
  rownorm<<<cNSRC, 128, 0, stream>>>(Z1);
  rownorm<<<cNSRC, 128, 0, stream>>>(Z2);
  cl_sums<<<cNSRC / 16, 256, 0, stream>>>(Z1, Z2, SCAL);
  emb_sum_k<<<cNSRC, 256, 0, stream>>>(S1, S2, relation, etype, SCAL + 1);

  // ---- message + predict ----
  msg_build<<<cNSRC, 256, 0, stream>>>(S1, S2, relation, etype, MSG);
  dim3 gP(cT / 64, cNSRC / 64);
  gemm64<<<gP, 256, 0, stream>>>(MSG, fc_w, Pb, cNSRC, cT, 2 * cD, fc_b, nullptr, 0, 0);

  // ---- MHA ----
  gemm64<<<gP, 256, 0, stream>>>(Pb, wq, Qb, cNSRC, cT, cT, bq, nullptr, 0, 0);
  gemm64<<<gP, 256, 0, stream>>>(Pb, wk, Kb, cNSRC, cT, cT, bk, nullptr, 0, 0);
  gemm64<<<gP, 256, 0, stream>>>(Pb, wv, Vb, cNSRC, cT, cT, bv, nullptr, 0, 0);
  mha_attn<<<cB * 8, 64, 0, stream>>>(Qb, Kb, Vb, Pb);           // o_pre -> Pb
  gemm64<<<gP, 256, 0, stream>>>(Pb, wo, Qb, cNSRC, cT, cT, bo, nullptr, 0, 0);  // o -> Qb

  // ---- MoE ----
  gate_k<<<cNSRC, 64, 0, stream>>>(Qb, gate_w, GATE);
  hipMemsetAsync(Vb, 0, BIGB * sizeof(float), stream);
  for (int e = 0; e < cE; ++e) {
    gemm64<<<gP, 256, 0, stream>>>(Qb, exp_w + (size_t)e * cT * cT, Vb, cNSRC, cT, cT,
                                   exp_b + (size_t)e * cT, GATE + e, cE, 2);
  }

  // ---- output ----
  mean_sigmoid<<<(cB * cT) / 256, 256, 0, stream>>>(Vb, (float*)d_out);
  finalize_k<<<1, 1, 0, stream>>>(SCAL, (float*)d_out + (size_t)cB * cT);
}

// Round 2
// 2297.938 us; speedup vs baseline: 2.3868x; 2.3868x over previous
//
#include <hip/hip_runtime.h>
#include <hip/hip_bf16.h>
#include <cmath>

// ---------------------------------------------------------------------------
// Problem constants (fixed shapes)
// ---------------------------------------------------------------------------
constexpr int cNE = 100000, cNT = 1024, cNC = 128, cD = 128, cNR = 500;
constexpr int cB = 512, cNSRC = 4096, cT = 1024, cE = 4;
constexpr int cNNZ_E2T = 1000000, cNNZ_T2C = 50000, cNNZ_E2C = 500000;
constexpr float cDECAY = 1e-4f, cCLW = 0.1f;
constexpr int cNN_E2T = cNE + cNT;     // 101024
constexpr int cNN_E2C = cNE + cNC;     // 100128
constexpr int cNN_T2C = cNT + cNC;     // 1152

// ---------------------------------------------------------------------------
// Workspace layout (all offsets in FLOAT units)
// ---------------------------------------------------------------------------
constexpr size_t F_S1   = 0;                          // f32 4096x128
constexpr size_t F_S2   = F_S1 + 524288;
constexpr size_t F_PT   = F_S2 + 524288;
constexpr size_t F_Z1   = F_PT + 524288;
constexpr size_t F_Z2   = F_Z1 + 524288;
constexpr size_t F_MSG  = F_Z2 + 524288;              // bf16 4096x256 (524288 fl)
constexpr size_t F_GATE = F_MSG + 524288;             // f32 4096x4
constexpr size_t F_SCAL = F_GATE + 16384;
constexpr size_t F_U    = F_SCAL + 64;                // union region base
// --- GCN phase members of the union ---
constexpr size_t G_X1F  = F_U;                        // f32 101024x128
constexpr size_t G_X2C  = G_X1F + 12931072;           // f32 4096x128
constexpr size_t G_SLOT = G_X2C + 524288;             // int[101376]
constexpr size_t G_REP  = G_SLOT + 101376;            // int[4096]
constexpr size_t G_RP   = G_REP + 4096;               // int[101376] rowptr
constexpr size_t G_FILL = G_RP + 101376;              // int[101376] cnt/fill
constexpr size_t G_EIDX = G_FILL + 101376;            // int[1000000]
constexpr size_t G_X1T  = G_EIDX + 1000000;           // f32 1152x128
constexpr size_t G_X2T  = G_X1T + 147456;             // f32 1152x128
constexpr size_t G_BSUM = G_X2T + 147456;             // int[512]
// --- activation phase members (bf16 buffers are 4096x1024 = 2,097,152 fl) ---
constexpr size_t A_U0  = F_U;                 // P, then attn-out O1; MOE f32 spans U0+U1
constexpr size_t A_U1  = F_U + 2097152;       // Q
constexpr size_t A_U2  = F_U + 2 * 2097152;   // K, then o-proj out O
constexpr size_t A_U3  = F_U + 3 * 2097152;   // V
constexpr size_t A_WBT = F_U + 4 * 2097152;   // bf16 weight^T scratch (1M elems)

typedef __attribute__((ext_vector_type(8))) short short8v;
typedef __attribute__((ext_vector_type(4))) float f32x4;

// ---------------------------------------------------------------------------
// Helpers
// ---------------------------------------------------------------------------
__device__ __forceinline__ void atomAdd(float* p, float v) {
  __hip_atomic_fetch_add(p, v, __ATOMIC_RELAXED, __HIP_MEMORY_SCOPE_AGENT);
}
__device__ __forceinline__ ushort f2bf(float f) {
  __hip_bfloat16 h = __float2bfloat16(f);
  return *reinterpret_cast<ushort*>(&h);
}
__device__ __forceinline__ float bf2f(ushort u) {
  __hip_bfloat16 h; *reinterpret_cast<ushort*>(&h) = u;
  return __bfloat162float(h);
}

__device__ __forceinline__ int mapNode(int mode, int id) {
  switch (mode) {
    case 0:  return (id < cNE + cNT) ? id : -1;                        // e2t -> node1
    case 1:  return (id >= cNE + cNT) ? (id - cNE) : -1;               // t2c cluster -> node1
    case 2:  return (id >= cNE && id < cNE + cNT) ? (id - cNE) : -1;   // t2c type -> node2
    default: return (id < cNE) ? id
                   : ((id >= cNE + cNT) ? (id - cNT) : -1);            // e2c -> node2
  }
}

__device__ __forceinline__ float blockReduce128(float v, float* sh, int tid) {
  sh[tid] = v; __syncthreads();
  if (tid < 64) sh[tid] += sh[tid + 64]; __syncthreads();
  if (tid < 32) sh[tid] += sh[tid + 32]; __syncthreads();
  if (tid < 16) sh[tid] += sh[tid + 16]; __syncthreads();
  if (tid < 8)  sh[tid] += sh[tid + 8];  __syncthreads();
  if (tid < 4)  sh[tid] += sh[tid + 4];  __syncthreads();
  if (tid < 2)  sh[tid] += sh[tid + 2];  __syncthreads();
  if (tid < 1)  sh[tid] += sh[tid + 1];  __syncthreads();
  float r = sh[0]; __syncthreads();
  return r;
}
__device__ __forceinline__ float blockReduce256(float v, float* sh, int tid) {
  sh[tid] = v; __syncthreads();
  for (int s = 128; s > 0; s >>= 1) {
    if (tid < s) sh[tid] += sh[tid + s];
    __syncthreads();
  }
  float r = sh[0]; __syncthreads();
  return r;
}

// ---------------------------------------------------------------------------
// CSR build: histogram -> block scan -> bsum scan -> add+copy -> fill
// ---------------------------------------------------------------------------
__global__ __launch_bounds__(256) void k_hist(const int* __restrict__ row, int nnz,
                                              int* __restrict__ cnt) {
  int e = blockIdx.x * 256 + threadIdx.x;
  if (e < nnz) atomicAdd(&cnt[row[e]], 1);
}

__global__ __launch_bounds__(256) void k_scan_block(const int* __restrict__ cnt, int n,
                                                    int* __restrict__ excl, int* __restrict__ bsum) {
  __shared__ int sh[256];
  int tid = threadIdx.x;
  int i = blockIdx.x * 256 + tid;
  int v = (i < n) ? cnt[i] : 0;
  sh[tid] = v; __syncthreads();
  for (int off = 1; off < 256; off <<= 1) {
    int t = (tid >= off) ? sh[tid - off] : 0;
    __syncthreads();
    sh[tid] += t;
    __syncthreads();
  }
  if (i < n) excl[i] = sh[tid] - v;
  if (tid == 255) bsum[blockIdx.x] = sh[255];
}

__global__ __launch_bounds__(512) void k_bsum_scan(int* __restrict__ bsum, int nb,
                                                   int* __restrict__ rowptr, int n) {
  __shared__ int sh[512];
  int tid = threadIdx.x;
  int v = (tid < nb) ? bsum[tid] : 0;
  sh[tid] = v; __syncthreads();
  for (int off = 1; off < 512; off <<= 1) {
    int t = (tid >= off) ? sh[tid - off] : 0;
    __syncthreads();
    sh[tid] += t;
    __syncthreads();
  }
  if (tid < nb) bsum[tid] = sh[tid] - v;
  if (tid == 511) rowptr[n] = sh[511];
}

__global__ __launch_bounds__(256) void k_scan_add(int* __restrict__ rowptr,
                                                  const int* __restrict__ bsum, int n,
                                                  int* __restrict__ fill) {
  int i = blockIdx.x * 256 + threadIdx.x;
  if (i < n) {
    int r = rowptr[i] + bsum[blockIdx.x];
    rowptr[i] = r;
    fill[i] = r;
  }
}

__global__ __launch_bounds__(256) void k_fill(const int* __restrict__ row, int nnz,
                                              int* __restrict__ fill, int* __restrict__ eidx) {
  int e = blockIdx.x * 256 + threadIdx.x;
  if (e < nnz) {
    int pos = atomicAdd(&fill[row[e]], 1);
    eidx[pos] = e;
  }
}

// wave-per-row gather: out[r] = sum val[e] * x[col[e]]; x = concat(ea[na], eb)
__global__ __launch_bounds__(256) void k_gather(
    const int* __restrict__ rowptr, const int* __restrict__ eidx,
    const int* __restrict__ col, const float* __restrict__ val,
    const float* __restrict__ ea, const float* __restrict__ eb, int na,
    int nrows, float* __restrict__ out) {
  int r = blockIdx.x * 4 + (threadIdx.x >> 6);
  if (r >= nrows) return;
  int lane = threadIdx.x & 63;
  int p0 = rowptr[r], p1 = rowptr[r + 1];
  float ax = 0.f, ay = 0.f;
  for (int p = p0; p < p1; ++p) {
    int e = eidx[p];
    int c = col[e];
    float v = val[e];
    const float* src = (c < na) ? (ea + (size_t)c * cD) : (eb + (size_t)(c - na) * cD);
    float2 x = *reinterpret_cast<const float2*>(src + lane * 2);
    ax += v * x.x; ay += v * x.y;
  }
  float2 o; o.x = ax; o.y = ay;
  *reinterpret_cast<float2*>(out + (size_t)r * cD + lane * 2) = o;
}

__global__ __launch_bounds__(256) void slot_build(const int* __restrict__ ids,
                                                  int* __restrict__ slot, int mode) {
  int i = blockIdx.x * 256 + threadIdx.x;
  if (i >= cNSRC) return;
  int node = mapNode(mode, ids[i]);
  if (node >= 0) atomicMin(&slot[node], i);
}

__global__ __launch_bounds__(256) void k_rep(const int* __restrict__ ids,
                                             const int* __restrict__ slot, int mode,
                                             int* __restrict__ rep) {
  int i = blockIdx.x * 256 + threadIdx.x;
  if (i >= cNSRC) return;
  int node = mapNode(mode, ids[i]);
  rep[i] = (node >= 0 && slot[node] == i) ? node : -1;
}

// layer-2 gather only at representative slots
__global__ __launch_bounds__(256) void k_gather_slot(
    const int* __restrict__ rowptr, const int* __restrict__ eidx,
    const int* __restrict__ col, const float* __restrict__ val,
    const float* __restrict__ x1, const int* __restrict__ rep,
    float* __restrict__ outc) {
  int i = blockIdx.x * 4 + (threadIdx.x >> 6);
  if (i >= cNSRC) return;
  int r = rep[i];
  if (r < 0) return;
  int lane = threadIdx.x & 63;
  int p0 = rowptr[r], p1 = rowptr[r + 1];
  float ax = 0.f, ay = 0.f;
  for (int p = p0; p < p1; ++p) {
    int e = eidx[p];
    int c = col[e];
    float v = val[e];
    float2 x = *reinterpret_cast<const float2*>(x1 + (size_t)c * cD + lane * 2);
    ax += v * x.x; ay += v * x.y;
  }
  float2 o; o.x = ax; o.y = ay;
  *reinterpret_cast<float2*>(outc + (size_t)i * cD + lane * 2) = o;
}

// (x0 + x1 + x2)/3 at gathered rows -> LayerNorm -> dst
__global__ __launch_bounds__(128) void gather_ln(
    const int* __restrict__ ids, int mode,
    const float* __restrict__ ea, const float* __restrict__ eb, int na,
    const float* __restrict__ x1, const float* __restrict__ x2, const int* __restrict__ slot,
    const float* __restrict__ g, const float* __restrict__ bia, float* __restrict__ dst) {
  __shared__ float sh[128];
  int i = blockIdx.x;
  int tid = threadIdx.x;
  int id = ids[i];
  int node = mapNode(mode, id);
  if (node < 0) return;
  const float* x0 = (node < na) ? (ea + (size_t)node * cD) : (eb + (size_t)(node - na) * cD);
  int xi2 = slot ? slot[node] : node;
  float a = (x0[tid] + x1[(size_t)node * cD + tid] + x2[(size_t)xi2 * cD + tid]) * (1.0f / 3.0f);
  float s  = blockReduce128(a, sh, tid);
  float ss = blockReduce128(a * a, sh, tid);
  float mu = s * (1.0f / 128.0f);
  float var = ss * (1.0f / 128.0f) - mu * mu;
  float y = (a - mu) * rsqrtf(var + 1e-5f) * g[tid] + bia[tid];
  dst[(size_t)i * cD + tid] = y;
}

// ---------------------------------------------------------------------------
// fp32 GEMM (small cl projections only): epi 0=store, 1=store ELU
// ---------------------------------------------------------------------------
__global__ __launch_bounds__(256) void gemm64(
    const float* __restrict__ A, const float* __restrict__ B, float* __restrict__ C,
    int M, int N, int K, const float* __restrict__ bias, int epi) {
  __shared__ __align__(16) float As[16][68];
  __shared__ __align__(16) float Bs[16][68];
  const int bx = blockIdx.x, by = blockIdx.y;
  const int tx = threadIdx.x & 15, ty = threadIdx.x >> 4;
  const int la_r = threadIdx.x >> 2;
  const int la_k = (threadIdx.x & 3) * 4;
  const int lb_k = threadIdx.x >> 4;
  const int lb_c = (threadIdx.x & 15) * 4;
  float acc[4][4] = {};
  for (int kt = 0; kt < K; kt += 16) {
    __syncthreads();
    float4 av = *reinterpret_cast<const float4*>(A + (size_t)(by * 64 + la_r) * K + kt + la_k);
    As[la_k + 0][la_r] = av.x; As[la_k + 1][la_r] = av.y;
    As[la_k + 2][la_r] = av.z; As[la_k + 3][la_r] = av.w;
    *reinterpret_cast<float4*>(&Bs[lb_k][lb_c]) =
        *reinterpret_cast<const float4*>(B + (size_t)(kt + lb_k) * N + bx * 64 + lb_c);
    __syncthreads();
#pragma unroll
    for (int kk = 0; kk < 16; ++kk) {
      float4 a = *reinterpret_cast<const float4*>(&As[kk][ty * 4]);
      float4 b = *reinterpret_cast<const float4*>(&Bs[kk][tx * 4]);
      acc[0][0] += a.x * b.x; acc[0][1] += a.x * b.y; acc[0][2] += a.x * b.z; acc[0][3] += a.x * b.w;
      acc[1][0] += a.y * b.x; acc[1][1] += a.y * b.y; acc[1][2] += a.y * b.z; acc[1][3] += a.y * b.w;
      acc[2][0] += a.z * b.x; acc[2][1] += a.z * b.y; acc[2][2] += a.z * b.z; acc[2][3] += a.z * b.w;
      acc[3][0] += a.w * b.x; acc[3][1] += a.w * b.y; acc[3][2] += a.w * b.z; acc[3][3] += a.w * b.w;
    }
  }
  const int row0 = by * 64 + ty * 4, col0 = bx * 64 + tx * 4;
#pragma unroll
  for (int i = 0; i < 4; ++i)
#pragma unroll
    for (int j = 0; j < 4; ++j) {
      int r = row0 + i, c = col0 + j;
      float v = acc[i][j] + bias[c];
      if (epi == 1) v = (v > 0.0f) ? v : expm1f(v);
      C[(size_t)r * N + c] = v;
    }
}

// ---------------------------------------------------------------------------
// bf16 MFMA GEMM: C[M,N] = A[M,K] @ Bt[N,K]^T, 128x128 tile, 4 waves
// epi 0: Cbf = bf16(acc + bias); epi 1: Cf32 += rowscale[r*4] * (acc + bias)
// ---------------------------------------------------------------------------
__global__ __launch_bounds__(256) void gemm_bf(
    const ushort* __restrict__ A, const ushort* __restrict__ Bt,
    int N, int K, const float* __restrict__ bias,
    ushort* __restrict__ Cbf, float* __restrict__ Cf32,
    const float* __restrict__ rowscale, int epi) {
  __shared__ ushort As[128 * 40];
  __shared__ ushort Bs[128 * 40];
  const int bx = blockIdx.x, by = blockIdx.y;
  const int t = threadIdx.x;
  const int wv = t >> 6, lane = t & 63;
  const int wr = (wv >> 1) * 64, wc = (wv & 1) * 64;
  const int srow = t >> 1, shalf = t & 1;
  const ushort* Ag = A + (size_t)(by * 128 + srow) * K + shalf * 16;
  const ushort* Bg = Bt + (size_t)(bx * 128 + srow) * K + shalf * 16;
  uint4 ra0 = *reinterpret_cast<const uint4*>(Ag);
  uint4 ra1 = *reinterpret_cast<const uint4*>(Ag + 8);
  uint4 rb0 = *reinterpret_cast<const uint4*>(Bg);
  uint4 rb1 = *reinterpret_cast<const uint4*>(Bg + 8);
  f32x4 acc[4][4];
  const f32x4 z4 = {0.f, 0.f, 0.f, 0.f};
#pragma unroll
  for (int i = 0; i < 4; ++i)
#pragma unroll
    for (int j = 0; j < 4; ++j) acc[i][j] = z4;
  const int la = lane & 15, lk = (lane >> 4) * 8;
  const int sdst = srow * 40 + shalf * 16;
  for (int kt = 0; kt < K; kt += 32) {
    __syncthreads();
    *reinterpret_cast<uint4*>(&As[sdst])     = ra0;
    *reinterpret_cast<uint4*>(&As[sdst + 8]) = ra1;
    *reinterpret_cast<uint4*>(&Bs[sdst])     = rb0;
    *reinterpret_cast<uint4*>(&Bs[sdst + 8]) = rb1;
    __syncthreads();
    if (kt + 32 < K) {   // T14-lite: issue next chunk's loads before compute
      ra0 = *reinterpret_cast<const uint4*>(Ag + kt + 32);
      ra1 = *reinterpret_cast<const uint4*>(Ag + kt + 40);
      rb0 = *reinterpret_cast<const uint4*>(Bg + kt + 32);
      rb1 = *reinterpret_cast<const uint4*>(Bg + kt + 40);
    }
    short8v af[4], bfr[4];
#pragma unroll
    for (int i = 0; i < 4; ++i)
      af[i] = *reinterpret_cast<const short8v*>(&As[(wr + i * 16 + la) * 40 + lk]);
#pragma unroll
    for (int j = 0; j < 4; ++j)
      bfr[j] = *reinterpret_cast<const short8v*>(&Bs[(wc + j * 16 + la) * 40 + lk]);
#pragma unroll
    for (int i = 0; i < 4; ++i)
#pragma unroll
      for (int j = 0; j < 4; ++j)
        acc[i][j] = __builtin_amdgcn_mfma_f32_16x16x32_bf16(af[i], bfr[j], acc[i][j], 0, 0, 0);
  }
  const int r0 = by * 128 + wr + (lane >> 4) * 4;
  const int c0 = bx * 128 + wc + la;
#pragma unroll
  for (int i = 0; i < 4; ++i)
#pragma unroll
    for (int j = 0; j < 4; ++j) {
      int c = c0 + j * 16;
      float bv = bias[c];
#pragma unroll
      for (int q = 0; q < 4; ++q) {
        int r = r0 + i * 16 + q;
        float v = acc[i][j][q] + bv;
        size_t idx = (size_t)r * N + c;
        if (epi == 0) Cbf[idx] = f2bf(v);
        else Cf32[idx] += rowscale[(size_t)r * 4] * v;
      }
    }
}

// weight transpose + bf16 convert: Bt[n*K+k] = bf16(W[k*N+n])
__global__ __launch_bounds__(256) void k_wt_bt(const float* __restrict__ W,
                                               ushort* __restrict__ Bt, int K, int N) {
  __shared__ float tile[32][33];
  int n0 = blockIdx.x * 32, k0 = blockIdx.y * 32;
  int tx = threadIdx.x & 31, ty = threadIdx.x >> 5;
#pragma unroll
  for (int i = 0; i < 4; ++i)
    tile[ty + 8 * i][tx] = W[(size_t)(k0 + ty + 8 * i) * N + n0 + tx];
  __syncthreads();
#pragma unroll
  for (int i = 0; i < 4; ++i)
    Bt[(size_t)(n0 + ty + 8 * i) * K + k0 + tx] = f2bf(tile[tx][ty + 8 * i]);
}

// ---------------------------------------------------------------------------
// Contrastive loss
// ---------------------------------------------------------------------------
__global__ __launch_bounds__(128) void rownorm(float* __restrict__ z) {
  __shared__ float sh[128];
  int i = blockIdx.x, tid = threadIdx.x;
  float v = z[(size_t)i * cD + tid];
  float ss = blockReduce128(v * v, sh, tid);
  float n = sqrtf(ss);
  z[(size_t)i * cD + tid] = v / fmaxf(n, 1e-12f);
}

__global__ __launch_bounds__(256) void cl_sums(
    const float* __restrict__ z1, const float* __restrict__ z2, float* __restrict__ cl_sum) {
  __shared__ float z1i[16][128], z2i[16][128];
  __shared__ float z1j[32][128], z2j[32][128];
  __shared__ float red[4][16][16];
  __shared__ float dd[3][16];
  const int i0 = blockIdx.x * 16;
  const int tx = threadIdx.x;
  for (int idx = tx; idx < 16 * 128; idx += 256) {
    int r = idx >> 7, c = idx & 127;
    z1i[r][c] = z1[(size_t)(i0 + r) * cD + c];
    z2i[r][c] = z2[(size_t)(i0 + r) * cD + c];
  }
  const int ti = tx & 15, tj = tx >> 4;
  float r11 = 0, r12 = 0, r21 = 0, r22 = 0;
  float d12 = 0, diag11 = 0, diag22 = 0;
  for (int j0 = 0; j0 < cNSRC; j0 += 32) {
    __syncthreads();
    for (int idx = tx; idx < 32 * 128; idx += 256) {
      int r = idx >> 7, c = idx & 127;
      z1j[r][c] = z1[(size_t)(j0 + r) * cD + c];
      z2j[r][c] = z2[(size_t)(j0 + r) * cD + c];
    }
    __syncthreads();
    float a11[2] = {0, 0}, a12[2] = {0, 0}, a21[2] = {0, 0}, a22[2] = {0, 0};
#pragma unroll 8
    for (int kk = 0; kk < 128; ++kk) {
      float x1 = z1i[ti][kk], x2 = z2i[ti][kk];
#pragma unroll
      for (int rr = 0; rr < 2; ++rr) {
        float y1 = z1j[tj + 16 * rr][kk], y2 = z2j[tj + 16 * rr][kk];
        a11[rr] += x1 * y1; a12[rr] += x1 * y2;
        a21[rr] += x2 * y1; a22[rr] += x2 * y2;
      }
    }
#pragma unroll
    for (int rr = 0; rr < 2; ++rr) {
      float e11 = expf(2.0f * a11[rr]), e12 = expf(2.0f * a12[rr]);
      float e21 = expf(2.0f * a21[rr]), e22 = expf(2.0f * a22[rr]);
      r11 += e11; r12 += e12; r21 += e21; r22 += e22;
      if (j0 + tj + 16 * rr == i0 + ti) { d12 = e12; diag11 = e11; diag22 = e22; }
    }
  }
  red[0][ti][tj] = r11; red[1][ti][tj] = r12; red[2][ti][tj] = r21; red[3][ti][tj] = r22;
  if (d12 != 0.0f) { dd[0][ti] = d12; dd[1][ti] = diag11; dd[2][ti] = diag22; }
  __syncthreads();
  if (tj == 0) {
    float R11 = 0, R12 = 0, R21 = 0, R22 = 0;
    for (int t = 0; t < 16; ++t) {
      R11 += red[0][ti][t]; R12 += red[1][ti][t];
      R21 += red[2][ti][t]; R22 += red[3][ti][t];
    }
    float denA = R11 + R12 - dd[1][ti];
    float denB = R22 + R21 - dd[2][ti];
    float l = 0.5f * (logf(denA) + logf(denB)) - logf(dd[0][ti]);
    atomAdd(cl_sum, l);
  }
}

// ---------------------------------------------------------------------------
// message / losses / MHA / MoE
// ---------------------------------------------------------------------------
__global__ __launch_bounds__(256) void emb_sum_k(
    const float* __restrict__ s1, const float* __restrict__ s2,
    const float* __restrict__ relation, const int* __restrict__ etype, float* __restrict__ out) {
  __shared__ float sh[256];
  int idx = blockIdx.x * 256 + threadIdx.x;
  int i = idx >> 8, j = idx & 255;
  float a = (j < 128) ? s1[(size_t)i * 128 + j] : s2[(size_t)i * 128 + j - 128];
  int et = etype[i];
  float r = relation[(size_t)(et % cNR) * 256 + j];
  float t = blockReduce256(a * a + r * r, sh, threadIdx.x);
  if (threadIdx.x == 0) atomAdd(out, t);
}

__global__ __launch_bounds__(256) void msg_build(
    const float* __restrict__ s1, const float* __restrict__ s2,
    const float* __restrict__ relation, const int* __restrict__ etype,
    ushort* __restrict__ msg) {
  int idx = blockIdx.x * 256 + threadIdx.x;
  int i = idx >> 8, j = idx & 255;
  int et = etype[i];
  float sign = (et >= cNR) ? -1.0f : 1.0f;
  float r = relation[(size_t)(et % cNR) * 256 + j] * sign;
  float s = (j < 128) ? s1[(size_t)i * 128 + j] : s2[(size_t)i * 128 + j - 128];
  msg[idx] = f2bf(fmaxf(s + r, 0.0f));
}

__global__ __launch_bounds__(64) void mha_attn(
    const ushort* __restrict__ q, const ushort* __restrict__ k,
    const ushort* __restrict__ v, ushort* __restrict__ o) {
  __shared__ float qs[8][128], ks[8][128], vs[8][128], att[8][8];
  int bh = blockIdx.x;
  int b = bh >> 3, h = bh & 7;
  int tid = threadIdx.x;
  for (int idx = tid; idx < 1024; idx += 64) {
    int l = idx >> 7, d = idx & 127;
    size_t src = (size_t)(b * 8 + l) * cT + h * 128 + d;
    qs[l][d] = bf2f(q[src]); ks[l][d] = bf2f(k[src]); vs[l][d] = bf2f(v[src]);
  }
  __syncthreads();
  int l = tid >> 3, m = tid & 7;
  float s = 0;
#pragma unroll 16
  for (int d = 0; d < 128; ++d) s += qs[l][d] * ks[m][d];
  s *= 0.08838834764831845f;
  float mx = s;
  for (int off = 1; off < 8; off <<= 1) mx = fmaxf(mx, __shfl_xor(mx, off, 8));
  float p = expf(s - mx);
  float sum = p;
  for (int off = 1; off < 8; off <<= 1) sum += __shfl_xor(sum, off, 8);
  att[l][m] = p / sum;
  __syncthreads();
  for (int idx = tid; idx < 1024; idx += 64) {
    int ll = idx >> 7, d = idx & 127;
    float acc = 0;
#pragma unroll
    for (int mm = 0; mm < 8; ++mm) acc += att[ll][mm] * vs[mm][d];
    o[(size_t)(b * 8 + ll) * cT + h * 128 + d] = f2bf(acc);
  }
}

__global__ __launch_bounds__(64) void gate_k(
    const ushort* __restrict__ o, const float* __restrict__ gw, float* __restrict__ gate) {
  int i = blockIdx.x;
  int lane = threadIdx.x;
  float g[4] = {0, 0, 0, 0};
  for (int d = lane; d < cT; d += 64) {
    float ov = bf2f(o[(size_t)i * cT + d]);
    g[0] += ov * gw[d * 4 + 0];
    g[1] += ov * gw[d * 4 + 1];
    g[2] += ov * gw[d * 4 + 2];
    g[3] += ov * gw[d * 4 + 3];
  }
#pragma unroll
  for (int off = 32; off > 0; off >>= 1)
#pragma unroll
    for (int e = 0; e < 4; ++e) g[e] += __shfl_down(g[e], off);
  if (lane == 0) {
    float mx = fmaxf(fmaxf(g[0], g[1]), fmaxf(g[2], g[3]));
    float ex[4], sum = 0;
#pragma unroll
    for (int e = 0; e < 4; ++e) { ex[e] = expf(g[e] - mx); sum += ex[e]; }
#pragma unroll
    for (int e = 0; e < 4; ++e) gate[(size_t)i * 4 + e] = ex[e] / sum;
  }
}

__global__ __launch_bounds__(256) void mean_sigmoid(
    const float* __restrict__ moe, float* __restrict__ out) {
  int idx = blockIdx.x * 256 + threadIdx.x;
  int b = idx >> 10, t = idx & 1023;
  float s = 0;
#pragma unroll
  for (int l = 0; l < 8; ++l) s += moe[(size_t)(b * 8 + l) * cT + t];
  s *= (1.0f / 8.0f);
  out[idx] = 1.0f / (1.0f + expf(-s));
}

__global__ void finalize_k(const float* __restrict__ scal, float* __restrict__ out_aux) {
  float cl = scal[0] * (1.0f / cNSRC);
  float emb = cDECAY * 0.5f * scal[1] * (1.0f / cNSRC);
  out_aux[0] = cCLW * cl + emb;
}

// ---------------------------------------------------------------------------
// Launch
// ---------------------------------------------------------------------------
extern "C" void kernel_launch(void* const* d_in, const int* in_sizes, int n_in,
                              void* d_out, int out_size, void* d_ws, size_t ws_size,
                              hipStream_t stream) {
  (void)in_sizes; (void)n_in; (void)out_size; (void)ws_size;
  const float* entity   = (const float*)d_in[0];
  const float* type_e   = (const float*)d_in[1];
  const float* cluster  = (const float*)d_in[2];
  const float* relation = (const float*)d_in[3];
  const float* ln_g  = (const float*)d_in[4];
  const float* ln_b  = (const float*)d_in[5];
  const float* cl_w1 = (const float*)d_in[6];
  const float* cl_b1 = (const float*)d_in[7];
  const float* cl_w2 = (const float*)d_in[8];
  const float* cl_b2 = (const float*)d_in[9];
  const float* fc_w  = (const float*)d_in[10];
  const float* fc_b  = (const float*)d_in[11];
  const float* wq = (const float*)d_in[12];
  const float* bq = (const float*)d_in[13];
  const float* wk = (const float*)d_in[14];
  const float* bk = (const float*)d_in[15];
  const float* wv = (const float*)d_in[16];
  const float* bv = (const float*)d_in[17];
  const float* wo = (const float*)d_in[18];
  const float* bo = (const float*)d_in[19];
  const float* gate_w = (const float*)d_in[20];
  const float* exp_w  = (const float*)d_in[21];
  const float* exp_b  = (const float*)d_in[22];
  const float* e2t_val = (const float*)d_in[23];
  const float* t2c_val = (const float*)d_in[24];
  const float* e2c_val = (const float*)d_in[25];
  const int* e2t_row = (const int*)d_in[26];
  const int* e2t_col = (const int*)d_in[27];
  const int* t2c_row = (const int*)d_in[28];
  const int* t2c_col = (const int*)d_in[29];
  const int* e2c_row = (const int*)d_in[30];
  const int* e2c_col = (const int*)d_in[31];
  const int* src_ids = (const int*)d_in[32];
  const int* etype   = (const int*)d_in[33];

  float* ws = (float*)d_ws;
  float* S1 = ws + F_S1;
  float* S2 = ws + F_S2;
  float* PT = ws + F_PT;
  float* Z1 = ws + F_Z1;
  float* Z2 = ws + F_Z2;
  ushort* MSGbf = (ushort*)(ws + F_MSG);
  float* GATE = ws + F_GATE;
  float* SCAL = ws + F_SCAL;
  float* X1F  = ws + G_X1F;
  float* X2C  = ws + G_X2C;
  int*   SLOT = (int*)(ws + G_SLOT);
  int*   REP  = (int*)(ws + G_REP);
  int*   RP   = (int*)(ws + G_RP);
  int*   FILL = (int*)(ws + G_FILL);
  int*   EIDX = (int*)(ws + G_EIDX);
  float* X1T  = ws + G_X1T;
  float* X2T  = ws + G_X2T;
  int*   BSUM = (int*)(ws + G_BSUM);
  ushort* PB  = (ushort*)(ws + A_U0);   // predict, later attn-out
  ushort* QB  = (ushort*)(ws + A_U1);
  ushort* KB  = (ushort*)(ws + A_U2);   // later o-proj out
  ushort* VB  = (ushort*)(ws + A_U3);
  ushort* WBT = (ushort*)(ws + A_WBT);
  float*  MOE = ws + A_U0;              // f32, spans U0+U1

  hipMemsetAsync(SCAL, 0, 2 * sizeof(float), stream);

  // ================= GCN via CSR gather =================
  auto run_gcn = [&](const int* row, const int* col, const float* val, int nnz, int nn,
                     const float* ea, const float* eb, int na, float* x1out) {
    int nb = (nn + 255) / 256;
    int gEdge = (nnz + 255) / 256;
    hipMemsetAsync(FILL, 0, (size_t)nn * sizeof(int), stream);
    k_hist<<<gEdge, 256, 0, stream>>>(row, nnz, FILL);
    k_scan_block<<<nb, 256, 0, stream>>>(FILL, nn, RP, BSUM);
    k_bsum_scan<<<1, 512, 0, stream>>>(BSUM, nb, RP, nn);
    k_scan_add<<<nb, 256, 0, stream>>>(RP, BSUM, nn, FILL);
    k_fill<<<gEdge, 256, 0, stream>>>(row, nnz, FILL, EIDX);
    k_gather<<<(nn + 3) / 4, 256, 0, stream>>>(RP, EIDX, col, val, ea, eb, na, nn, x1out);
  };

  // ---- e2t: layer1 full, layer2 at slots, LN -> S1 (mode 0) ----
  run_gcn(e2t_row, e2t_col, e2t_val, cNNZ_E2T, cNN_E2T, entity, type_e, cNE, X1F);
  hipMemsetAsync(SLOT, 0x7F, (size_t)cNN_E2T * sizeof(int), stream);
  slot_build<<<16, 256, 0, stream>>>(src_ids, SLOT, 0);
  k_rep<<<16, 256, 0, stream>>>(src_ids, SLOT, 0, REP);
  k_gather_slot<<<cNSRC / 4, 256, 0, stream>>>(RP, EIDX, e2t_col, e2t_val, X1F, REP, X2C);
  gather_ln<<<cNSRC, 128, 0, stream>>>(src_ids, 0, entity, type_e, cNE, X1F, X2C, SLOT,
                                       ln_g, ln_b, S1);

  // ---- e2c: layer1 full, layer2 at slots, LN -> S2 (mode 3) ----
  run_gcn(e2c_row, e2c_col, e2c_val, cNNZ_E2C, cNN_E2C, entity, cluster, cNE, X1F);
  hipMemsetAsync(SLOT, 0x7F, (size_t)cNN_E2C * sizeof(int), stream);
  slot_build<<<16, 256, 0, stream>>>(src_ids, SLOT, 3);
  k_rep<<<16, 256, 0, stream>>>(src_ids, SLOT, 3, REP);
  k_gather_slot<<<cNSRC / 4, 256, 0, stream>>>(RP, EIDX, e2c_col, e2c_val, X1F, REP, X2C);
  gather_ln<<<cNSRC, 128, 0, stream>>>(src_ids, 3, entity, cluster, cNE, X1F, X2C, SLOT,
                                       ln_g, ln_b, S2);

  // ---- t2c: tiny, both layers full ----
  run_gcn(t2c_row, t2c_col, t2c_val, cNNZ_T2C, cNN_T2C, type_e, cluster, cNT, X1T);
  k_gather<<<(cNN_T2C + 3) / 4, 256, 0, stream>>>(RP, EIDX, t2c_col, t2c_val,
                                                  X1T, X1T, 1 << 30, cNN_T2C, X2T);
  gather_ln<<<cNSRC, 128, 0, stream>>>(src_ids, 1, type_e, cluster, cNT, X1T, X2T, nullptr,
                                       ln_g, ln_b, S1);
  gather_ln<<<cNSRC, 128, 0, stream>>>(src_ids, 2, type_e, cluster, cNT, X1T, X2T, nullptr,
                                       ln_g, ln_b, S2);

  // ================= contrastive loss (fp32) =================
  dim3 g128(cD / 64, cNSRC / 64);
  gemm64<<<g128, 256, 0, stream>>>(S1, cl_w1, PT, cNSRC, cD, cD, cl_b1, 1);
  gemm64<<<g128, 256, 0, stream>>>(PT, cl_w2, Z1, cNSRC, cD, cD, cl_b2, 0);
  gemm64<<<g128, 256, 0, stream>>>(S2, cl_w1, PT, cNSRC, cD, cD, cl_b1, 1);
  gemm64<<<g128, 256, 0, stream>>>(PT, cl_w2, Z2, cNSRC, cD, cD, cl_b2, 0);
  rownorm<<<cNSRC, 128, 0, stream>>>(Z1);
  rownorm<<<cNSRC, 128, 0, stream>>>(Z2);
  cl_sums<<<cNSRC / 16, 256, 0, stream>>>(Z1, Z2, SCAL);
  emb_sum_k<<<cNSRC, 256, 0, stream>>>(S1, S2, relation, etype, SCAL + 1);

  // ================= message + predict (bf16 MFMA) =================
  msg_build<<<cNSRC, 256, 0, stream>>>(S1, S2, relation, etype, MSGbf);
  dim3 gBF(cT / 128, cNSRC / 128);
  k_wt_bt<<<dim3(cT / 32, 256 / 32), 256, 0, stream>>>(fc_w, WBT, 256, cT);
  gemm_bf<<<gBF, 256, 0, stream>>>(MSGbf, WBT, cT, 256, fc_b, PB, nullptr, nullptr, 0);

  // ================= MHA =================
  k_wt_bt<<<dim3(cT / 32, cT / 32), 256, 0, stream>>>(wq, WBT, cT, cT);
  gemm_bf<<<gBF, 256, 0, stream>>>(PB, WBT, cT, cT, bq, QB, nullptr, nullptr, 0);
  k_wt_bt<<<dim3(cT / 32, cT / 32), 256, 0, stream>>>(wk, WBT, cT, cT);
  gemm_bf<<<gBF, 256, 0, stream>>>(PB, WBT, cT, cT, bk, KB, nullptr, nullptr, 0);
  k_wt_bt<<<dim3(cT / 32, cT / 32), 256, 0, stream>>>(wv, WBT, cT, cT);
  gemm_bf<<<gBF, 256, 0, stream>>>(PB, WBT, cT, cT, bv, VB, nullptr, nullptr, 0);
  mha_attn<<<cB * 8, 64, 0, stream>>>(QB, KB, VB, PB);            // attn-out -> U0
  k_wt_bt<<<dim3(cT / 32, cT / 32), 256, 0, stream>>>(wo, WBT, cT, cT);
  gemm_bf<<<gBF, 256, 0, stream>>>(PB, WBT, cT, cT, bo, KB, nullptr, nullptr, 0);  // o -> U2

  // ================= MoE =================
  gate_k<<<cNSRC, 64, 0, stream>>>(KB, gate_w, GATE);
  hipMemsetAsync(MOE, 0, (size_t)cNSRC * cT * sizeof(float), stream);
  for (int e = 0; e < cE; ++e) {
    k_wt_bt<<<dim3(cT / 32, cT / 32), 256, 0, stream>>>(exp_w + (size_t)e * cT * cT, WBT, cT, cT);
    gemm_bf<<<gBF, 256, 0, stream>>>(KB, WBT, cT, cT, exp_b + (size_t)e * cT,
                                     nullptr, MOE, GATE + e, 1);
  }

  // ================= output =================
  mean_sigmoid<<<(cB * cT) / 256, 256, 0, stream>>>(MOE, (float*)d_out);
  finalize_k<<<1, 1, 0, stream>>>(SCAL, (float*)d_out + (size_t)cB * cT);
}

// Round 3
// 1104.803 us; speedup vs baseline: 4.9645x; 2.0800x over previous
//
#include <hip/hip_runtime.h>
#include <hip/hip_bf16.h>
#include <cmath>

// ---------------------------------------------------------------------------
// Problem constants (fixed shapes)
// ---------------------------------------------------------------------------
constexpr int cNE = 100000, cNT = 1024, cNC = 128, cD = 128, cNR = 500;
constexpr int cB = 512, cNSRC = 4096, cT = 1024, cE = 4;
constexpr int cNNZ_E2T = 1000000, cNNZ_T2C = 50000, cNNZ_E2C = 500000;
constexpr float cDECAY = 1e-4f, cCLW = 0.1f;
constexpr int cNN_E2T = cNE + cNT;     // 101024
constexpr int cNN_E2C = cNE + cNC;     // 100128
constexpr int cNN_T2C = cNT + cNC;     // 1152

// ---------------------------------------------------------------------------
// Workspace layout (all offsets in FLOAT units)
// ---------------------------------------------------------------------------
constexpr size_t F_S1   = 0;                          // f32 4096x128
constexpr size_t F_S2   = F_S1 + 524288;
constexpr size_t F_PT   = F_S2 + 524288;              // proj tmp; later W bf16 [8192][128]
constexpr size_t F_Z1   = F_PT + 524288;
constexpr size_t F_Z2   = F_Z1 + 524288;
constexpr size_t F_MSG  = F_Z2 + 524288;              // bf16 4096x256 (524288 fl)
constexpr size_t F_GATE = F_MSG + 524288;             // f32 4096x4
constexpr size_t F_SCAL = F_GATE + 16384;
constexpr size_t F_RS   = F_SCAL + 64;                // f32 [2][8192] gram row sums
constexpr size_t F_D11  = F_RS + 16384;               // f32 [4096]
constexpr size_t F_D12  = F_D11 + 4096;
constexpr size_t F_D22  = F_D12 + 4096;
constexpr size_t F_U    = F_D22 + 4096;               // union region base
// --- GCN phase members of the union ---
constexpr size_t G_X1F  = F_U;                        // f32 101024x128
constexpr size_t G_X2C  = G_X1F + 12931072;           // f32 4096x128
constexpr size_t G_SLOT = G_X2C + 524288;             // int[101376]
constexpr size_t G_REP  = G_SLOT + 101376;            // int[4096]
constexpr size_t G_RP   = G_REP + 4096;               // int[101376] rowptr
constexpr size_t G_FILL = G_RP + 101376;              // int[101376] cnt/fill
constexpr size_t G_EIDX = G_FILL + 101376;            // int[1000000]
constexpr size_t G_X1T  = G_EIDX + 1000000;           // f32 1152x128
constexpr size_t G_X2T  = G_X1T + 147456;             // f32 1152x128
constexpr size_t G_BSUM = G_X2T + 147456;             // int[512]
// --- activation phase members (bf16 buffers are 4096x1024 = 2,097,152 fl) ---
constexpr size_t A_U0  = F_U;                 // P, then attn-out O1; MOE f32 spans U0+U1
constexpr size_t A_U1  = F_U + 2097152;       // Q
constexpr size_t A_U2  = F_U + 2 * 2097152;   // K, then o-proj out O
constexpr size_t A_U3  = F_U + 3 * 2097152;   // V
constexpr size_t A_WBT = F_U + 4 * 2097152;   // bf16 weight^T scratch (1M elems)

typedef __attribute__((ext_vector_type(8))) short short8v;
typedef __attribute__((ext_vector_type(4))) float f32x4;

// ---------------------------------------------------------------------------
// Helpers
// ---------------------------------------------------------------------------
__device__ __forceinline__ void atomAdd(float* p, float v) {
  __hip_atomic_fetch_add(p, v, __ATOMIC_RELAXED, __HIP_MEMORY_SCOPE_AGENT);
}
__device__ __forceinline__ ushort f2bf(float f) {
  __hip_bfloat16 h = __float2bfloat16(f);
  return *reinterpret_cast<ushort*>(&h);
}
__device__ __forceinline__ float bf2f(ushort u) {
  __hip_bfloat16 h; *reinterpret_cast<ushort*>(&h) = u;
  return __bfloat162float(h);
}

__device__ __forceinline__ int mapNode(int mode, int id) {
  switch (mode) {
    case 0:  return (id < cNE + cNT) ? id : -1;                        // e2t -> node1
    case 1:  return (id >= cNE + cNT) ? (id - cNE) : -1;               // t2c cluster -> node1
    case 2:  return (id >= cNE && id < cNE + cNT) ? (id - cNE) : -1;   // t2c type -> node2
    default: return (id < cNE) ? id
                   : ((id >= cNE + cNT) ? (id - cNT) : -1);            // e2c -> node2
  }
}

__device__ __forceinline__ float blockReduce128(float v, float* sh, int tid) {
  sh[tid] = v; __syncthreads();
  if (tid < 64) sh[tid] += sh[tid + 64]; __syncthreads();
  if (tid < 32) sh[tid] += sh[tid + 32]; __syncthreads();
  if (tid < 16) sh[tid] += sh[tid + 16]; __syncthreads();
  if (tid < 8)  sh[tid] += sh[tid + 8];  __syncthreads();
  if (tid < 4)  sh[tid] += sh[tid + 4];  __syncthreads();
  if (tid < 2)  sh[tid] += sh[tid + 2];  __syncthreads();
  if (tid < 1)  sh[tid] += sh[tid + 1];  __syncthreads();
  float r = sh[0]; __syncthreads();
  return r;
}
__device__ __forceinline__ float blockReduce256(float v, float* sh, int tid) {
  sh[tid] = v; __syncthreads();
  for (int s = 128; s > 0; s >>= 1) {
    if (tid < s) sh[tid] += sh[tid + s];
    __syncthreads();
  }
  float r = sh[0]; __syncthreads();
  return r;
}

// ---------------------------------------------------------------------------
// CSR build: histogram -> block scan -> bsum scan -> add+copy -> fill
// ---------------------------------------------------------------------------
__global__ __launch_bounds__(256) void k_hist(const int* __restrict__ row, int nnz,
                                              int* __restrict__ cnt) {
  int e = blockIdx.x * 256 + threadIdx.x;
  if (e < nnz) atomicAdd(&cnt[row[e]], 1);
}

__global__ __launch_bounds__(256) void k_scan_block(const int* __restrict__ cnt, int n,
                                                    int* __restrict__ excl, int* __restrict__ bsum) {
  __shared__ int sh[256];
  int tid = threadIdx.x;
  int i = blockIdx.x * 256 + tid;
  int v = (i < n) ? cnt[i] : 0;
  sh[tid] = v; __syncthreads();
  for (int off = 1; off < 256; off <<= 1) {
    int t = (tid >= off) ? sh[tid - off] : 0;
    __syncthreads();
    sh[tid] += t;
    __syncthreads();
  }
  if (i < n) excl[i] = sh[tid] - v;
  if (tid == 255) bsum[blockIdx.x] = sh[255];
}

__global__ __launch_bounds__(512) void k_bsum_scan(int* __restrict__ bsum, int nb,
                                                   int* __restrict__ rowptr, int n) {
  __shared__ int sh[512];
  int tid = threadIdx.x;
  int v = (tid < nb) ? bsum[tid] : 0;
  sh[tid] = v; __syncthreads();
  for (int off = 1; off < 512; off <<= 1) {
    int t = (tid >= off) ? sh[tid - off] : 0;
    __syncthreads();
    sh[tid] += t;
    __syncthreads();
  }
  if (tid < nb) bsum[tid] = sh[tid] - v;
  if (tid == 511) rowptr[n] = sh[511];
}

__global__ __launch_bounds__(256) void k_scan_add(int* __restrict__ rowptr,
                                                  const int* __restrict__ bsum, int n,
                                                  int* __restrict__ fill) {
  int i = blockIdx.x * 256 + threadIdx.x;
  if (i < n) {
    int r = rowptr[i] + bsum[blockIdx.x];
    rowptr[i] = r;
    fill[i] = r;
  }
}

__global__ __launch_bounds__(256) void k_fill(const int* __restrict__ row, int nnz,
                                              int* __restrict__ fill, int* __restrict__ eidx) {
  int e = blockIdx.x * 256 + threadIdx.x;
  if (e < nnz) {
    int pos = atomicAdd(&fill[row[e]], 1);
    eidx[pos] = e;
  }
}

// wave-per-row gather: out[r] = sum val[e] * x[col[e]]; x = concat(ea[na], eb)
__global__ __launch_bounds__(256) void k_gather(
    const int* __restrict__ rowptr, const int* __restrict__ eidx,
    const int* __restrict__ col, const float* __restrict__ val,
    const float* __restrict__ ea, const float* __restrict__ eb, int na,
    int nrows, float* __restrict__ out) {
  int r = blockIdx.x * 4 + (threadIdx.x >> 6);
  if (r >= nrows) return;
  int lane = threadIdx.x & 63;
  int p0 = rowptr[r], p1 = rowptr[r + 1];
  float ax = 0.f, ay = 0.f;
  for (int p = p0; p < p1; ++p) {
    int e = eidx[p];
    int c = col[e];
    float v = val[e];
    const float* src = (c < na) ? (ea + (size_t)c * cD) : (eb + (size_t)(c - na) * cD);
    float2 x = *reinterpret_cast<const float2*>(src + lane * 2);
    ax += v * x.x; ay += v * x.y;
  }
  float2 o; o.x = ax; o.y = ay;
  *reinterpret_cast<float2*>(out + (size_t)r * cD + lane * 2) = o;
}

__global__ __launch_bounds__(256) void slot_build(const int* __restrict__ ids,
                                                  int* __restrict__ slot, int mode) {
  int i = blockIdx.x * 256 + threadIdx.x;
  if (i >= cNSRC) return;
  int node = mapNode(mode, ids[i]);
  if (node >= 0) atomicMin(&slot[node], i);
}

__global__ __launch_bounds__(256) void k_rep(const int* __restrict__ ids,
                                             const int* __restrict__ slot, int mode,
                                             int* __restrict__ rep) {
  int i = blockIdx.x * 256 + threadIdx.x;
  if (i >= cNSRC) return;
  int node = mapNode(mode, ids[i]);
  rep[i] = (node >= 0 && slot[node] == i) ? node : -1;
}

// layer-2 gather only at representative slots
__global__ __launch_bounds__(256) void k_gather_slot(
    const int* __restrict__ rowptr, const int* __restrict__ eidx,
    const int* __restrict__ col, const float* __restrict__ val,
    const float* __restrict__ x1, const int* __restrict__ rep,
    float* __restrict__ outc) {
  int i = blockIdx.x * 4 + (threadIdx.x >> 6);
  if (i >= cNSRC) return;
  int r = rep[i];
  if (r < 0) return;
  int lane = threadIdx.x & 63;
  int p0 = rowptr[r], p1 = rowptr[r + 1];
  float ax = 0.f, ay = 0.f;
  for (int p = p0; p < p1; ++p) {
    int e = eidx[p];
    int c = col[e];
    float v = val[e];
    float2 x = *reinterpret_cast<const float2*>(x1 + (size_t)c * cD + lane * 2);
    ax += v * x.x; ay += v * x.y;
  }
  float2 o; o.x = ax; o.y = ay;
  *reinterpret_cast<float2*>(outc + (size_t)i * cD + lane * 2) = o;
}

// (x0 + x1 + x2)/3 at gathered rows -> LayerNorm -> dst
__global__ __launch_bounds__(128) void gather_ln(
    const int* __restrict__ ids, int mode,
    const float* __restrict__ ea, const float* __restrict__ eb, int na,
    const float* __restrict__ x1, const float* __restrict__ x2, const int* __restrict__ slot,
    const float* __restrict__ g, const float* __restrict__ bia, float* __restrict__ dst) {
  __shared__ float sh[128];
  int i = blockIdx.x;
  int tid = threadIdx.x;
  int id = ids[i];
  int node = mapNode(mode, id);
  if (node < 0) return;
  const float* x0 = (node < na) ? (ea + (size_t)node * cD) : (eb + (size_t)(node - na) * cD);
  int xi2 = slot ? slot[node] : node;
  float a = (x0[tid] + x1[(size_t)node * cD + tid] + x2[(size_t)xi2 * cD + tid]) * (1.0f / 3.0f);
  float s  = blockReduce128(a, sh, tid);
  float ss = blockReduce128(a * a, sh, tid);
  float mu = s * (1.0f / 128.0f);
  float var = ss * (1.0f / 128.0f) - mu * mu;
  float y = (a - mu) * rsqrtf(var + 1e-5f) * g[tid] + bia[tid];
  dst[(size_t)i * cD + tid] = y;
}

// ---------------------------------------------------------------------------
// fp32 GEMM (small cl projections only): epi 0=store, 1=store ELU
// ---------------------------------------------------------------------------
__global__ __launch_bounds__(256) void gemm64(
    const float* __restrict__ A, const float* __restrict__ B, float* __restrict__ C,
    int M, int N, int K, const float* __restrict__ bias, int epi) {
  __shared__ __align__(16) float As[16][68];
  __shared__ __align__(16) float Bs[16][68];
  const int bx = blockIdx.x, by = blockIdx.y;
  const int tx = threadIdx.x & 15, ty = threadIdx.x >> 4;
  const int la_r = threadIdx.x >> 2;
  const int la_k = (threadIdx.x & 3) * 4;
  const int lb_k = threadIdx.x >> 4;
  const int lb_c = (threadIdx.x & 15) * 4;
  float acc[4][4] = {};
  for (int kt = 0; kt < K; kt += 16) {
    __syncthreads();
    float4 av = *reinterpret_cast<const float4*>(A + (size_t)(by * 64 + la_r) * K + kt + la_k);
    As[la_k + 0][la_r] = av.x; As[la_k + 1][la_r] = av.y;
    As[la_k + 2][la_r] = av.z; As[la_k + 3][la_r] = av.w;
    *reinterpret_cast<float4*>(&Bs[lb_k][lb_c]) =
        *reinterpret_cast<const float4*>(B + (size_t)(kt + lb_k) * N + bx * 64 + lb_c);
    __syncthreads();
#pragma unroll
    for (int kk = 0; kk < 16; ++kk) {
      float4 a = *reinterpret_cast<const float4*>(&As[kk][ty * 4]);
      float4 b = *reinterpret_cast<const float4*>(&Bs[kk][tx * 4]);
      acc[0][0] += a.x * b.x; acc[0][1] += a.x * b.y; acc[0][2] += a.x * b.z; acc[0][3] += a.x * b.w;
      acc[1][0] += a.y * b.x; acc[1][1] += a.y * b.y; acc[1][2] += a.y * b.z; acc[1][3] += a.y * b.w;
      acc[2][0] += a.z * b.x; acc[2][1] += a.z * b.y; acc[2][2] += a.z * b.z; acc[2][3] += a.z * b.w;
      acc[3][0] += a.w * b.x; acc[3][1] += a.w * b.y; acc[3][2] += a.w * b.z; acc[3][3] += a.w * b.w;
    }
  }
  const int row0 = by * 64 + ty * 4, col0 = bx * 64 + tx * 4;
#pragma unroll
  for (int i = 0; i < 4; ++i)
#pragma unroll
    for (int j = 0; j < 4; ++j) {
      int r = row0 + i, c = col0 + j;
      float v = acc[i][j] + bias[c];
      if (epi == 1) v = (v > 0.0f) ? v : expm1f(v);
      C[(size_t)r * N + c] = v;
    }
}

// ---------------------------------------------------------------------------
// bf16 MFMA GEMM: C[M,N] = A[M,K] @ Bt[N,K]^T, 128x128 tile, 4 waves
// epi 0: Cbf = bf16(acc + bias); epi 1: Cf32 += rowscale[r*4] * (acc + bias)
// ---------------------------------------------------------------------------
__global__ __launch_bounds__(256) void gemm_bf(
    const ushort* __restrict__ A, const ushort* __restrict__ Bt,
    int N, int K, const float* __restrict__ bias,
    ushort* __restrict__ Cbf, float* __restrict__ Cf32,
    const float* __restrict__ rowscale, int epi) {
  __shared__ ushort As[128 * 40];
  __shared__ ushort Bs[128 * 40];
  const int bx = blockIdx.x, by = blockIdx.y;
  const int t = threadIdx.x;
  const int wv = t >> 6, lane = t & 63;
  const int wr = (wv >> 1) * 64, wc = (wv & 1) * 64;
  const int srow = t >> 1, shalf = t & 1;
  const ushort* Ag = A + (size_t)(by * 128 + srow) * K + shalf * 16;
  const ushort* Bg = Bt + (size_t)(bx * 128 + srow) * K + shalf * 16;
  uint4 ra0 = *reinterpret_cast<const uint4*>(Ag);
  uint4 ra1 = *reinterpret_cast<const uint4*>(Ag + 8);
  uint4 rb0 = *reinterpret_cast<const uint4*>(Bg);
  uint4 rb1 = *reinterpret_cast<const uint4*>(Bg + 8);
  f32x4 acc[4][4];
  const f32x4 z4 = {0.f, 0.f, 0.f, 0.f};
#pragma unroll
  for (int i = 0; i < 4; ++i)
#pragma unroll
    for (int j = 0; j < 4; ++j) acc[i][j] = z4;
  const int la = lane & 15, lk = (lane >> 4) * 8;
  const int sdst = srow * 40 + shalf * 16;
  for (int kt = 0; kt < K; kt += 32) {
    __syncthreads();
    *reinterpret_cast<uint4*>(&As[sdst])     = ra0;
    *reinterpret_cast<uint4*>(&As[sdst + 8]) = ra1;
    *reinterpret_cast<uint4*>(&Bs[sdst])     = rb0;
    *reinterpret_cast<uint4*>(&Bs[sdst + 8]) = rb1;
    __syncthreads();
    if (kt + 32 < K) {   // T14-lite: issue next chunk's loads before compute
      ra0 = *reinterpret_cast<const uint4*>(Ag + kt + 32);
      ra1 = *reinterpret_cast<const uint4*>(Ag + kt + 40);
      rb0 = *reinterpret_cast<const uint4*>(Bg + kt + 32);
      rb1 = *reinterpret_cast<const uint4*>(Bg + kt + 40);
    }
    short8v af[4], bfr[4];
#pragma unroll
    for (int i = 0; i < 4; ++i)
      af[i] = *reinterpret_cast<const short8v*>(&As[(wr + i * 16 + la) * 40 + lk]);
#pragma unroll
    for (int j = 0; j < 4; ++j)
      bfr[j] = *reinterpret_cast<const short8v*>(&Bs[(wc + j * 16 + la) * 40 + lk]);
#pragma unroll
    for (int i = 0; i < 4; ++i)
#pragma unroll
      for (int j = 0; j < 4; ++j)
        acc[i][j] = __builtin_amdgcn_mfma_f32_16x16x32_bf16(af[i], bfr[j], acc[i][j], 0, 0, 0);
  }
  const int r0 = by * 128 + wr + (lane >> 4) * 4;
  const int c0 = bx * 128 + wc + la;
#pragma unroll
  for (int i = 0; i < 4; ++i)
#pragma unroll
    for (int j = 0; j < 4; ++j) {
      int c = c0 + j * 16;
      float bv = bias[c];
#pragma unroll
      for (int q = 0; q < 4; ++q) {
        int r = r0 + i * 16 + q;
        float v = acc[i][j][q] + bv;
        size_t idx = (size_t)r * N + c;
        if (epi == 0) Cbf[idx] = f2bf(v);
        else Cf32[idx] += rowscale[(size_t)r * 4] * v;
      }
    }
}

// ---------------------------------------------------------------------------
// Gram contrastive kernel: G = W @ W^T (8192x8192, K=128), fused exp(2x),
// per-row half-sums into rsum[2][8192], diag captures d11/d12/d22.
// ---------------------------------------------------------------------------
__global__ __launch_bounds__(256) void gram_cl(
    const ushort* __restrict__ W, float* __restrict__ rsum,
    float* __restrict__ d11, float* __restrict__ d12, float* __restrict__ d22) {
  __shared__ ushort As[128 * 40];
  __shared__ ushort Bs[128 * 40];
  const int bx = blockIdx.x, by = blockIdx.y;
  const int t = threadIdx.x;
  const int wv = t >> 6, lane = t & 63;
  const int wr = (wv >> 1) * 64, wc = (wv & 1) * 64;
  const int srow = t >> 1, shalf = t & 1;
  const ushort* Ag = W + (size_t)(by * 128 + srow) * 128 + shalf * 16;
  const ushort* Bg = W + (size_t)(bx * 128 + srow) * 128 + shalf * 16;
  uint4 ra0 = *reinterpret_cast<const uint4*>(Ag);
  uint4 ra1 = *reinterpret_cast<const uint4*>(Ag + 8);
  uint4 rb0 = *reinterpret_cast<const uint4*>(Bg);
  uint4 rb1 = *reinterpret_cast<const uint4*>(Bg + 8);
  f32x4 acc[4][4];
  const f32x4 z4 = {0.f, 0.f, 0.f, 0.f};
#pragma unroll
  for (int i = 0; i < 4; ++i)
#pragma unroll
    for (int j = 0; j < 4; ++j) acc[i][j] = z4;
  const int la = lane & 15, lk = (lane >> 4) * 8;
  const int sdst = srow * 40 + shalf * 16;
  for (int kt = 0; kt < 128; kt += 32) {
    __syncthreads();
    *reinterpret_cast<uint4*>(&As[sdst])     = ra0;
    *reinterpret_cast<uint4*>(&As[sdst + 8]) = ra1;
    *reinterpret_cast<uint4*>(&Bs[sdst])     = rb0;
    *reinterpret_cast<uint4*>(&Bs[sdst + 8]) = rb1;
    __syncthreads();
    if (kt + 32 < 128) {
      ra0 = *reinterpret_cast<const uint4*>(Ag + kt + 32);
      ra1 = *reinterpret_cast<const uint4*>(Ag + kt + 40);
      rb0 = *reinterpret_cast<const uint4*>(Bg + kt + 32);
      rb1 = *reinterpret_cast<const uint4*>(Bg + kt + 40);
    }
    short8v af[4], bfr[4];
#pragma unroll
    for (int i = 0; i < 4; ++i)
      af[i] = *reinterpret_cast<const short8v*>(&As[(wr + i * 16 + la) * 40 + lk]);
#pragma unroll
    for (int j = 0; j < 4; ++j)
      bfr[j] = *reinterpret_cast<const short8v*>(&Bs[(wc + j * 16 + la) * 40 + lk]);
#pragma unroll
    for (int i = 0; i < 4; ++i)
#pragma unroll
      for (int j = 0; j < 4; ++j)
        acc[i][j] = __builtin_amdgcn_mfma_f32_16x16x32_bf16(af[i], bfr[j], acc[i][j], 0, 0, 0);
  }
  const int r0 = by * 128 + wr + (lane >> 4) * 4;
  const int c0 = bx * 128 + wc + la;
  float rs[4][4];
#pragma unroll
  for (int i = 0; i < 4; ++i)
#pragma unroll
    for (int q = 0; q < 4; ++q) rs[i][q] = 0.f;
#pragma unroll
  for (int i = 0; i < 4; ++i)
#pragma unroll
    for (int j = 0; j < 4; ++j)
#pragma unroll
      for (int q = 0; q < 4; ++q) {
        int r = r0 + i * 16 + q;
        int c = c0 + j * 16;
        float e = expf(2.0f * acc[i][j][q]);
        rs[i][q] += e;
        if (c == r)        { if (r < 4096) d11[r] = e; else d22[r - 4096] = e; }
        if (c == r + 4096) d12[r] = e;
      }
  // reduce across the 16-lane column group (la = lane&15)
#pragma unroll
  for (int m = 1; m < 16; m <<= 1)
#pragma unroll
    for (int i = 0; i < 4; ++i)
#pragma unroll
      for (int q = 0; q < 4; ++q) rs[i][q] += __shfl_xor(rs[i][q], m);
  if (la == 0) {
    float* dst = rsum + (bx < 32 ? 0 : 8192);
#pragma unroll
    for (int i = 0; i < 4; ++i)
#pragma unroll
      for (int q = 0; q < 4; ++q) atomAdd(&dst[r0 + i * 16 + q], rs[i][q]);
  }
}

// per-row loss from rsum/diag -> atomicAdd scalar
__global__ __launch_bounds__(256) void cl_row(
    const float* __restrict__ rsum, const float* __restrict__ d11,
    const float* __restrict__ d12, const float* __restrict__ d22,
    float* __restrict__ cl_sum) {
  __shared__ float sh[256];
  int i = blockIdx.x * 256 + threadIdx.x;   // 4096 total
  float denA = rsum[i] + rsum[8192 + i] - d11[i];
  float denB = rsum[8192 + 4096 + i] + rsum[4096 + i] - d22[i];
  float l = 0.5f * (logf(denA) + logf(denB)) - logf(d12[i]);
  float s = blockReduce256(l, sh, threadIdx.x);
  if (threadIdx.x == 0) atomAdd(cl_sum, s);
}

// weight transpose + bf16 convert: Bt[n*K+k] = bf16(W[k*N+n])
__global__ __launch_bounds__(256) void k_wt_bt(const float* __restrict__ W,
                                               ushort* __restrict__ Bt, int K, int N) {
  __shared__ float tile[32][33];
  int n0 = blockIdx.x * 32, k0 = blockIdx.y * 32;
  int tx = threadIdx.x & 31, ty = threadIdx.x >> 5;
#pragma unroll
  for (int i = 0; i < 4; ++i)
    tile[ty + 8 * i][tx] = W[(size_t)(k0 + ty + 8 * i) * N + n0 + tx];
  __syncthreads();
#pragma unroll
  for (int i = 0; i < 4; ++i)
    Bt[(size_t)(n0 + ty + 8 * i) * K + k0 + tx] = f2bf(tile[tx][ty + 8 * i]);
}

// ---------------------------------------------------------------------------
// rownorm -> bf16 into W
// ---------------------------------------------------------------------------
__global__ __launch_bounds__(128) void rownorm_bf(const float* __restrict__ z,
                                                  ushort* __restrict__ w) {
  __shared__ float sh[128];
  int i = blockIdx.x, tid = threadIdx.x;
  float v = z[(size_t)i * cD + tid];
  float ss = blockReduce128(v * v, sh, tid);
  float n = fmaxf(sqrtf(ss), 1e-12f);
  w[(size_t)i * cD + tid] = f2bf(v / n);
}

// ---------------------------------------------------------------------------
// message / losses / MHA / MoE
// ---------------------------------------------------------------------------
__global__ __launch_bounds__(256) void emb_sum_k(
    const float* __restrict__ s1, const float* __restrict__ s2,
    const float* __restrict__ relation, const int* __restrict__ etype, float* __restrict__ out) {
  __shared__ float sh[256];
  int idx = blockIdx.x * 256 + threadIdx.x;
  int i = idx >> 8, j = idx & 255;
  float a = (j < 128) ? s1[(size_t)i * 128 + j] : s2[(size_t)i * 128 + j - 128];
  int et = etype[i];
  float r = relation[(size_t)(et % cNR) * 256 + j];
  float t = blockReduce256(a * a + r * r, sh, threadIdx.x);
  if (threadIdx.x == 0) atomAdd(out, t);
}

__global__ __launch_bounds__(256) void msg_build(
    const float* __restrict__ s1, const float* __restrict__ s2,
    const float* __restrict__ relation, const int* __restrict__ etype,
    ushort* __restrict__ msg) {
  int idx = blockIdx.x * 256 + threadIdx.x;
  int i = idx >> 8, j = idx & 255;
  int et = etype[i];
  float sign = (et >= cNR) ? -1.0f : 1.0f;
  float r = relation[(size_t)(et % cNR) * 256 + j] * sign;
  float s = (j < 128) ? s1[(size_t)i * 128 + j] : s2[(size_t)i * 128 + j - 128];
  msg[idx] = f2bf(fmaxf(s + r, 0.0f));
}

__global__ __launch_bounds__(64) void mha_attn(
    const ushort* __restrict__ q, const ushort* __restrict__ k,
    const ushort* __restrict__ v, ushort* __restrict__ o) {
  __shared__ float qs[8][128], ks[8][128], vs[8][128], att[8][8];
  int bh = blockIdx.x;
  int b = bh >> 3, h = bh & 7;
  int tid = threadIdx.x;
  for (int idx = tid; idx < 1024; idx += 64) {
    int l = idx >> 7, d = idx & 127;
    size_t src = (size_t)(b * 8 + l) * cT + h * 128 + d;
    qs[l][d] = bf2f(q[src]); ks[l][d] = bf2f(k[src]); vs[l][d] = bf2f(v[src]);
  }
  __syncthreads();
  int l = tid >> 3, m = tid & 7;
  float s = 0;
#pragma unroll 16
  for (int d = 0; d < 128; ++d) s += qs[l][d] * ks[m][d];
  s *= 0.08838834764831845f;
  float mx = s;
  for (int off = 1; off < 8; off <<= 1) mx = fmaxf(mx, __shfl_xor(mx, off, 8));
  float p = expf(s - mx);
  float sum = p;
  for (int off = 1; off < 8; off <<= 1) sum += __shfl_xor(sum, off, 8);
  att[l][m] = p / sum;
  __syncthreads();
  for (int idx = tid; idx < 1024; idx += 64) {
    int ll = idx >> 7, d = idx & 127;
    float acc = 0;
#pragma unroll
    for (int mm = 0; mm < 8; ++mm) acc += att[ll][mm] * vs[mm][d];
    o[(size_t)(b * 8 + ll) * cT + h * 128 + d] = f2bf(acc);
  }
}

__global__ __launch_bounds__(64) void gate_k(
    const ushort* __restrict__ o, const float* __restrict__ gw, float* __restrict__ gate) {
  int i = blockIdx.x;
  int lane = threadIdx.x;
  float g[4] = {0, 0, 0, 0};
  for (int d = lane; d < cT; d += 64) {
    float ov = bf2f(o[(size_t)i * cT + d]);
    g[0] += ov * gw[d * 4 + 0];
    g[1] += ov * gw[d * 4 + 1];
    g[2] += ov * gw[d * 4 + 2];
    g[3] += ov * gw[d * 4 + 3];
  }
#pragma unroll
  for (int off = 32; off > 0; off >>= 1)
#pragma unroll
    for (int e = 0; e < 4; ++e) g[e] += __shfl_down(g[e], off);
  if (lane == 0) {
    float mx = fmaxf(fmaxf(g[0], g[1]), fmaxf(g[2], g[3]));
    float ex[4], sum = 0;
#pragma unroll
    for (int e = 0; e < 4; ++e) { ex[e] = expf(g[e] - mx); sum += ex[e]; }
#pragma unroll
    for (int e = 0; e < 4; ++e) gate[(size_t)i * 4 + e] = ex[e] / sum;
  }
}

__global__ __launch_bounds__(256) void mean_sigmoid(
    const float* __restrict__ moe, float* __restrict__ out) {
  int idx = blockIdx.x * 256 + threadIdx.x;
  int b = idx >> 10, t = idx & 1023;
  float s = 0;
#pragma unroll
  for (int l = 0; l < 8; ++l) s += moe[(size_t)(b * 8 + l) * cT + t];
  s *= (1.0f / 8.0f);
  out[idx] = 1.0f / (1.0f + expf(-s));
}

__global__ void finalize_k(const float* __restrict__ scal, float* __restrict__ out_aux) {
  float cl = scal[0] * (1.0f / cNSRC);
  float emb = cDECAY * 0.5f * scal[1] * (1.0f / cNSRC);
  out_aux[0] = cCLW * cl + emb;
}

// ---------------------------------------------------------------------------
// Launch
// ---------------------------------------------------------------------------
extern "C" void kernel_launch(void* const* d_in, const int* in_sizes, int n_in,
                              void* d_out, int out_size, void* d_ws, size_t ws_size,
                              hipStream_t stream) {
  (void)in_sizes; (void)n_in; (void)out_size; (void)ws_size;
  const float* entity   = (const float*)d_in[0];
  const float* type_e   = (const float*)d_in[1];
  const float* cluster  = (const float*)d_in[2];
  const float* relation = (const float*)d_in[3];
  const float* ln_g  = (const float*)d_in[4];
  const float* ln_b  = (const float*)d_in[5];
  const float* cl_w1 = (const float*)d_in[6];
  const float* cl_b1 = (const float*)d_in[7];
  const float* cl_w2 = (const float*)d_in[8];
  const float* cl_b2 = (const float*)d_in[9];
  const float* fc_w  = (const float*)d_in[10];
  const float* fc_b  = (const float*)d_in[11];
  const float* wq = (const float*)d_in[12];
  const float* bq = (const float*)d_in[13];
  const float* wk = (const float*)d_in[14];
  const float* bk = (const float*)d_in[15];
  const float* wv = (const float*)d_in[16];
  const float* bv = (const float*)d_in[17];
  const float* wo = (const float*)d_in[18];
  const float* bo = (const float*)d_in[19];
  const float* gate_w = (const float*)d_in[20];
  const float* exp_w  = (const float*)d_in[21];
  const float* exp_b  = (const float*)d_in[22];
  const float* e2t_val = (const float*)d_in[23];
  const float* t2c_val = (const float*)d_in[24];
  const float* e2c_val = (const float*)d_in[25];
  const int* e2t_row = (const int*)d_in[26];
  const int* e2t_col = (const int*)d_in[27];
  const int* t2c_row = (const int*)d_in[28];
  const int* t2c_col = (const int*)d_in[29];
  const int* e2c_row = (const int*)d_in[30];
  const int* e2c_col = (const int*)d_in[31];
  const int* src_ids = (const int*)d_in[32];
  const int* etype   = (const int*)d_in[33];

  float* ws = (float*)d_ws;
  float* S1 = ws + F_S1;
  float* S2 = ws + F_S2;
  float* PT = ws + F_PT;
  float* Z1 = ws + F_Z1;
  float* Z2 = ws + F_Z2;
  ushort* MSGbf = (ushort*)(ws + F_MSG);
  float* GATE = ws + F_GATE;
  float* SCAL = ws + F_SCAL;
  float* RS   = ws + F_RS;
  float* D11  = ws + F_D11;
  float* D12  = ws + F_D12;
  float* D22  = ws + F_D22;
  ushort* Wbf = (ushort*)(ws + F_PT);   // W reuses PT (dead after projections)
  float* X1F  = ws + G_X1F;
  float* X2C  = ws + G_X2C;
  int*   SLOT = (int*)(ws + G_SLOT);
  int*   REP  = (int*)(ws + G_REP);
  int*   RP   = (int*)(ws + G_RP);
  int*   FILL = (int*)(ws + G_FILL);
  int*   EIDX = (int*)(ws + G_EIDX);
  float* X1T  = ws + G_X1T;
  float* X2T  = ws + G_X2T;
  int*   BSUM = (int*)(ws + G_BSUM);
  ushort* PB  = (ushort*)(ws + A_U0);   // predict, later attn-out
  ushort* QB  = (ushort*)(ws + A_U1);
  ushort* KB  = (ushort*)(ws + A_U2);   // later o-proj out
  ushort* VB  = (ushort*)(ws + A_U3);
  ushort* WBT = (ushort*)(ws + A_WBT);
  float*  MOE = ws + A_U0;              // f32, spans U0+U1

  hipMemsetAsync(SCAL, 0, 2 * sizeof(float), stream);
  hipMemsetAsync(RS, 0, (16384 + 3 * 4096) * sizeof(float), stream);

  // ================= GCN via CSR gather =================
  auto run_gcn = [&](const int* row, const int* col, const float* val, int nnz, int nn,
                     const float* ea, const float* eb, int na, float* x1out) {
    int nb = (nn + 255) / 256;
    int gEdge = (nnz + 255) / 256;
    hipMemsetAsync(FILL, 0, (size_t)nn * sizeof(int), stream);
    k_hist<<<gEdge, 256, 0, stream>>>(row, nnz, FILL);
    k_scan_block<<<nb, 256, 0, stream>>>(FILL, nn, RP, BSUM);
    k_bsum_scan<<<1, 512, 0, stream>>>(BSUM, nb, RP, nn);
    k_scan_add<<<nb, 256, 0, stream>>>(RP, BSUM, nn, FILL);
    k_fill<<<gEdge, 256, 0, stream>>>(row, nnz, FILL, EIDX);
    k_gather<<<(nn + 3) / 4, 256, 0, stream>>>(RP, EIDX, col, val, ea, eb, na, nn, x1out);
  };

  // ---- e2t: layer1 full, layer2 at slots, LN -> S1 (mode 0) ----
  run_gcn(e2t_row, e2t_col, e2t_val, cNNZ_E2T, cNN_E2T, entity, type_e, cNE, X1F);
  hipMemsetAsync(SLOT, 0x7F, (size_t)cNN_E2T * sizeof(int), stream);
  slot_build<<<16, 256, 0, stream>>>(src_ids, SLOT, 0);
  k_rep<<<16, 256, 0, stream>>>(src_ids, SLOT, 0, REP);
  k_gather_slot<<<cNSRC / 4, 256, 0, stream>>>(RP, EIDX, e2t_col, e2t_val, X1F, REP, X2C);
  gather_ln<<<cNSRC, 128, 0, stream>>>(src_ids, 0, entity, type_e, cNE, X1F, X2C, SLOT,
                                       ln_g, ln_b, S1);

  // ---- e2c: layer1 full, layer2 at slots, LN -> S2 (mode 3) ----
  run_gcn(e2c_row, e2c_col, e2c_val, cNNZ_E2C, cNN_E2C, entity, cluster, cNE, X1F);
  hipMemsetAsync(SLOT, 0x7F, (size_t)cNN_E2C * sizeof(int), stream);
  slot_build<<<16, 256, 0, stream>>>(src_ids, SLOT, 3);
  k_rep<<<16, 256, 0, stream>>>(src_ids, SLOT, 3, REP);
  k_gather_slot<<<cNSRC / 4, 256, 0, stream>>>(RP, EIDX, e2c_col, e2c_val, X1F, REP, X2C);
  gather_ln<<<cNSRC, 128, 0, stream>>>(src_ids, 3, entity, cluster, cNE, X1F, X2C, SLOT,
                                       ln_g, ln_b, S2);

  // ---- t2c: tiny, both layers full ----
  run_gcn(t2c_row, t2c_col, t2c_val, cNNZ_T2C, cNN_T2C, type_e, cluster, cNT, X1T);
  k_gather<<<(cNN_T2C + 3) / 4, 256, 0, stream>>>(RP, EIDX, t2c_col, t2c_val,
                                                  X1T, X1T, 1 << 30, cNN_T2C, X2T);
  gather_ln<<<cNSRC, 128, 0, stream>>>(src_ids, 1, type_e, cluster, cNT, X1T, X2T, nullptr,
                                       ln_g, ln_b, S1);
  gather_ln<<<cNSRC, 128, 0, stream>>>(src_ids, 2, type_e, cluster, cNT, X1T, X2T, nullptr,
                                       ln_g, ln_b, S2);

  // ================= contrastive loss =================
  dim3 g128(cD / 64, cNSRC / 64);
  gemm64<<<g128, 256, 0, stream>>>(S1, cl_w1, PT, cNSRC, cD, cD, cl_b1, 1);
  gemm64<<<g128, 256, 0, stream>>>(PT, cl_w2, Z1, cNSRC, cD, cD, cl_b2, 0);
  gemm64<<<g128, 256, 0, stream>>>(S2, cl_w1, PT, cNSRC, cD, cD, cl_b1, 1);
  gemm64<<<g128, 256, 0, stream>>>(PT, cl_w2, Z2, cNSRC, cD, cD, cl_b2, 0);
  rownorm_bf<<<cNSRC, 128, 0, stream>>>(Z1, Wbf);                      // rows 0..4095
  rownorm_bf<<<cNSRC, 128, 0, stream>>>(Z2, Wbf + (size_t)cNSRC * cD); // rows 4096..8191
  gram_cl<<<dim3(64, 64), 256, 0, stream>>>(Wbf, RS, D11, D12, D22);
  cl_row<<<16, 256, 0, stream>>>(RS, D11, D12, D22, SCAL);
  emb_sum_k<<<cNSRC, 256, 0, stream>>>(S1, S2, relation, etype, SCAL + 1);

  // ================= message + predict (bf16 MFMA) =================
  msg_build<<<cNSRC, 256, 0, stream>>>(S1, S2, relation, etype, MSGbf);
  dim3 gBF(cT / 128, cNSRC / 128);
  k_wt_bt<<<dim3(cT / 32, 256 / 32), 256, 0, stream>>>(fc_w, WBT, 256, cT);
  gemm_bf<<<gBF, 256, 0, stream>>>(MSGbf, WBT, cT, 256, fc_b, PB, nullptr, nullptr, 0);

  // ================= MHA =================
  k_wt_bt<<<dim3(cT / 32, cT / 32), 256, 0, stream>>>(wq, WBT, cT, cT);
  gemm_bf<<<gBF, 256, 0, stream>>>(PB, WBT, cT, cT, bq, QB, nullptr, nullptr, 0);
  k_wt_bt<<<dim3(cT / 32, cT / 32), 256, 0, stream>>>(wk, WBT, cT, cT);
  gemm_bf<<<gBF, 256, 0, stream>>>(PB, WBT, cT, cT, bk, KB, nullptr, nullptr, 0);
  k_wt_bt<<<dim3(cT / 32, cT / 32), 256, 0, stream>>>(wv, WBT, cT, cT);
  gemm_bf<<<gBF, 256, 0, stream>>>(PB, WBT, cT, cT, bv, VB, nullptr, nullptr, 0);
  mha_attn<<<cB * 8, 64, 0, stream>>>(QB, KB, VB, PB);            // attn-out -> U0
  k_wt_bt<<<dim3(cT / 32, cT / 32), 256, 0, stream>>>(wo, WBT, cT, cT);
  gemm_bf<<<gBF, 256, 0, stream>>>(PB, WBT, cT, cT, bo, KB, nullptr, nullptr, 0);  // o -> U2

  // ================= MoE =================
  gate_k<<<cNSRC, 64, 0, stream>>>(KB, gate_w, GATE);
  hipMemsetAsync(MOE, 0, (size_t)cNSRC * cT * sizeof(float), stream);
  for (int e = 0; e < cE; ++e) {
    k_wt_bt<<<dim3(cT / 32, cT / 32), 256, 0, stream>>>(exp_w + (size_t)e * cT * cT, WBT, cT, cT);
    gemm_bf<<<gBF, 256, 0, stream>>>(KB, WBT, cT, cT, exp_b + (size_t)e * cT,
                                     nullptr, MOE, GATE + e, 1);
  }

  // ================= output =================
  mean_sigmoid<<<(cB * cT) / 256, 256, 0, stream>>>(MOE, (float*)d_out);
  finalize_k<<<1, 1, 0, stream>>>(SCAL, (float*)d_out + (size_t)cB * cT);
}

// Round 4
// 727.566 us; speedup vs baseline: 7.5386x; 1.5185x over previous
//
#include <hip/hip_runtime.h>
#include <hip/hip_bf16.h>
#include <cmath>

// ---------------------------------------------------------------------------
// Problem constants (fixed shapes)
// ---------------------------------------------------------------------------
constexpr int cNE = 100000, cNT = 1024, cNC = 128, cD = 128, cNR = 500;
constexpr int cB = 512, cNSRC = 4096, cT = 1024, cE = 4;
constexpr int cNNZ_E2T = 1000000, cNNZ_T2C = 50000, cNNZ_E2C = 500000;
constexpr float cDECAY = 1e-4f, cCLW = 0.1f;
constexpr int cNN_E2T = cNE + cNT;     // 101024
constexpr int cNN_E2C = cNE + cNC;     // 100128
constexpr int cNN_T2C = cNT + cNC;     // 1152

// ---------------------------------------------------------------------------
// Workspace layout (all offsets in FLOAT units)
// ---------------------------------------------------------------------------
constexpr size_t F_S1   = 0;                          // f32 4096x128
constexpr size_t F_S2   = F_S1 + 524288;
constexpr size_t F_PT   = F_S2 + 524288;              // proj tmp; later W bf16 [8192][128]
constexpr size_t F_Z1   = F_PT + 524288;
constexpr size_t F_Z2   = F_Z1 + 524288;
constexpr size_t F_MSG  = F_Z2 + 524288;              // bf16 4096x256
constexpr size_t F_GATE = F_MSG + 524288;             // f32 4096x4
constexpr size_t F_SCAL = F_GATE + 16384;
constexpr size_t F_RS   = F_SCAL + 64;                // f32 [2][8192] gram row sums
constexpr size_t F_D11  = F_RS + 16384;               // f32 [4096]
constexpr size_t F_D12  = F_D11 + 4096;
constexpr size_t F_D22  = F_D12 + 4096;
constexpr size_t F_U    = F_D22 + 4096;               // union region base
// --- GCN phase members of the union ---
constexpr size_t G_X1F  = F_U;                        // f32 101024x128
constexpr size_t G_X2C  = G_X1F + 12931072;           // f32 4096x128 (also MARK int[101376])
constexpr size_t G_SLOT = G_X2C + 524288;             // int[101376]
constexpr size_t G_REP  = G_SLOT + 101376;            // int[4096]
constexpr size_t G_RP   = G_REP + 4096;               // int[101376] rowptr
constexpr size_t G_FILL = G_RP + 101376;              // int[101376] cnt/fill
constexpr size_t G_EIDX = G_FILL + 101376;            // int[1000000]
constexpr size_t G_X1T  = G_EIDX + 1000000;           // f32 1152x128
constexpr size_t G_X2T  = G_X1T + 147456;             // f32 1152x128
constexpr size_t G_BSUM = G_X2T + 147456;             // int[512]
// --- activation phase members (bf16 buffers 4096x1024 = 2,097,152 fl) ---
constexpr size_t A_U0  = F_U;                 // P, then attn-out
constexpr size_t A_U1  = F_U + 2097152;       // Q
constexpr size_t A_U2  = F_U + 2 * 2097152;   // K, then o-proj out O
constexpr size_t A_U3  = F_U + 3 * 2097152;   // V
constexpr size_t A_WBT = F_U + 4 * 2097152;   // bf16 weight^T scratch (4 experts: 2M ushort)

typedef __attribute__((ext_vector_type(8))) short short8v;
typedef __attribute__((ext_vector_type(4))) float f32x4;

// ---------------------------------------------------------------------------
// Helpers
// ---------------------------------------------------------------------------
__device__ __forceinline__ void atomAdd(float* p, float v) {
  __hip_atomic_fetch_add(p, v, __ATOMIC_RELAXED, __HIP_MEMORY_SCOPE_AGENT);
}
__device__ __forceinline__ ushort f2bf(float f) {
  __hip_bfloat16 h = __float2bfloat16(f);
  return *reinterpret_cast<ushort*>(&h);
}
__device__ __forceinline__ float bf2f(ushort u) {
  __hip_bfloat16 h; *reinterpret_cast<ushort*>(&h) = u;
  return __bfloat162float(h);
}

__device__ __forceinline__ int mapNode(int mode, int id) {
  switch (mode) {
    case 0:  return (id < cNE + cNT) ? id : -1;                        // e2t -> node1
    case 1:  return (id >= cNE + cNT) ? (id - cNE) : -1;               // t2c cluster -> node1
    case 2:  return (id >= cNE && id < cNE + cNT) ? (id - cNE) : -1;   // t2c type -> node2
    default: return (id < cNE) ? id
                   : ((id >= cNE + cNT) ? (id - cNT) : -1);            // e2c -> node2
  }
}

__device__ __forceinline__ float blockReduce128(float v, float* sh, int tid) {
  sh[tid] = v; __syncthreads();
  if (tid < 64) sh[tid] += sh[tid + 64]; __syncthreads();
  if (tid < 32) sh[tid] += sh[tid + 32]; __syncthreads();
  if (tid < 16) sh[tid] += sh[tid + 16]; __syncthreads();
  if (tid < 8)  sh[tid] += sh[tid + 8];  __syncthreads();
  if (tid < 4)  sh[tid] += sh[tid + 4];  __syncthreads();
  if (tid < 2)  sh[tid] += sh[tid + 2];  __syncthreads();
  if (tid < 1)  sh[tid] += sh[tid + 1];  __syncthreads();
  float r = sh[0]; __syncthreads();
  return r;
}
__device__ __forceinline__ float blockReduce256(float v, float* sh, int tid) {
  sh[tid] = v; __syncthreads();
  for (int s = 128; s > 0; s >>= 1) {
    if (tid < s) sh[tid] += sh[tid + s];
    __syncthreads();
  }
  float r = sh[0]; __syncthreads();
  return r;
}

// ---------------------------------------------------------------------------
// mask + CSR build
// ---------------------------------------------------------------------------
__global__ __launch_bounds__(256) void slot_build(const int* __restrict__ ids,
                                                  int* __restrict__ slot, int mode) {
  int i = blockIdx.x * 256 + threadIdx.x;
  if (i >= cNSRC) return;
  int node = mapNode(mode, ids[i]);
  if (node >= 0) atomicMin(&slot[node], i);
}

__global__ __launch_bounds__(256) void k_mark_nodes(const int* __restrict__ ids,
                                                    int* __restrict__ mark, int mode) {
  int i = blockIdx.x * 256 + threadIdx.x;
  if (i >= cNSRC) return;
  int node = mapNode(mode, ids[i]);
  if (node >= 0) mark[node] = 1;
}

// mark all columns of rows that are gathered nodes (slot[row] < NSRC)
__global__ __launch_bounds__(256) void k_mark_edges(const int* __restrict__ row,
                                                    const int* __restrict__ col, int nnz,
                                                    const int* __restrict__ slot,
                                                    int* __restrict__ mark) {
  int e = blockIdx.x * 256 + threadIdx.x;
  if (e >= nnz) return;
  int r = row[e];
  if (slot[r] < cNSRC) mark[col[e]] = 1;
}

__global__ __launch_bounds__(256) void k_hist(const int* __restrict__ row, int nnz,
                                              const int* __restrict__ mark,
                                              int* __restrict__ cnt) {
  int e = blockIdx.x * 256 + threadIdx.x;
  if (e >= nnz) return;
  int r = row[e];
  if (mark && !mark[r]) return;
  atomicAdd(&cnt[r], 1);
}

__global__ __launch_bounds__(256) void k_scan_block(const int* __restrict__ cnt, int n,
                                                    int* __restrict__ excl, int* __restrict__ bsum) {
  __shared__ int sh[256];
  int tid = threadIdx.x;
  int i = blockIdx.x * 256 + tid;
  int v = (i < n) ? cnt[i] : 0;
  sh[tid] = v; __syncthreads();
  for (int off = 1; off < 256; off <<= 1) {
    int t = (tid >= off) ? sh[tid - off] : 0;
    __syncthreads();
    sh[tid] += t;
    __syncthreads();
  }
  if (i < n) excl[i] = sh[tid] - v;
  if (tid == 255) bsum[blockIdx.x] = sh[255];
}

__global__ __launch_bounds__(512) void k_bsum_scan(int* __restrict__ bsum, int nb,
                                                   int* __restrict__ rowptr, int n) {
  __shared__ int sh[512];
  int tid = threadIdx.x;
  int v = (tid < nb) ? bsum[tid] : 0;
  sh[tid] = v; __syncthreads();
  for (int off = 1; off < 512; off <<= 1) {
    int t = (tid >= off) ? sh[tid - off] : 0;
    __syncthreads();
    sh[tid] += t;
    __syncthreads();
  }
  if (tid < nb) bsum[tid] = sh[tid] - v;
  if (tid == 511) rowptr[n] = sh[511];
}

__global__ __launch_bounds__(256) void k_scan_add(int* __restrict__ rowptr,
                                                  const int* __restrict__ bsum, int n,
                                                  int* __restrict__ fill) {
  int i = blockIdx.x * 256 + threadIdx.x;
  if (i < n) {
    int r = rowptr[i] + bsum[blockIdx.x];
    rowptr[i] = r;
    fill[i] = r;
  }
}

__global__ __launch_bounds__(256) void k_fill(const int* __restrict__ row, int nnz,
                                              const int* __restrict__ mark,
                                              int* __restrict__ fill, int* __restrict__ eidx) {
  int e = blockIdx.x * 256 + threadIdx.x;
  if (e >= nnz) return;
  int r = row[e];
  if (mark && !mark[r]) return;
  int pos = atomicAdd(&fill[r], 1);
  eidx[pos] = e;
}

// wave-per-row gather (2-wide unrolled): out[r] = sum val[e] * x[col[e]]
__global__ __launch_bounds__(256) void k_gather(
    const int* __restrict__ rowptr, const int* __restrict__ eidx,
    const int* __restrict__ col, const float* __restrict__ val,
    const float* __restrict__ ea, const float* __restrict__ eb, int na,
    int nrows, const int* __restrict__ mark, float* __restrict__ out) {
  int r = blockIdx.x * 4 + (threadIdx.x >> 6);
  if (r >= nrows) return;
  if (mark && !mark[r]) return;
  int lane = threadIdx.x & 63;
  int p0 = rowptr[r], p1 = rowptr[r + 1];
  float ax = 0.f, ay = 0.f;
  int p = p0;
  for (; p + 2 <= p1; p += 2) {
    int e0 = eidx[p], e1 = eidx[p + 1];
    int c0 = col[e0], c1 = col[e1];
    float v0 = val[e0], v1 = val[e1];
    const float* s0 = (c0 < na) ? (ea + (size_t)c0 * cD) : (eb + (size_t)(c0 - na) * cD);
    const float* s1 = (c1 < na) ? (ea + (size_t)c1 * cD) : (eb + (size_t)(c1 - na) * cD);
    float2 x0 = *reinterpret_cast<const float2*>(s0 + lane * 2);
    float2 x1 = *reinterpret_cast<const float2*>(s1 + lane * 2);
    ax += v0 * x0.x + v1 * x1.x;
    ay += v0 * x0.y + v1 * x1.y;
  }
  if (p < p1) {
    int e = eidx[p];
    int c = col[e];
    float v = val[e];
    const float* s = (c < na) ? (ea + (size_t)c * cD) : (eb + (size_t)(c - na) * cD);
    float2 x = *reinterpret_cast<const float2*>(s + lane * 2);
    ax += v * x.x; ay += v * x.y;
  }
  float2 o; o.x = ax; o.y = ay;
  *reinterpret_cast<float2*>(out + (size_t)r * cD + lane * 2) = o;
}

__global__ __launch_bounds__(256) void k_rep(const int* __restrict__ ids,
                                             const int* __restrict__ slot, int mode,
                                             int* __restrict__ rep) {
  int i = blockIdx.x * 256 + threadIdx.x;
  if (i >= cNSRC) return;
  int node = mapNode(mode, ids[i]);
  rep[i] = (node >= 0 && slot[node] == i) ? node : -1;
}

// layer-2 gather only at representative slots (2-wide unrolled)
__global__ __launch_bounds__(256) void k_gather_slot(
    const int* __restrict__ rowptr, const int* __restrict__ eidx,
    const int* __restrict__ col, const float* __restrict__ val,
    const float* __restrict__ x1, const int* __restrict__ rep,
    float* __restrict__ outc) {
  int i = blockIdx.x * 4 + (threadIdx.x >> 6);
  if (i >= cNSRC) return;
  int r = rep[i];
  if (r < 0) return;
  int lane = threadIdx.x & 63;
  int p0 = rowptr[r], p1 = rowptr[r + 1];
  float ax = 0.f, ay = 0.f;
  int p = p0;
  for (; p + 2 <= p1; p += 2) {
    int e0 = eidx[p], e1 = eidx[p + 1];
    int c0 = col[e0], c1 = col[e1];
    float v0 = val[e0], v1 = val[e1];
    float2 x0 = *reinterpret_cast<const float2*>(x1 + (size_t)c0 * cD + lane * 2);
    float2 x1v = *reinterpret_cast<const float2*>(x1 + (size_t)c1 * cD + lane * 2);
    ax += v0 * x0.x + v1 * x1v.x;
    ay += v0 * x0.y + v1 * x1v.y;
  }
  if (p < p1) {
    int e = eidx[p];
    int c = col[e];
    float v = val[e];
    float2 x = *reinterpret_cast<const float2*>(x1 + (size_t)c * cD + lane * 2);
    ax += v * x.x; ay += v * x.y;
  }
  float2 o; o.x = ax; o.y = ay;
  *reinterpret_cast<float2*>(outc + (size_t)i * cD + lane * 2) = o;
}

// (x0 + x1 + x2)/3 at gathered rows -> LayerNorm -> dst
__global__ __launch_bounds__(128) void gather_ln(
    const int* __restrict__ ids, int mode,
    const float* __restrict__ ea, const float* __restrict__ eb, int na,
    const float* __restrict__ x1, const float* __restrict__ x2, const int* __restrict__ slot,
    const float* __restrict__ g, const float* __restrict__ bia, float* __restrict__ dst) {
  __shared__ float sh[128];
  int i = blockIdx.x;
  int tid = threadIdx.x;
  int id = ids[i];
  int node = mapNode(mode, id);
  if (node < 0) return;
  const float* x0 = (node < na) ? (ea + (size_t)node * cD) : (eb + (size_t)(node - na) * cD);
  int xi2 = slot ? slot[node] : node;
  float a = (x0[tid] + x1[(size_t)node * cD + tid] + x2[(size_t)xi2 * cD + tid]) * (1.0f / 3.0f);
  float s  = blockReduce128(a, sh, tid);
  float ss = blockReduce128(a * a, sh, tid);
  float mu = s * (1.0f / 128.0f);
  float var = ss * (1.0f / 128.0f) - mu * mu;
  float y = (a - mu) * rsqrtf(var + 1e-5f) * g[tid] + bia[tid];
  dst[(size_t)i * cD + tid] = y;
}

// ---------------------------------------------------------------------------
// fp32 GEMM (small cl projections only): epi 0=store, 1=store ELU
// ---------------------------------------------------------------------------
__global__ __launch_bounds__(256) void gemm64(
    const float* __restrict__ A, const float* __restrict__ B, float* __restrict__ C,
    int M, int N, int K, const float* __restrict__ bias, int epi) {
  __shared__ __align__(16) float As[16][68];
  __shared__ __align__(16) float Bs[16][68];
  const int bx = blockIdx.x, by = blockIdx.y;
  const int tx = threadIdx.x & 15, ty = threadIdx.x >> 4;
  const int la_r = threadIdx.x >> 2;
  const int la_k = (threadIdx.x & 3) * 4;
  const int lb_k = threadIdx.x >> 4;
  const int lb_c = (threadIdx.x & 15) * 4;
  float acc[4][4] = {};
  for (int kt = 0; kt < K; kt += 16) {
    __syncthreads();
    float4 av = *reinterpret_cast<const float4*>(A + (size_t)(by * 64 + la_r) * K + kt + la_k);
    As[la_k + 0][la_r] = av.x; As[la_k + 1][la_r] = av.y;
    As[la_k + 2][la_r] = av.z; As[la_k + 3][la_r] = av.w;
    *reinterpret_cast<float4*>(&Bs[lb_k][lb_c]) =
        *reinterpret_cast<const float4*>(B + (size_t)(kt + lb_k) * N + bx * 64 + lb_c);
    __syncthreads();
#pragma unroll
    for (int kk = 0; kk < 16; ++kk) {
      float4 a = *reinterpret_cast<const float4*>(&As[kk][ty * 4]);
      float4 b = *reinterpret_cast<const float4*>(&Bs[kk][tx * 4]);
      acc[0][0] += a.x * b.x; acc[0][1] += a.x * b.y; acc[0][2] += a.x * b.z; acc[0][3] += a.x * b.w;
      acc[1][0] += a.y * b.x; acc[1][1] += a.y * b.y; acc[1][2] += a.y * b.z; acc[1][3] += a.y * b.w;
      acc[2][0] += a.z * b.x; acc[2][1] += a.z * b.y; acc[2][2] += a.z * b.z; acc[2][3] += a.z * b.w;
      acc[3][0] += a.w * b.x; acc[3][1] += a.w * b.y; acc[3][2] += a.w * b.z; acc[3][3] += a.w * b.w;
    }
  }
  const int row0 = by * 64 + ty * 4, col0 = bx * 64 + tx * 4;
#pragma unroll
  for (int i = 0; i < 4; ++i)
#pragma unroll
    for (int j = 0; j < 4; ++j) {
      int r = row0 + i, c = col0 + j;
      float v = acc[i][j] + bias[c];
      if (epi == 1) v = (v > 0.0f) ? v : expm1f(v);
      C[(size_t)r * N + c] = v;
    }
}

// ---------------------------------------------------------------------------
// bf16 MFMA GEMM: C[M,N] = A[M,K] @ Bt[N,K]^T, 128x128 tile, 4 waves
// Cbf = bf16(acc + bias)
// ---------------------------------------------------------------------------
__global__ __launch_bounds__(256) void gemm_bf(
    const ushort* __restrict__ A, const ushort* __restrict__ Bt,
    int N, int K, const float* __restrict__ bias, ushort* __restrict__ Cbf) {
  __shared__ ushort As[128 * 40];
  __shared__ ushort Bs[128 * 40];
  const int bx = blockIdx.x, by = blockIdx.y;
  const int t = threadIdx.x;
  const int wv = t >> 6, lane = t & 63;
  const int wr = (wv >> 1) * 64, wc = (wv & 1) * 64;
  const int srow = t >> 1, shalf = t & 1;
  const ushort* Ag = A + (size_t)(by * 128 + srow) * K + shalf * 16;
  const ushort* Bg = Bt + (size_t)(bx * 128 + srow) * K + shalf * 16;
  uint4 ra0 = *reinterpret_cast<const uint4*>(Ag);
  uint4 ra1 = *reinterpret_cast<const uint4*>(Ag + 8);
  uint4 rb0 = *reinterpret_cast<const uint4*>(Bg);
  uint4 rb1 = *reinterpret_cast<const uint4*>(Bg + 8);
  f32x4 acc[4][4];
  const f32x4 z4 = {0.f, 0.f, 0.f, 0.f};
#pragma unroll
  for (int i = 0; i < 4; ++i)
#pragma unroll
    for (int j = 0; j < 4; ++j) acc[i][j] = z4;
  const int la = lane & 15, lk = (lane >> 4) * 8;
  const int sdst = srow * 40 + shalf * 16;
  for (int kt = 0; kt < K; kt += 32) {
    __syncthreads();
    *reinterpret_cast<uint4*>(&As[sdst])     = ra0;
    *reinterpret_cast<uint4*>(&As[sdst + 8]) = ra1;
    *reinterpret_cast<uint4*>(&Bs[sdst])     = rb0;
    *reinterpret_cast<uint4*>(&Bs[sdst + 8]) = rb1;
    __syncthreads();
    if (kt + 32 < K) {
      ra0 = *reinterpret_cast<const uint4*>(Ag + kt + 32);
      ra1 = *reinterpret_cast<const uint4*>(Ag + kt + 40);
      rb0 = *reinterpret_cast<const uint4*>(Bg + kt + 32);
      rb1 = *reinterpret_cast<const uint4*>(Bg + kt + 40);
    }
    short8v af[4], bfr[4];
#pragma unroll
    for (int i = 0; i < 4; ++i)
      af[i] = *reinterpret_cast<const short8v*>(&As[(wr + i * 16 + la) * 40 + lk]);
#pragma unroll
    for (int j = 0; j < 4; ++j)
      bfr[j] = *reinterpret_cast<const short8v*>(&Bs[(wc + j * 16 + la) * 40 + lk]);
#pragma unroll
    for (int i = 0; i < 4; ++i)
#pragma unroll
      for (int j = 0; j < 4; ++j)
        acc[i][j] = __builtin_amdgcn_mfma_f32_16x16x32_bf16(af[i], bfr[j], acc[i][j], 0, 0, 0);
  }
  const int r0 = by * 128 + wr + (lane >> 4) * 4;
  const int c0 = bx * 128 + wc + la;
#pragma unroll
  for (int i = 0; i < 4; ++i)
#pragma unroll
    for (int j = 0; j < 4; ++j) {
      int c = c0 + j * 16;
      float bv = bias[c];
#pragma unroll
      for (int q = 0; q < 4; ++q) {
        int r = r0 + i * 16 + q;
        Cbf[(size_t)r * N + c] = f2bf(acc[i][j][q] + bv);
      }
    }
}

// ---------------------------------------------------------------------------
// Fused MoE: out[b,t] = sigmoid(mean_l sum_e gate[r,e]*(A@Bt_e + exp_b_e))
// A: [4096][1024] bf16; Bt4: 4 x [1024][1024] bf16 (transposed); K=N=1024.
// ---------------------------------------------------------------------------
__global__ __launch_bounds__(256) void gemm_moe_out(
    const ushort* __restrict__ A, const ushort* __restrict__ Bt4,
    const float* __restrict__ expb, const float* __restrict__ gate,
    float* __restrict__ out) {
  __shared__ ushort As[128 * 40];
  __shared__ ushort Bs[128 * 40];
  __shared__ float gs[128][4];
  const int bx = blockIdx.x, by = blockIdx.y;
  const int t = threadIdx.x;
  const int wv = t >> 6, lane = t & 63;
  const int wr = (wv >> 1) * 64, wc = (wv & 1) * 64;
  const int srow = t >> 1, shalf = t & 1;
  const int la = lane & 15, lk = (lane >> 4) * 8;
  const int sdst = srow * 40 + shalf * 16;
  if (t < 128)
    *reinterpret_cast<float4*>(&gs[t][0]) =
        *reinterpret_cast<const float4*>(gate + (size_t)(by * 128 + t) * 4);
  const ushort* Ag = A + (size_t)(by * 128 + srow) * 1024 + shalf * 16;
  f32x4 rs[4][4];
  const f32x4 z4 = {0.f, 0.f, 0.f, 0.f};
#pragma unroll
  for (int i = 0; i < 4; ++i)
#pragma unroll
    for (int j = 0; j < 4; ++j) rs[i][j] = z4;
  for (int e = 0; e < 4; ++e) {
    const ushort* Bg = Bt4 + (size_t)e * 1048576 + (size_t)(bx * 128 + srow) * 1024 + shalf * 16;
    uint4 ra0 = *reinterpret_cast<const uint4*>(Ag);
    uint4 ra1 = *reinterpret_cast<const uint4*>(Ag + 8);
    uint4 rb0 = *reinterpret_cast<const uint4*>(Bg);
    uint4 rb1 = *reinterpret_cast<const uint4*>(Bg + 8);
    f32x4 acc[4][4];
#pragma unroll
    for (int i = 0; i < 4; ++i)
#pragma unroll
      for (int j = 0; j < 4; ++j) acc[i][j] = z4;
    for (int kt = 0; kt < 1024; kt += 32) {
      __syncthreads();
      *reinterpret_cast<uint4*>(&As[sdst])     = ra0;
      *reinterpret_cast<uint4*>(&As[sdst + 8]) = ra1;
      *reinterpret_cast<uint4*>(&Bs[sdst])     = rb0;
      *reinterpret_cast<uint4*>(&Bs[sdst + 8]) = rb1;
      __syncthreads();
      if (kt + 32 < 1024) {
        ra0 = *reinterpret_cast<const uint4*>(Ag + kt + 32);
        ra1 = *reinterpret_cast<const uint4*>(Ag + kt + 40);
        rb0 = *reinterpret_cast<const uint4*>(Bg + kt + 32);
        rb1 = *reinterpret_cast<const uint4*>(Bg + kt + 40);
      }
      short8v af[4], bfr[4];
#pragma unroll
      for (int i = 0; i < 4; ++i)
        af[i] = *reinterpret_cast<const short8v*>(&As[(wr + i * 16 + la) * 40 + lk]);
#pragma unroll
      for (int j = 0; j < 4; ++j)
        bfr[j] = *reinterpret_cast<const short8v*>(&Bs[(wc + j * 16 + la) * 40 + lk]);
#pragma unroll
      for (int i = 0; i < 4; ++i)
#pragma unroll
        for (int j = 0; j < 4; ++j)
          acc[i][j] = __builtin_amdgcn_mfma_f32_16x16x32_bf16(af[i], bfr[j], acc[i][j], 0, 0, 0);
    }
#pragma unroll
    for (int j = 0; j < 4; ++j) {
      float eb = expb[e * 1024 + bx * 128 + wc + j * 16 + la];
#pragma unroll
      for (int i = 0; i < 4; ++i)
#pragma unroll
        for (int q = 0; q < 4; ++q) {
          int rl = wr + (lane >> 4) * 4 + i * 16 + q;
          rs[i][j][q] += gs[rl][e] * (acc[i][j][q] + eb);
        }
    }
  }
  // mean over mailbox (8 rows) + sigmoid, write out directly
#pragma unroll
  for (int i = 0; i < 4; ++i)
#pragma unroll
    for (int j = 0; j < 4; ++j) {
      float s = rs[i][j][0] + rs[i][j][1] + rs[i][j][2] + rs[i][j][3];
      s += __shfl_xor(s, 16);
      if (((lane >> 4) & 1) == 0) {
        int bl = (wr >> 3) + 2 * i + ((lane >> 4) >> 1);
        int c = bx * 128 + wc + j * 16 + la;
        out[(size_t)(by * 16 + bl) * 1024 + c] = 1.0f / (1.0f + expf(-s * 0.125f));
      }
    }
}

// ---------------------------------------------------------------------------
// Gram contrastive kernel: G = W @ W^T (8192x8192, K=128), fused exp(2x),
// per-row half-sums into rsum[2][8192], diag captures d11/d12/d22.
// ---------------------------------------------------------------------------
__global__ __launch_bounds__(256) void gram_cl(
    const ushort* __restrict__ W, float* __restrict__ rsum,
    float* __restrict__ d11, float* __restrict__ d12, float* __restrict__ d22) {
  __shared__ ushort As[128 * 40];
  __shared__ ushort Bs[128 * 40];
  const int bx = blockIdx.x, by = blockIdx.y;
  const int t = threadIdx.x;
  const int wv = t >> 6, lane = t & 63;
  const int wr = (wv >> 1) * 64, wc = (wv & 1) * 64;
  const int srow = t >> 1, shalf = t & 1;
  const ushort* Ag = W + (size_t)(by * 128 + srow) * 128 + shalf * 16;
  const ushort* Bg = W + (size_t)(bx * 128 + srow) * 128 + shalf * 16;
  uint4 ra0 = *reinterpret_cast<const uint4*>(Ag);
  uint4 ra1 = *reinterpret_cast<const uint4*>(Ag + 8);
  uint4 rb0 = *reinterpret_cast<const uint4*>(Bg);
  uint4 rb1 = *reinterpret_cast<const uint4*>(Bg + 8);
  f32x4 acc[4][4];
  const f32x4 z4 = {0.f, 0.f, 0.f, 0.f};
#pragma unroll
  for (int i = 0; i < 4; ++i)
#pragma unroll
    for (int j = 0; j < 4; ++j) acc[i][j] = z4;
  const int la = lane & 15, lk = (lane >> 4) * 8;
  const int sdst = srow * 40 + shalf * 16;
  for (int kt = 0; kt < 128; kt += 32) {
    __syncthreads();
    *reinterpret_cast<uint4*>(&As[sdst])     = ra0;
    *reinterpret_cast<uint4*>(&As[sdst + 8]) = ra1;
    *reinterpret_cast<uint4*>(&Bs[sdst])     = rb0;
    *reinterpret_cast<uint4*>(&Bs[sdst + 8]) = rb1;
    __syncthreads();
    if (kt + 32 < 128) {
      ra0 = *reinterpret_cast<const uint4*>(Ag + kt + 32);
      ra1 = *reinterpret_cast<const uint4*>(Ag + kt + 40);
      rb0 = *reinterpret_cast<const uint4*>(Bg + kt + 32);
      rb1 = *reinterpret_cast<const uint4*>(Bg + kt + 40);
    }
    short8v af[4], bfr[4];
#pragma unroll
    for (int i = 0; i < 4; ++i)
      af[i] = *reinterpret_cast<const short8v*>(&As[(wr + i * 16 + la) * 40 + lk]);
#pragma unroll
    for (int j = 0; j < 4; ++j)
      bfr[j] = *reinterpret_cast<const short8v*>(&Bs[(wc + j * 16 + la) * 40 + lk]);
#pragma unroll
    for (int i = 0; i < 4; ++i)
#pragma unroll
      for (int j = 0; j < 4; ++j)
        acc[i][j] = __builtin_amdgcn_mfma_f32_16x16x32_bf16(af[i], bfr[j], acc[i][j], 0, 0, 0);
  }
  const int r0 = by * 128 + wr + (lane >> 4) * 4;
  const int c0 = bx * 128 + wc + la;
  float rs[4][4];
#pragma unroll
  for (int i = 0; i < 4; ++i)
#pragma unroll
    for (int q = 0; q < 4; ++q) rs[i][q] = 0.f;
#pragma unroll
  for (int i = 0; i < 4; ++i)
#pragma unroll
    for (int j = 0; j < 4; ++j)
#pragma unroll
      for (int q = 0; q < 4; ++q) {
        int r = r0 + i * 16 + q;
        int c = c0 + j * 16;
        float e = expf(2.0f * acc[i][j][q]);
        rs[i][q] += e;
        if (c == r)        { if (r < 4096) d11[r] = e; else d22[r - 4096] = e; }
        if (c == r + 4096) d12[r] = e;
      }
#pragma unroll
  for (int m = 1; m < 16; m <<= 1)
#pragma unroll
    for (int i = 0; i < 4; ++i)
#pragma unroll
      for (int q = 0; q < 4; ++q) rs[i][q] += __shfl_xor(rs[i][q], m);
  if (la == 0) {
    float* dst = rsum + (bx < 32 ? 0 : 8192);
#pragma unroll
    for (int i = 0; i < 4; ++i)
#pragma unroll
      for (int q = 0; q < 4; ++q) atomAdd(&dst[r0 + i * 16 + q], rs[i][q]);
  }
}

__global__ __launch_bounds__(256) void cl_row(
    const float* __restrict__ rsum, const float* __restrict__ d11,
    const float* __restrict__ d12, const float* __restrict__ d22,
    float* __restrict__ cl_sum) {
  __shared__ float sh[256];
  int i = blockIdx.x * 256 + threadIdx.x;
  float denA = rsum[i] + rsum[8192 + i] - d11[i];
  float denB = rsum[8192 + 4096 + i] + rsum[4096 + i] - d22[i];
  float l = 0.5f * (logf(denA) + logf(denB)) - logf(d12[i]);
  float s = blockReduce256(l, sh, threadIdx.x);
  if (threadIdx.x == 0) atomAdd(cl_sum, s);
}

// weight transpose + bf16 convert: Bt[n*K+k] = bf16(W[k*N+n])
__global__ __launch_bounds__(256) void k_wt_bt(const float* __restrict__ W,
                                               ushort* __restrict__ Bt, int K, int N) {
  __shared__ float tile[32][33];
  int n0 = blockIdx.x * 32, k0 = blockIdx.y * 32;
  int tx = threadIdx.x & 31, ty = threadIdx.x >> 5;
#pragma unroll
  for (int i = 0; i < 4; ++i)
    tile[ty + 8 * i][tx] = W[(size_t)(k0 + ty + 8 * i) * N + n0 + tx];
  __syncthreads();
#pragma unroll
  for (int i = 0; i < 4; ++i)
    Bt[(size_t)(n0 + ty + 8 * i) * K + k0 + tx] = f2bf(tile[tx][ty + 8 * i]);
}

__global__ __launch_bounds__(128) void rownorm_bf(const float* __restrict__ z,
                                                  ushort* __restrict__ w) {
  __shared__ float sh[128];
  int i = blockIdx.x, tid = threadIdx.x;
  float v = z[(size_t)i * cD + tid];
  float ss = blockReduce128(v * v, sh, tid);
  float n = fmaxf(sqrtf(ss), 1e-12f);
  w[(size_t)i * cD + tid] = f2bf(v / n);
}

// ---------------------------------------------------------------------------
// message / losses / MHA
// ---------------------------------------------------------------------------
__global__ __launch_bounds__(256) void emb_sum_k(
    const float* __restrict__ s1, const float* __restrict__ s2,
    const float* __restrict__ relation, const int* __restrict__ etype, float* __restrict__ out) {
  __shared__ float sh[256];
  int idx = blockIdx.x * 256 + threadIdx.x;
  int i = idx >> 8, j = idx & 255;
  float a = (j < 128) ? s1[(size_t)i * 128 + j] : s2[(size_t)i * 128 + j - 128];
  int et = etype[i];
  float r = relation[(size_t)(et % cNR) * 256 + j];
  float t = blockReduce256(a * a + r * r, sh, threadIdx.x);
  if (threadIdx.x == 0) atomAdd(out, t);
}

__global__ __launch_bounds__(256) void msg_build(
    const float* __restrict__ s1, const float* __restrict__ s2,
    const float* __restrict__ relation, const int* __restrict__ etype,
    ushort* __restrict__ msg) {
  int idx = blockIdx.x * 256 + threadIdx.x;
  int i = idx >> 8, j = idx & 255;
  int et = etype[i];
  float sign = (et >= cNR) ? -1.0f : 1.0f;
  float r = relation[(size_t)(et % cNR) * 256 + j] * sign;
  float s = (j < 128) ? s1[(size_t)i * 128 + j] : s2[(size_t)i * 128 + j - 128];
  msg[idx] = f2bf(fmaxf(s + r, 0.0f));
}

__global__ __launch_bounds__(64) void mha_attn(
    const ushort* __restrict__ q, const ushort* __restrict__ k,
    const ushort* __restrict__ v, ushort* __restrict__ o) {
  __shared__ float qs[8][128], ks[8][128], vs[8][128], att[8][8];
  int bh = blockIdx.x;
  int b = bh >> 3, h = bh & 7;
  int tid = threadIdx.x;
  for (int idx = tid; idx < 1024; idx += 64) {
    int l = idx >> 7, d = idx & 127;
    size_t src = (size_t)(b * 8 + l) * cT + h * 128 + d;
    qs[l][d] = bf2f(q[src]); ks[l][d] = bf2f(k[src]); vs[l][d] = bf2f(v[src]);
  }
  __syncthreads();
  int l = tid >> 3, m = tid & 7;
  float s = 0;
#pragma unroll 16
  for (int d = 0; d < 128; ++d) s += qs[l][d] * ks[m][d];
  s *= 0.08838834764831845f;
  float mx = s;
  for (int off = 1; off < 8; off <<= 1) mx = fmaxf(mx, __shfl_xor(mx, off, 8));
  float p = expf(s - mx);
  float sum = p;
  for (int off = 1; off < 8; off <<= 1) sum += __shfl_xor(sum, off, 8);
  att[l][m] = p / sum;
  __syncthreads();
  for (int idx = tid; idx < 1024; idx += 64) {
    int ll = idx >> 7, d = idx & 127;
    float acc = 0;
#pragma unroll
    for (int mm = 0; mm < 8; ++mm) acc += att[ll][mm] * vs[mm][d];
    o[(size_t)(b * 8 + ll) * cT + h * 128 + d] = f2bf(acc);
  }
}

__global__ __launch_bounds__(64) void gate_k(
    const ushort* __restrict__ o, const float* __restrict__ gw, float* __restrict__ gate) {
  int i = blockIdx.x;
  int lane = threadIdx.x;
  float g[4] = {0, 0, 0, 0};
  for (int d = lane; d < cT; d += 64) {
    float ov = bf2f(o[(size_t)i * cT + d]);
    g[0] += ov * gw[d * 4 + 0];
    g[1] += ov * gw[d * 4 + 1];
    g[2] += ov * gw[d * 4 + 2];
    g[3] += ov * gw[d * 4 + 3];
  }
#pragma unroll
  for (int off = 32; off > 0; off >>= 1)
#pragma unroll
    for (int e = 0; e < 4; ++e) g[e] += __shfl_down(g[e], off);
  if (lane == 0) {
    float mx = fmaxf(fmaxf(g[0], g[1]), fmaxf(g[2], g[3]));
    float ex[4], sum = 0;
#pragma unroll
    for (int e = 0; e < 4; ++e) { ex[e] = expf(g[e] - mx); sum += ex[e]; }
#pragma unroll
    for (int e = 0; e < 4; ++e) gate[(size_t)i * 4 + e] = ex[e] / sum;
  }
}

__global__ void finalize_k(const float* __restrict__ scal, float* __restrict__ out_aux) {
  float cl = scal[0] * (1.0f / cNSRC);
  float emb = cDECAY * 0.5f * scal[1] * (1.0f / cNSRC);
  out_aux[0] = cCLW * cl + emb;
}

// ---------------------------------------------------------------------------
// Launch
// ---------------------------------------------------------------------------
extern "C" void kernel_launch(void* const* d_in, const int* in_sizes, int n_in,
                              void* d_out, int out_size, void* d_ws, size_t ws_size,
                              hipStream_t stream) {
  (void)in_sizes; (void)n_in; (void)out_size; (void)ws_size;
  const float* entity   = (const float*)d_in[0];
  const float* type_e   = (const float*)d_in[1];
  const float* cluster  = (const float*)d_in[2];
  const float* relation = (const float*)d_in[3];
  const float* ln_g  = (const float*)d_in[4];
  const float* ln_b  = (const float*)d_in[5];
  const float* cl_w1 = (const float*)d_in[6];
  const float* cl_b1 = (const float*)d_in[7];
  const float* cl_w2 = (const float*)d_in[8];
  const float* cl_b2 = (const float*)d_in[9];
  const float* fc_w  = (const float*)d_in[10];
  const float* fc_b  = (const float*)d_in[11];
  const float* wq = (const float*)d_in[12];
  const float* bq = (const float*)d_in[13];
  const float* wk = (const float*)d_in[14];
  const float* bk = (const float*)d_in[15];
  const float* wv = (const float*)d_in[16];
  const float* bv = (const float*)d_in[17];
  const float* wo = (const float*)d_in[18];
  const float* bo = (const float*)d_in[19];
  const float* gate_w = (const float*)d_in[20];
  const float* exp_w  = (const float*)d_in[21];
  const float* exp_b  = (const float*)d_in[22];
  const float* e2t_val = (const float*)d_in[23];
  const float* t2c_val = (const float*)d_in[24];
  const float* e2c_val = (const float*)d_in[25];
  const int* e2t_row = (const int*)d_in[26];
  const int* e2t_col = (const int*)d_in[27];
  const int* t2c_row = (const int*)d_in[28];
  const int* t2c_col = (const int*)d_in[29];
  const int* e2c_row = (const int*)d_in[30];
  const int* e2c_col = (const int*)d_in[31];
  const int* src_ids = (const int*)d_in[32];
  const int* etype   = (const int*)d_in[33];

  float* ws = (float*)d_ws;
  float* S1 = ws + F_S1;
  float* S2 = ws + F_S2;
  float* PT = ws + F_PT;
  float* Z1 = ws + F_Z1;
  float* Z2 = ws + F_Z2;
  ushort* MSGbf = (ushort*)(ws + F_MSG);
  float* GATE = ws + F_GATE;
  float* SCAL = ws + F_SCAL;
  float* RS   = ws + F_RS;
  float* D11  = ws + F_D11;
  float* D12  = ws + F_D12;
  float* D22  = ws + F_D22;
  ushort* Wbf = (ushort*)(ws + F_PT);
  float* X1F  = ws + G_X1F;
  float* X2C  = ws + G_X2C;
  int*   MARK = (int*)(ws + G_X2C);     // aliased: mark dead before X2C written
  int*   SLOT = (int*)(ws + G_SLOT);
  int*   REP  = (int*)(ws + G_REP);
  int*   RP   = (int*)(ws + G_RP);
  int*   FILL = (int*)(ws + G_FILL);
  int*   EIDX = (int*)(ws + G_EIDX);
  float* X1T  = ws + G_X1T;
  float* X2T  = ws + G_X2T;
  int*   BSUM = (int*)(ws + G_BSUM);
  ushort* PB  = (ushort*)(ws + A_U0);
  ushort* QB  = (ushort*)(ws + A_U1);
  ushort* KB  = (ushort*)(ws + A_U2);
  ushort* VB  = (ushort*)(ws + A_U3);
  ushort* WBT = (ushort*)(ws + A_WBT);  // up to 4 x 1Mi ushorts

  hipMemsetAsync(SCAL, 0, 2 * sizeof(float), stream);
  hipMemsetAsync(RS, 0, (16384 + 3 * 4096) * sizeof(float), stream);

  // masked GCN: slot -> mark -> CSR(marked) -> gather(marked) -> slot layer2 -> LN
  auto run_gcn_masked = [&](const int* row, const int* col, const float* val, int nnz, int nn,
                            const float* ea, const float* eb, int na, int mode,
                            float* dst) {
    int nb = (nn + 255) / 256;
    int gEdge = (nnz + 255) / 256;
    hipMemsetAsync(SLOT, 0x7F, (size_t)nn * sizeof(int), stream);
    slot_build<<<16, 256, 0, stream>>>(src_ids, SLOT, mode);
    hipMemsetAsync(MARK, 0, (size_t)nn * sizeof(int), stream);
    k_mark_nodes<<<16, 256, 0, stream>>>(src_ids, MARK, mode);
    k_mark_edges<<<gEdge, 256, 0, stream>>>(row, col, nnz, SLOT, MARK);
    hipMemsetAsync(FILL, 0, (size_t)nn * sizeof(int), stream);
    k_hist<<<gEdge, 256, 0, stream>>>(row, nnz, MARK, FILL);
    k_scan_block<<<nb, 256, 0, stream>>>(FILL, nn, RP, BSUM);
    k_bsum_scan<<<1, 512, 0, stream>>>(BSUM, nb, RP, nn);
    k_scan_add<<<nb, 256, 0, stream>>>(RP, BSUM, nn, FILL);
    k_fill<<<gEdge, 256, 0, stream>>>(row, nnz, MARK, FILL, EIDX);
    k_rep<<<16, 256, 0, stream>>>(src_ids, SLOT, mode, REP);
    k_gather<<<(nn + 3) / 4, 256, 0, stream>>>(RP, EIDX, col, val, ea, eb, na, nn, MARK, X1F);
    k_gather_slot<<<cNSRC / 4, 256, 0, stream>>>(RP, EIDX, col, val, X1F, REP, X2C);
    gather_ln<<<cNSRC, 128, 0, stream>>>(src_ids, mode, ea, eb, na, X1F, X2C, SLOT,
                                         ln_g, ln_b, dst);
  };

  run_gcn_masked(e2t_row, e2t_col, e2t_val, cNNZ_E2T, cNN_E2T, entity, type_e, cNE, 0, S1);
  run_gcn_masked(e2c_row, e2c_col, e2c_val, cNNZ_E2C, cNN_E2C, entity, cluster, cNE, 3, S2);

  // ---- t2c: tiny, both layers full ----
  {
    int nn = cNN_T2C, nb = (nn + 255) / 256, gEdge = (cNNZ_T2C + 255) / 256;
    hipMemsetAsync(FILL, 0, (size_t)nn * sizeof(int), stream);
    k_hist<<<gEdge, 256, 0, stream>>>(t2c_row, cNNZ_T2C, nullptr, FILL);
    k_scan_block<<<nb, 256, 0, stream>>>(FILL, nn, RP, BSUM);
    k_bsum_scan<<<1, 512, 0, stream>>>(BSUM, nb, RP, nn);
    k_scan_add<<<nb, 256, 0, stream>>>(RP, BSUM, nn, FILL);
    k_fill<<<gEdge, 256, 0, stream>>>(t2c_row, cNNZ_T2C, nullptr, FILL, EIDX);
    k_gather<<<(nn + 3) / 4, 256, 0, stream>>>(RP, EIDX, t2c_col, t2c_val,
                                               type_e, cluster, cNT, nn, nullptr, X1T);
    k_gather<<<(nn + 3) / 4, 256, 0, stream>>>(RP, EIDX, t2c_col, t2c_val,
                                               X1T, X1T, 1 << 30, nn, nullptr, X2T);
    gather_ln<<<cNSRC, 128, 0, stream>>>(src_ids, 1, type_e, cluster, cNT, X1T, X2T, nullptr,
                                         ln_g, ln_b, S1);
    gather_ln<<<cNSRC, 128, 0, stream>>>(src_ids, 2, type_e, cluster, cNT, X1T, X2T, nullptr,
                                         ln_g, ln_b, S2);
  }

  // ================= contrastive loss =================
  dim3 g128(cD / 64, cNSRC / 64);
  gemm64<<<g128, 256, 0, stream>>>(S1, cl_w1, PT, cNSRC, cD, cD, cl_b1, 1);
  gemm64<<<g128, 256, 0, stream>>>(PT, cl_w2, Z1, cNSRC, cD, cD, cl_b2, 0);
  gemm64<<<g128, 256, 0, stream>>>(S2, cl_w1, PT, cNSRC, cD, cD, cl_b1, 1);
  gemm64<<<g128, 256, 0, stream>>>(PT, cl_w2, Z2, cNSRC, cD, cD, cl_b2, 0);
  rownorm_bf<<<cNSRC, 128, 0, stream>>>(Z1, Wbf);
  rownorm_bf<<<cNSRC, 128, 0, stream>>>(Z2, Wbf + (size_t)cNSRC * cD);
  gram_cl<<<dim3(64, 64), 256, 0, stream>>>(Wbf, RS, D11, D12, D22);
  cl_row<<<16, 256, 0, stream>>>(RS, D11, D12, D22, SCAL);
  emb_sum_k<<<cNSRC, 256, 0, stream>>>(S1, S2, relation, etype, SCAL + 1);

  // ================= message + predict (bf16 MFMA) =================
  msg_build<<<cNSRC, 256, 0, stream>>>(S1, S2, relation, etype, MSGbf);
  dim3 gBF(cT / 128, cNSRC / 128);
  k_wt_bt<<<dim3(cT / 32, 256 / 32), 256, 0, stream>>>(fc_w, WBT, 256, cT);
  gemm_bf<<<gBF, 256, 0, stream>>>(MSGbf, WBT, cT, 256, fc_b, PB);

  // ================= MHA =================
  k_wt_bt<<<dim3(cT / 32, cT / 32), 256, 0, stream>>>(wq, WBT, cT, cT);
  gemm_bf<<<gBF, 256, 0, stream>>>(PB, WBT, cT, cT, bq, QB);
  k_wt_bt<<<dim3(cT / 32, cT / 32), 256, 0, stream>>>(wk, WBT, cT, cT);
  gemm_bf<<<gBF, 256, 0, stream>>>(PB, WBT, cT, cT, bk, KB);
  k_wt_bt<<<dim3(cT / 32, cT / 32), 256, 0, stream>>>(wv, WBT, cT, cT);
  gemm_bf<<<gBF, 256, 0, stream>>>(PB, WBT, cT, cT, bv, VB);
  mha_attn<<<cB * 8, 64, 0, stream>>>(QB, KB, VB, PB);
  k_wt_bt<<<dim3(cT / 32, cT / 32), 256, 0, stream>>>(wo, WBT, cT, cT);
  gemm_bf<<<gBF, 256, 0, stream>>>(PB, WBT, cT, cT, bo, KB);

  // ================= fused MoE + mean + sigmoid =================
  gate_k<<<cNSRC, 64, 0, stream>>>(KB, gate_w, GATE);
  for (int e = 0; e < cE; ++e)
    k_wt_bt<<<dim3(cT / 32, cT / 32), 256, 0, stream>>>(exp_w + (size_t)e * cT * cT,
                                                        WBT + (size_t)e * cT * cT, cT, cT);
  gemm_moe_out<<<dim3(8, 32), 256, 0, stream>>>(KB, WBT, exp_b, GATE, (float*)d_out);

  finalize_k<<<1, 1, 0, stream>>>(SCAL, (float*)d_out + (size_t)cB * cT);
}

// Round 5
// 627.800 us; speedup vs baseline: 8.7366x; 1.1589x over previous
//
#include <hip/hip_runtime.h>
#include <hip/hip_bf16.h>
#include <cmath>

// ---------------------------------------------------------------------------
// Problem constants (fixed shapes)
// ---------------------------------------------------------------------------
constexpr int cNE = 100000, cNT = 1024, cNC = 128, cD = 128, cNR = 500;
constexpr int cB = 512, cNSRC = 4096, cT = 1024, cE = 4;
constexpr int cNNZ_E2T = 1000000, cNNZ_T2C = 50000, cNNZ_E2C = 500000;
constexpr float cDECAY = 1e-4f, cCLW = 0.1f;
constexpr int cNN_E2T = cNE + cNT;     // 101024
constexpr int cNN_E2C = cNE + cNC;     // 100128
constexpr int cNN_T2C = cNT + cNC;     // 1152

// ---------------------------------------------------------------------------
// Workspace layout (FLOAT units)
// ---------------------------------------------------------------------------
constexpr size_t F_S1   = 0;                          // f32 4096x128
constexpr size_t F_S2   = F_S1 + 524288;
constexpr size_t F_PT   = F_S2 + 524288;              // bf16 W [8192][128] (Z/normed)
constexpr size_t F_Z1   = F_PT + 524288;              // bf16 P1 [8192][128]
constexpr size_t F_Z2   = F_Z1 + 524288;              // bf16 SB [8192][128]
constexpr size_t F_MSG  = F_Z2 + 524288;              // bf16 4096x256
constexpr size_t F_GATE = F_MSG + 524288;             // f32 4096x4
constexpr size_t F_SCAL = F_GATE + 16384;
constexpr size_t F_RS   = F_SCAL + 64;                // f32 [2][8192] gram sums; later bias_qkv
constexpr size_t F_D11  = F_RS + 16384;               // f32 [4096]
constexpr size_t F_D12  = F_D11 + 4096;
constexpr size_t F_D22  = F_D12 + 4096;
constexpr size_t F_U    = F_D22 + 4096;               // union base
// --- GCN phase ---
constexpr size_t G_X1F  = F_U;                        // f32 101024x128
constexpr size_t G_X2C  = G_X1F + 12931072;           // f32 4096x128 (also MARK)
constexpr size_t G_SLOT = G_X2C + 524288;
constexpr size_t G_REP  = G_SLOT + 101376;
constexpr size_t G_RP   = G_REP + 4096;
constexpr size_t G_FILL = G_RP + 101376;
constexpr size_t G_EIDX = G_FILL + 101376;
constexpr size_t G_X1T  = G_EIDX + 1000000;
constexpr size_t G_X2T  = G_X1T + 147456;
constexpr size_t G_BSUM = G_X2T + 147456;
// --- activation phase ---
constexpr size_t A_U0  = F_U;                 // predict bf16; then attn-out
constexpr size_t A_U1  = F_U + 2097152;       // QKV bf16 [4096][3072] spans U1..U3; then O
constexpr size_t A_WBT = F_U + 4 * 2097152;   // bf16 weight^T scratch

typedef __attribute__((ext_vector_type(8))) short short8v;
typedef __attribute__((ext_vector_type(4))) float f32x4;

// ---------------------------------------------------------------------------
// Helpers
// ---------------------------------------------------------------------------
__device__ __forceinline__ void atomAdd(float* p, float v) {
  __hip_atomic_fetch_add(p, v, __ATOMIC_RELAXED, __HIP_MEMORY_SCOPE_AGENT);
}
__device__ __forceinline__ ushort f2bf(float f) {
  __hip_bfloat16 h = __float2bfloat16(f);
  return *reinterpret_cast<ushort*>(&h);
}
__device__ __forceinline__ float bf2f(ushort u) {
  __hip_bfloat16 h; *reinterpret_cast<ushort*>(&h) = u;
  return __bfloat162float(h);
}

__device__ __forceinline__ int mapNode(int mode, int id) {
  switch (mode) {
    case 0:  return (id < cNE + cNT) ? id : -1;
    case 1:  return (id >= cNE + cNT) ? (id - cNE) : -1;
    case 2:  return (id >= cNE && id < cNE + cNT) ? (id - cNE) : -1;
    default: return (id < cNE) ? id
                   : ((id >= cNE + cNT) ? (id - cNT) : -1);
  }
}

__device__ __forceinline__ float blockReduce128(float v, float* sh, int tid) {
  sh[tid] = v; __syncthreads();
  if (tid < 64) sh[tid] += sh[tid + 64]; __syncthreads();
  if (tid < 32) sh[tid] += sh[tid + 32]; __syncthreads();
  if (tid < 16) sh[tid] += sh[tid + 16]; __syncthreads();
  if (tid < 8)  sh[tid] += sh[tid + 8];  __syncthreads();
  if (tid < 4)  sh[tid] += sh[tid + 4];  __syncthreads();
  if (tid < 2)  sh[tid] += sh[tid + 2];  __syncthreads();
  if (tid < 1)  sh[tid] += sh[tid + 1];  __syncthreads();
  float r = sh[0]; __syncthreads();
  return r;
}
__device__ __forceinline__ float blockReduce256(float v, float* sh, int tid) {
  sh[tid] = v; __syncthreads();
  for (int s = 128; s > 0; s >>= 1) {
    if (tid < s) sh[tid] += sh[tid + s];
    __syncthreads();
  }
  float r = sh[0]; __syncthreads();
  return r;
}

// ---------------------------------------------------------------------------
// mask + CSR build
// ---------------------------------------------------------------------------
__global__ __launch_bounds__(256) void slot_build(const int* __restrict__ ids,
                                                  int* __restrict__ slot, int mode) {
  int i = blockIdx.x * 256 + threadIdx.x;
  if (i >= cNSRC) return;
  int node = mapNode(mode, ids[i]);
  if (node >= 0) atomicMin(&slot[node], i);
}

__global__ __launch_bounds__(256) void k_mark_nodes(const int* __restrict__ ids,
                                                    int* __restrict__ mark, int mode) {
  int i = blockIdx.x * 256 + threadIdx.x;
  if (i >= cNSRC) return;
  int node = mapNode(mode, ids[i]);
  if (node >= 0) mark[node] = 1;
}

__global__ __launch_bounds__(256) void k_mark_edges(const int* __restrict__ row,
                                                    const int* __restrict__ col, int nnz,
                                                    const int* __restrict__ slot,
                                                    int* __restrict__ mark) {
  int e = blockIdx.x * 256 + threadIdx.x;
  if (e >= nnz) return;
  int r = row[e];
  if (slot[r] < cNSRC) mark[col[e]] = 1;
}

__global__ __launch_bounds__(256) void k_hist(const int* __restrict__ row, int nnz,
                                              const int* __restrict__ mark,
                                              int* __restrict__ cnt) {
  int e = blockIdx.x * 256 + threadIdx.x;
  if (e >= nnz) return;
  int r = row[e];
  if (mark && !mark[r]) return;
  atomicAdd(&cnt[r], 1);
}

__global__ __launch_bounds__(256) void k_scan_block(const int* __restrict__ cnt, int n,
                                                    int* __restrict__ excl, int* __restrict__ bsum) {
  __shared__ int sh[256];
  int tid = threadIdx.x;
  int i = blockIdx.x * 256 + tid;
  int v = (i < n) ? cnt[i] : 0;
  sh[tid] = v; __syncthreads();
  for (int off = 1; off < 256; off <<= 1) {
    int t = (tid >= off) ? sh[tid - off] : 0;
    __syncthreads();
    sh[tid] += t;
    __syncthreads();
  }
  if (i < n) excl[i] = sh[tid] - v;
  if (tid == 255) bsum[blockIdx.x] = sh[255];
}

__global__ __launch_bounds__(512) void k_bsum_scan(int* __restrict__ bsum, int nb,
                                                   int* __restrict__ rowptr, int n) {
  __shared__ int sh[512];
  int tid = threadIdx.x;
  int v = (tid < nb) ? bsum[tid] : 0;
  sh[tid] = v; __syncthreads();
  for (int off = 1; off < 512; off <<= 1) {
    int t = (tid >= off) ? sh[tid - off] : 0;
    __syncthreads();
    sh[tid] += t;
    __syncthreads();
  }
  if (tid < nb) bsum[tid] = sh[tid] - v;
  if (tid == 511) rowptr[n] = sh[511];
}

__global__ __launch_bounds__(256) void k_scan_add(int* __restrict__ rowptr,
                                                  const int* __restrict__ bsum, int n,
                                                  int* __restrict__ fill) {
  int i = blockIdx.x * 256 + threadIdx.x;
  if (i < n) {
    int r = rowptr[i] + bsum[blockIdx.x];
    rowptr[i] = r;
    fill[i] = r;
  }
}

__global__ __launch_bounds__(256) void k_fill(const int* __restrict__ row, int nnz,
                                              const int* __restrict__ mark,
                                              int* __restrict__ fill, int* __restrict__ eidx) {
  int e = blockIdx.x * 256 + threadIdx.x;
  if (e >= nnz) return;
  int r = row[e];
  if (mark && !mark[r]) return;
  int pos = atomicAdd(&fill[r], 1);
  eidx[pos] = e;
}

// wave-per-row gather (2-wide unrolled)
__global__ __launch_bounds__(256) void k_gather(
    const int* __restrict__ rowptr, const int* __restrict__ eidx,
    const int* __restrict__ col, const float* __restrict__ val,
    const float* __restrict__ ea, const float* __restrict__ eb, int na,
    int nrows, const int* __restrict__ mark, float* __restrict__ out) {
  int r = blockIdx.x * 4 + (threadIdx.x >> 6);
  if (r >= nrows) return;
  if (mark && !mark[r]) return;
  int lane = threadIdx.x & 63;
  int p0 = rowptr[r], p1 = rowptr[r + 1];
  float ax = 0.f, ay = 0.f;
  int p = p0;
  for (; p + 2 <= p1; p += 2) {
    int e0 = eidx[p], e1 = eidx[p + 1];
    int c0 = col[e0], c1 = col[e1];
    float v0 = val[e0], v1 = val[e1];
    const float* s0 = (c0 < na) ? (ea + (size_t)c0 * cD) : (eb + (size_t)(c0 - na) * cD);
    const float* s1 = (c1 < na) ? (ea + (size_t)c1 * cD) : (eb + (size_t)(c1 - na) * cD);
    float2 x0 = *reinterpret_cast<const float2*>(s0 + lane * 2);
    float2 x1 = *reinterpret_cast<const float2*>(s1 + lane * 2);
    ax += v0 * x0.x + v1 * x1.x;
    ay += v0 * x0.y + v1 * x1.y;
  }
  if (p < p1) {
    int e = eidx[p];
    int c = col[e];
    float v = val[e];
    const float* s = (c < na) ? (ea + (size_t)c * cD) : (eb + (size_t)(c - na) * cD);
    float2 x = *reinterpret_cast<const float2*>(s + lane * 2);
    ax += v * x.x; ay += v * x.y;
  }
  float2 o; o.x = ax; o.y = ay;
  *reinterpret_cast<float2*>(out + (size_t)r * cD + lane * 2) = o;
}

__global__ __launch_bounds__(256) void k_rep(const int* __restrict__ ids,
                                             const int* __restrict__ slot, int mode,
                                             int* __restrict__ rep) {
  int i = blockIdx.x * 256 + threadIdx.x;
  if (i >= cNSRC) return;
  int node = mapNode(mode, ids[i]);
  rep[i] = (node >= 0 && slot[node] == i) ? node : -1;
}

__global__ __launch_bounds__(256) void k_gather_slot(
    const int* __restrict__ rowptr, const int* __restrict__ eidx,
    const int* __restrict__ col, const float* __restrict__ val,
    const float* __restrict__ x1, const int* __restrict__ rep,
    float* __restrict__ outc) {
  int i = blockIdx.x * 4 + (threadIdx.x >> 6);
  if (i >= cNSRC) return;
  int r = rep[i];
  if (r < 0) return;
  int lane = threadIdx.x & 63;
  int p0 = rowptr[r], p1 = rowptr[r + 1];
  float ax = 0.f, ay = 0.f;
  int p = p0;
  for (; p + 2 <= p1; p += 2) {
    int e0 = eidx[p], e1 = eidx[p + 1];
    int c0 = col[e0], c1 = col[e1];
    float v0 = val[e0], v1 = val[e1];
    float2 x0 = *reinterpret_cast<const float2*>(x1 + (size_t)c0 * cD + lane * 2);
    float2 x1v = *reinterpret_cast<const float2*>(x1 + (size_t)c1 * cD + lane * 2);
    ax += v0 * x0.x + v1 * x1v.x;
    ay += v0 * x0.y + v1 * x1v.y;
  }
  if (p < p1) {
    int e = eidx[p];
    int c = col[e];
    float v = val[e];
    float2 x = *reinterpret_cast<const float2*>(x1 + (size_t)c * cD + lane * 2);
    ax += v * x.x; ay += v * x.y;
  }
  float2 o; o.x = ax; o.y = ay;
  *reinterpret_cast<float2*>(outc + (size_t)i * cD + lane * 2) = o;
}

__global__ __launch_bounds__(128) void gather_ln(
    const int* __restrict__ ids, int mode,
    const float* __restrict__ ea, const float* __restrict__ eb, int na,
    const float* __restrict__ x1, const float* __restrict__ x2, const int* __restrict__ slot,
    const float* __restrict__ g, const float* __restrict__ bia, float* __restrict__ dst) {
  __shared__ float sh[128];
  int i = blockIdx.x;
  int tid = threadIdx.x;
  int id = ids[i];
  int node = mapNode(mode, id);
  if (node < 0) return;
  const float* x0 = (node < na) ? (ea + (size_t)node * cD) : (eb + (size_t)(node - na) * cD);
  int xi2 = slot ? slot[node] : node;
  float a = (x0[tid] + x1[(size_t)node * cD + tid] + x2[(size_t)xi2 * cD + tid]) * (1.0f / 3.0f);
  float s  = blockReduce128(a, sh, tid);
  float ss = blockReduce128(a * a, sh, tid);
  float mu = s * (1.0f / 128.0f);
  float var = ss * (1.0f / 128.0f) - mu * mu;
  float y = (a - mu) * rsqrtf(var + 1e-5f) * g[tid] + bia[tid];
  dst[(size_t)i * cD + tid] = y;
}

// ---------------------------------------------------------------------------
// bf16 MFMA GEMM: C[M,N] = A[M,K] @ Bt[N,K]^T, 128x128 tile, 4 waves
// epi 0: store bf16(acc+bias); epi 1: store bf16(ELU(acc+bias))
// ---------------------------------------------------------------------------
__global__ __launch_bounds__(256) void gemm_bf(
    const ushort* __restrict__ A, const ushort* __restrict__ Bt,
    int N, int K, const float* __restrict__ bias, ushort* __restrict__ Cbf, int epi) {
  __shared__ ushort As[128 * 40];
  __shared__ ushort Bs[128 * 40];
  const int bx = blockIdx.x, by = blockIdx.y;
  const int t = threadIdx.x;
  const int wv = t >> 6, lane = t & 63;
  const int wr = (wv >> 1) * 64, wc = (wv & 1) * 64;
  const int srow = t >> 1, shalf = t & 1;
  const ushort* Ag = A + (size_t)(by * 128 + srow) * K + shalf * 16;
  const ushort* Bg = Bt + (size_t)(bx * 128 + srow) * K + shalf * 16;
  uint4 ra0 = *reinterpret_cast<const uint4*>(Ag);
  uint4 ra1 = *reinterpret_cast<const uint4*>(Ag + 8);
  uint4 rb0 = *reinterpret_cast<const uint4*>(Bg);
  uint4 rb1 = *reinterpret_cast<const uint4*>(Bg + 8);
  f32x4 acc[4][4];
  const f32x4 z4 = {0.f, 0.f, 0.f, 0.f};
#pragma unroll
  for (int i = 0; i < 4; ++i)
#pragma unroll
    for (int j = 0; j < 4; ++j) acc[i][j] = z4;
  const int la = lane & 15, lk = (lane >> 4) * 8;
  const int sdst = srow * 40 + shalf * 16;
  for (int kt = 0; kt < K; kt += 32) {
    __syncthreads();
    *reinterpret_cast<uint4*>(&As[sdst])     = ra0;
    *reinterpret_cast<uint4*>(&As[sdst + 8]) = ra1;
    *reinterpret_cast<uint4*>(&Bs[sdst])     = rb0;
    *reinterpret_cast<uint4*>(&Bs[sdst + 8]) = rb1;
    __syncthreads();
    if (kt + 32 < K) {
      ra0 = *reinterpret_cast<const uint4*>(Ag + kt + 32);
      ra1 = *reinterpret_cast<const uint4*>(Ag + kt + 40);
      rb0 = *reinterpret_cast<const uint4*>(Bg + kt + 32);
      rb1 = *reinterpret_cast<const uint4*>(Bg + kt + 40);
    }
    short8v af[4], bfr[4];
#pragma unroll
    for (int i = 0; i < 4; ++i)
      af[i] = *reinterpret_cast<const short8v*>(&As[(wr + i * 16 + la) * 40 + lk]);
#pragma unroll
    for (int j = 0; j < 4; ++j)
      bfr[j] = *reinterpret_cast<const short8v*>(&Bs[(wc + j * 16 + la) * 40 + lk]);
#pragma unroll
    for (int i = 0; i < 4; ++i)
#pragma unroll
      for (int j = 0; j < 4; ++j)
        acc[i][j] = __builtin_amdgcn_mfma_f32_16x16x32_bf16(af[i], bfr[j], acc[i][j], 0, 0, 0);
  }
  const int r0 = by * 128 + wr + (lane >> 4) * 4;
  const int c0 = bx * 128 + wc + la;
#pragma unroll
  for (int i = 0; i < 4; ++i)
#pragma unroll
    for (int j = 0; j < 4; ++j) {
      int c = c0 + j * 16;
      float bv = bias[c];
#pragma unroll
      for (int q = 0; q < 4; ++q) {
        int r = r0 + i * 16 + q;
        float v = acc[i][j][q] + bv;
        if (epi == 1) v = (v > 0.0f) ? v : expm1f(v);
        Cbf[(size_t)r * N + c] = f2bf(v);
      }
    }
}

// ---------------------------------------------------------------------------
// Fused MoE: out[b,t] = sigmoid(mean_l sum_e gate[r,e]*(A@Bt_e + exp_b_e))
// ---------------------------------------------------------------------------
__global__ __launch_bounds__(256) void gemm_moe_out(
    const ushort* __restrict__ A, const ushort* __restrict__ Bt4,
    const float* __restrict__ expb, const float* __restrict__ gate,
    float* __restrict__ out) {
  __shared__ ushort As[128 * 40];
  __shared__ ushort Bs[128 * 40];
  __shared__ float gs[128][4];
  const int bx = blockIdx.x, by = blockIdx.y;
  const int t = threadIdx.x;
  const int wv = t >> 6, lane = t & 63;
  const int wr = (wv >> 1) * 64, wc = (wv & 1) * 64;
  const int srow = t >> 1, shalf = t & 1;
  const int la = lane & 15, lk = (lane >> 4) * 8;
  const int sdst = srow * 40 + shalf * 16;
  if (t < 128)
    *reinterpret_cast<float4*>(&gs[t][0]) =
        *reinterpret_cast<const float4*>(gate + (size_t)(by * 128 + t) * 4);
  const ushort* Ag = A + (size_t)(by * 128 + srow) * 1024 + shalf * 16;
  f32x4 rs[4][4];
  const f32x4 z4 = {0.f, 0.f, 0.f, 0.f};
#pragma unroll
  for (int i = 0; i < 4; ++i)
#pragma unroll
    for (int j = 0; j < 4; ++j) rs[i][j] = z4;
  for (int e = 0; e < 4; ++e) {
    const ushort* Bg = Bt4 + (size_t)e * 1048576 + (size_t)(bx * 128 + srow) * 1024 + shalf * 16;
    uint4 ra0 = *reinterpret_cast<const uint4*>(Ag);
    uint4 ra1 = *reinterpret_cast<const uint4*>(Ag + 8);
    uint4 rb0 = *reinterpret_cast<const uint4*>(Bg);
    uint4 rb1 = *reinterpret_cast<const uint4*>(Bg + 8);
    f32x4 acc[4][4];
#pragma unroll
    for (int i = 0; i < 4; ++i)
#pragma unroll
      for (int j = 0; j < 4; ++j) acc[i][j] = z4;
    for (int kt = 0; kt < 1024; kt += 32) {
      __syncthreads();
      *reinterpret_cast<uint4*>(&As[sdst])     = ra0;
      *reinterpret_cast<uint4*>(&As[sdst + 8]) = ra1;
      *reinterpret_cast<uint4*>(&Bs[sdst])     = rb0;
      *reinterpret_cast<uint4*>(&Bs[sdst + 8]) = rb1;
      __syncthreads();
      if (kt + 32 < 1024) {
        ra0 = *reinterpret_cast<const uint4*>(Ag + kt + 32);
        ra1 = *reinterpret_cast<const uint4*>(Ag + kt + 40);
        rb0 = *reinterpret_cast<const uint4*>(Bg + kt + 32);
        rb1 = *reinterpret_cast<const uint4*>(Bg + kt + 40);
      }
      short8v af[4], bfr[4];
#pragma unroll
      for (int i = 0; i < 4; ++i)
        af[i] = *reinterpret_cast<const short8v*>(&As[(wr + i * 16 + la) * 40 + lk]);
#pragma unroll
      for (int j = 0; j < 4; ++j)
        bfr[j] = *reinterpret_cast<const short8v*>(&Bs[(wc + j * 16 + la) * 40 + lk]);
#pragma unroll
      for (int i = 0; i < 4; ++i)
#pragma unroll
        for (int j = 0; j < 4; ++j)
          acc[i][j] = __builtin_amdgcn_mfma_f32_16x16x32_bf16(af[i], bfr[j], acc[i][j], 0, 0, 0);
    }
#pragma unroll
    for (int j = 0; j < 4; ++j) {
      float eb = expb[e * 1024 + bx * 128 + wc + j * 16 + la];
#pragma unroll
      for (int i = 0; i < 4; ++i)
#pragma unroll
        for (int q = 0; q < 4; ++q) {
          int rl = wr + (lane >> 4) * 4 + i * 16 + q;
          rs[i][j][q] += gs[rl][e] * (acc[i][j][q] + eb);
        }
    }
  }
#pragma unroll
  for (int i = 0; i < 4; ++i)
#pragma unroll
    for (int j = 0; j < 4; ++j) {
      float s = rs[i][j][0] + rs[i][j][1] + rs[i][j][2] + rs[i][j][3];
      s += __shfl_xor(s, 16);
      if (((lane >> 4) & 1) == 0) {
        int bl = (wr >> 3) + 2 * i + ((lane >> 4) >> 1);
        int c = bx * 128 + wc + j * 16 + la;
        out[(size_t)(by * 16 + bl) * 1024 + c] = 1.0f / (1.0f + expf(-s * 0.125f));
      }
    }
}

// ---------------------------------------------------------------------------
// Symmetric Gram contrastive kernel: triangular tiles of G = W @ W^T.
// Off-diag tiles contribute exp values to both row-sums and (via col reduce)
// the transposed row-sums. 2080 blocks.
// ---------------------------------------------------------------------------
__global__ __launch_bounds__(256) void gram_sym(
    const ushort* __restrict__ W, float* __restrict__ rsum,
    float* __restrict__ d11, float* __restrict__ d12, float* __restrict__ d22) {
  __shared__ ushort As[128 * 40];
  __shared__ ushort Bs[128 * 40];
  // triangular decode: blockIdx.x -> (bi, bj), bi <= bj
  int tt = blockIdx.x, bi = 0, cnt = 64;
  while (tt >= cnt) { tt -= cnt; ++bi; --cnt; }
  int bj = bi + tt;
  const bool diag = (bi == bj);
  const int t = threadIdx.x;
  const int wv = t >> 6, lane = t & 63;
  const int wr = (wv >> 1) * 64, wc = (wv & 1) * 64;
  const int srow = t >> 1, shalf = t & 1;
  const ushort* Ag = W + (size_t)(bi * 128 + srow) * 128 + shalf * 16;
  const ushort* Bg = W + (size_t)(bj * 128 + srow) * 128 + shalf * 16;
  uint4 ra0 = *reinterpret_cast<const uint4*>(Ag);
  uint4 ra1 = *reinterpret_cast<const uint4*>(Ag + 8);
  uint4 rb0 = *reinterpret_cast<const uint4*>(Bg);
  uint4 rb1 = *reinterpret_cast<const uint4*>(Bg + 8);
  f32x4 acc[4][4];
  const f32x4 z4 = {0.f, 0.f, 0.f, 0.f};
#pragma unroll
  for (int i = 0; i < 4; ++i)
#pragma unroll
    for (int j = 0; j < 4; ++j) acc[i][j] = z4;
  const int la = lane & 15, lk = (lane >> 4) * 8;
  const int sdst = srow * 40 + shalf * 16;
  for (int kt = 0; kt < 128; kt += 32) {
    __syncthreads();
    *reinterpret_cast<uint4*>(&As[sdst])     = ra0;
    *reinterpret_cast<uint4*>(&As[sdst + 8]) = ra1;
    *reinterpret_cast<uint4*>(&Bs[sdst])     = rb0;
    *reinterpret_cast<uint4*>(&Bs[sdst + 8]) = rb1;
    __syncthreads();
    if (kt + 32 < 128) {
      ra0 = *reinterpret_cast<const uint4*>(Ag + kt + 32);
      ra1 = *reinterpret_cast<const uint4*>(Ag + kt + 40);
      rb0 = *reinterpret_cast<const uint4*>(Bg + kt + 32);
      rb1 = *reinterpret_cast<const uint4*>(Bg + kt + 40);
    }
    short8v af[4], bfr[4];
#pragma unroll
    for (int i = 0; i < 4; ++i)
      af[i] = *reinterpret_cast<const short8v*>(&As[(wr + i * 16 + la) * 40 + lk]);
#pragma unroll
    for (int j = 0; j < 4; ++j)
      bfr[j] = *reinterpret_cast<const short8v*>(&Bs[(wc + j * 16 + la) * 40 + lk]);
#pragma unroll
    for (int i = 0; i < 4; ++i)
#pragma unroll
      for (int j = 0; j < 4; ++j)
        acc[i][j] = __builtin_amdgcn_mfma_f32_16x16x32_bf16(af[i], bfr[j], acc[i][j], 0, 0, 0);
  }
  const int r0 = bi * 128 + wr + (lane >> 4) * 4;
  const int c0 = bj * 128 + wc + la;
  constexpr float K2 = 2.8853900817779268f;   // 2 / ln(2)
  float rs[4][4];
  float cs[4] = {0.f, 0.f, 0.f, 0.f};
#pragma unroll
  for (int i = 0; i < 4; ++i)
#pragma unroll
    for (int q = 0; q < 4; ++q) rs[i][q] = 0.f;
#pragma unroll
  for (int i = 0; i < 4; ++i)
#pragma unroll
    for (int j = 0; j < 4; ++j)
#pragma unroll
      for (int q = 0; q < 4; ++q) {
        int r = r0 + i * 16 + q;
        int c = c0 + j * 16;
        float e = exp2f(K2 * acc[i][j][q]);
        rs[i][q] += e;
        cs[j] += e;
        if (c == r)        { if (r < 4096) d11[r] = e; else d22[r - 4096] = e; }
        if (c == r + 4096) d12[r] = e;
      }
  // row sums: reduce over la (the 16 column lanes)
#pragma unroll
  for (int m = 1; m < 16; m <<= 1)
#pragma unroll
    for (int i = 0; i < 4; ++i)
#pragma unroll
      for (int q = 0; q < 4; ++q) rs[i][q] += __shfl_xor(rs[i][q], m);
  float* rowdst = rsum + ((bj >= 32) ? 8192 : 0);
  if (la == 0) {
#pragma unroll
    for (int i = 0; i < 4; ++i)
#pragma unroll
      for (int q = 0; q < 4; ++q) atomAdd(&rowdst[r0 + i * 16 + q], rs[i][q]);
  }
  if (!diag) {
    // col sums: reduce over the 4 row groups (lane bits 4,5)
#pragma unroll
    for (int j = 0; j < 4; ++j) {
      cs[j] += __shfl_xor(cs[j], 16);
      cs[j] += __shfl_xor(cs[j], 32);
    }
    float* coldst = rsum + ((bi >= 32) ? 8192 : 0);
    if ((lane >> 4) == 0) {
#pragma unroll
      for (int j = 0; j < 4; ++j) atomAdd(&coldst[c0 + j * 16], cs[j]);
    }
  }
}

__global__ __launch_bounds__(256) void cl_row(
    const float* __restrict__ rsum, const float* __restrict__ d11,
    const float* __restrict__ d12, const float* __restrict__ d22,
    float* __restrict__ cl_sum) {
  __shared__ float sh[256];
  int i = blockIdx.x * 256 + threadIdx.x;
  float denA = rsum[i] + rsum[8192 + i] - d11[i];
  float denB = rsum[8192 + 4096 + i] + rsum[4096 + i] - d22[i];
  float l = 0.5f * (logf(denA) + logf(denB)) - logf(d12[i]);
  float s = blockReduce256(l, sh, threadIdx.x);
  if (threadIdx.x == 0) atomAdd(cl_sum, s);
}

// weight transpose + bf16 convert: Bt[n*K+k] = bf16(W[k*N+n])
__global__ __launch_bounds__(256) void k_wt_bt(const float* __restrict__ W,
                                               ushort* __restrict__ Bt, int K, int N) {
  __shared__ float tile[32][33];
  int n0 = blockIdx.x * 32, k0 = blockIdx.y * 32;
  int tx = threadIdx.x & 31, ty = threadIdx.x >> 5;
#pragma unroll
  for (int i = 0; i < 4; ++i)
    tile[ty + 8 * i][tx] = W[(size_t)(k0 + ty + 8 * i) * N + n0 + tx];
  __syncthreads();
#pragma unroll
  for (int i = 0; i < 4; ++i)
    Bt[(size_t)(n0 + ty + 8 * i) * K + k0 + tx] = f2bf(tile[tx][ty + 8 * i]);
}

// S1|S2 (f32) -> SB bf16 [8192][128]
__global__ __launch_bounds__(256) void s_to_bf(const float* __restrict__ s1,
                                               const float* __restrict__ s2,
                                               ushort* __restrict__ sb) {
  int idx = blockIdx.x * 256 + threadIdx.x;   // 1,048,576 total
  float v = (idx < 524288) ? s1[idx] : s2[idx - 524288];
  sb[idx] = f2bf(v);
}

// in-place bf16 row normalize
__global__ __launch_bounds__(128) void rownorm_bf2(ushort* __restrict__ w) {
  __shared__ float sh[128];
  int i = blockIdx.x, tid = threadIdx.x;
  float v = bf2f(w[(size_t)i * cD + tid]);
  float ss = blockReduce128(v * v, sh, tid);
  float n = fmaxf(sqrtf(ss), 1e-12f);
  w[(size_t)i * cD + tid] = f2bf(v / n);
}

// ---------------------------------------------------------------------------
// message / losses / MHA
// ---------------------------------------------------------------------------
__global__ __launch_bounds__(256) void emb_sum_k(
    const float* __restrict__ s1, const float* __restrict__ s2,
    const float* __restrict__ relation, const int* __restrict__ etype, float* __restrict__ out) {
  __shared__ float sh[256];
  int idx = blockIdx.x * 256 + threadIdx.x;
  int i = idx >> 8, j = idx & 255;
  float a = (j < 128) ? s1[(size_t)i * 128 + j] : s2[(size_t)i * 128 + j - 128];
  int et = etype[i];
  float r = relation[(size_t)(et % cNR) * 256 + j];
  float t = blockReduce256(a * a + r * r, sh, threadIdx.x);
  if (threadIdx.x == 0) atomAdd(out, t);
}

__global__ __launch_bounds__(256) void msg_build(
    const float* __restrict__ s1, const float* __restrict__ s2,
    const float* __restrict__ relation, const int* __restrict__ etype,
    ushort* __restrict__ msg) {
  int idx = blockIdx.x * 256 + threadIdx.x;
  int i = idx >> 8, j = idx & 255;
  int et = etype[i];
  float sign = (et >= cNR) ? -1.0f : 1.0f;
  float r = relation[(size_t)(et % cNR) * 256 + j] * sign;
  float s = (j < 128) ? s1[(size_t)i * 128 + j] : s2[(size_t)i * 128 + j - 128];
  msg[idx] = f2bf(fmaxf(s + r, 0.0f));
}

// fused-QKV attention: qkv [4096][3072] (Q|K|V per row), o [4096][1024] bf16
__global__ __launch_bounds__(64) void mha_attn(
    const ushort* __restrict__ qkv, ushort* __restrict__ o) {
  __shared__ float qs[8][132], ks[8][132], vs[8][132];
  __shared__ float att[8][8];
  int bh = blockIdx.x;
  int b = bh >> 3, h = bh & 7;
  int tid = threadIdx.x;
  for (int u = tid; u < 256; u += 64) {
    int l = u >> 5;
    int d4 = (u & 31) * 4;
    size_t base = (size_t)(b * 8 + l) * 3072 + h * 128 + d4;
    ushort4 qv = *reinterpret_cast<const ushort4*>(qkv + base);
    ushort4 kv = *reinterpret_cast<const ushort4*>(qkv + base + 1024);
    ushort4 vv = *reinterpret_cast<const ushort4*>(qkv + base + 2048);
    qs[l][d4] = bf2f(qv.x); qs[l][d4 + 1] = bf2f(qv.y);
    qs[l][d4 + 2] = bf2f(qv.z); qs[l][d4 + 3] = bf2f(qv.w);
    ks[l][d4] = bf2f(kv.x); ks[l][d4 + 1] = bf2f(kv.y);
    ks[l][d4 + 2] = bf2f(kv.z); ks[l][d4 + 3] = bf2f(kv.w);
    vs[l][d4] = bf2f(vv.x); vs[l][d4 + 1] = bf2f(vv.y);
    vs[l][d4 + 2] = bf2f(vv.z); vs[l][d4 + 3] = bf2f(vv.w);
  }
  __syncthreads();
  int l = tid >> 3, m = tid & 7;
  const float4* qp = reinterpret_cast<const float4*>(&qs[l][0]);
  const float4* kp = reinterpret_cast<const float4*>(&ks[m][0]);
  float s = 0;
#pragma unroll
  for (int d4 = 0; d4 < 32; ++d4) {
    float4 a = qp[d4], bb = kp[d4];
    s += a.x * bb.x + a.y * bb.y + a.z * bb.z + a.w * bb.w;
  }
  s *= 0.08838834764831845f;
  float mx = s;
  for (int off = 1; off < 8; off <<= 1) mx = fmaxf(mx, __shfl_xor(mx, off, 8));
  float p = expf(s - mx);
  float sum = p;
  for (int off = 1; off < 8; off <<= 1) sum += __shfl_xor(sum, off, 8);
  att[l][m] = p / sum;
  __syncthreads();
  for (int u = tid; u < 1024; u += 64) {
    int ll = u >> 7, d = u & 127;
    float acc = 0;
#pragma unroll
    for (int mm = 0; mm < 8; ++mm) acc += att[ll][mm] * vs[mm][d];
    o[(size_t)(b * 8 + ll) * 1024 + h * 128 + d] = f2bf(acc);
  }
}

__global__ __launch_bounds__(64) void gate_k(
    const ushort* __restrict__ o, const float* __restrict__ gw, float* __restrict__ gate) {
  int i = blockIdx.x;
  int lane = threadIdx.x;
  float g[4] = {0, 0, 0, 0};
  for (int d = lane; d < cT; d += 64) {
    float ov = bf2f(o[(size_t)i * cT + d]);
    g[0] += ov * gw[d * 4 + 0];
    g[1] += ov * gw[d * 4 + 1];
    g[2] += ov * gw[d * 4 + 2];
    g[3] += ov * gw[d * 4 + 3];
  }
#pragma unroll
  for (int off = 32; off > 0; off >>= 1)
#pragma unroll
    for (int e = 0; e < 4; ++e) g[e] += __shfl_down(g[e], off);
  if (lane == 0) {
    float mx = fmaxf(fmaxf(g[0], g[1]), fmaxf(g[2], g[3]));
    float ex[4], sum = 0;
#pragma unroll
    for (int e = 0; e < 4; ++e) { ex[e] = expf(g[e] - mx); sum += ex[e]; }
#pragma unroll
    for (int e = 0; e < 4; ++e) gate[(size_t)i * 4 + e] = ex[e] / sum;
  }
}

__global__ void finalize_k(const float* __restrict__ scal, float* __restrict__ out_aux) {
  float cl = scal[0] * (1.0f / cNSRC);
  float emb = cDECAY * 0.5f * scal[1] * (1.0f / cNSRC);
  out_aux[0] = cCLW * cl + emb;
}

// ---------------------------------------------------------------------------
// Launch
// ---------------------------------------------------------------------------
extern "C" void kernel_launch(void* const* d_in, const int* in_sizes, int n_in,
                              void* d_out, int out_size, void* d_ws, size_t ws_size,
                              hipStream_t stream) {
  (void)in_sizes; (void)n_in; (void)out_size; (void)ws_size;
  const float* entity   = (const float*)d_in[0];
  const float* type_e   = (const float*)d_in[1];
  const float* cluster  = (const float*)d_in[2];
  const float* relation = (const float*)d_in[3];
  const float* ln_g  = (const float*)d_in[4];
  const float* ln_b  = (const float*)d_in[5];
  const float* cl_w1 = (const float*)d_in[6];
  const float* cl_b1 = (const float*)d_in[7];
  const float* cl_w2 = (const float*)d_in[8];
  const float* cl_b2 = (const float*)d_in[9];
  const float* fc_w  = (const float*)d_in[10];
  const float* fc_b  = (const float*)d_in[11];
  const float* wq = (const float*)d_in[12];
  const float* bq = (const float*)d_in[13];
  const float* wk = (const float*)d_in[14];
  const float* bk = (const float*)d_in[15];
  const float* wv = (const float*)d_in[16];
  const float* bv = (const float*)d_in[17];
  const float* wo = (const float*)d_in[18];
  const float* bo = (const float*)d_in[19];
  const float* gate_w = (const float*)d_in[20];
  const float* exp_w  = (const float*)d_in[21];
  const float* exp_b  = (const float*)d_in[22];
  const float* e2t_val = (const float*)d_in[23];
  const float* t2c_val = (const float*)d_in[24];
  const float* e2c_val = (const float*)d_in[25];
  const int* e2t_row = (const int*)d_in[26];
  const int* e2t_col = (const int*)d_in[27];
  const int* t2c_row = (const int*)d_in[28];
  const int* t2c_col = (const int*)d_in[29];
  const int* e2c_row = (const int*)d_in[30];
  const int* e2c_col = (const int*)d_in[31];
  const int* src_ids = (const int*)d_in[32];
  const int* etype   = (const int*)d_in[33];

  float* ws = (float*)d_ws;
  float* S1 = ws + F_S1;
  float* S2 = ws + F_S2;
  ushort* Wbf = (ushort*)(ws + F_PT);   // final normalized z (bf16) [8192][128]
  ushort* P1bf = (ushort*)(ws + F_Z1);
  ushort* SBbf = (ushort*)(ws + F_Z2);
  ushort* MSGbf = (ushort*)(ws + F_MSG);
  float* GATE = ws + F_GATE;
  float* SCAL = ws + F_SCAL;
  float* RS   = ws + F_RS;
  float* BQKV = ws + F_RS;              // reused after cl_row
  float* D11  = ws + F_D11;
  float* D12  = ws + F_D12;
  float* D22  = ws + F_D22;
  float* X1F  = ws + G_X1F;
  float* X2C  = ws + G_X2C;
  int*   MARK = (int*)(ws + G_X2C);
  int*   SLOT = (int*)(ws + G_SLOT);
  int*   REP  = (int*)(ws + G_REP);
  int*   RP   = (int*)(ws + G_RP);
  int*   FILL = (int*)(ws + G_FILL);
  int*   EIDX = (int*)(ws + G_EIDX);
  float* X1T  = ws + G_X1T;
  float* X2T  = ws + G_X2T;
  int*   BSUM = (int*)(ws + G_BSUM);
  ushort* PB   = (ushort*)(ws + A_U0);   // predict; later attn-out
  ushort* QKV  = (ushort*)(ws + A_U1);   // [4096][3072]
  ushort* OB   = (ushort*)(ws + A_U1);   // o-proj out (after QKV consumed)
  ushort* WBT  = (ushort*)(ws + A_WBT);

  hipMemsetAsync(SCAL, 0, 2 * sizeof(float), stream);
  hipMemsetAsync(RS, 0, (16384 + 3 * 4096) * sizeof(float), stream);

  // masked GCN
  auto run_gcn_masked = [&](const int* row, const int* col, const float* val, int nnz, int nn,
                            const float* ea, const float* eb, int na, int mode,
                            float* dst) {
    int nb = (nn + 255) / 256;
    int gEdge = (nnz + 255) / 256;
    hipMemsetAsync(SLOT, 0x7F, (size_t)nn * sizeof(int), stream);
    slot_build<<<16, 256, 0, stream>>>(src_ids, SLOT, mode);
    hipMemsetAsync(MARK, 0, (size_t)nn * sizeof(int), stream);
    k_mark_nodes<<<16, 256, 0, stream>>>(src_ids, MARK, mode);
    k_mark_edges<<<gEdge, 256, 0, stream>>>(row, col, nnz, SLOT, MARK);
    hipMemsetAsync(FILL, 0, (size_t)nn * sizeof(int), stream);
    k_hist<<<gEdge, 256, 0, stream>>>(row, nnz, MARK, FILL);
    k_scan_block<<<nb, 256, 0, stream>>>(FILL, nn, RP, BSUM);
    k_bsum_scan<<<1, 512, 0, stream>>>(BSUM, nb, RP, nn);
    k_scan_add<<<nb, 256, 0, stream>>>(RP, BSUM, nn, FILL);
    k_fill<<<gEdge, 256, 0, stream>>>(row, nnz, MARK, FILL, EIDX);
    k_rep<<<16, 256, 0, stream>>>(src_ids, SLOT, mode, REP);
    k_gather<<<(nn + 3) / 4, 256, 0, stream>>>(RP, EIDX, col, val, ea, eb, na, nn, MARK, X1F);
    k_gather_slot<<<cNSRC / 4, 256, 0, stream>>>(RP, EIDX, col, val, X1F, REP, X2C);
    gather_ln<<<cNSRC, 128, 0, stream>>>(src_ids, mode, ea, eb, na, X1F, X2C, SLOT,
                                         ln_g, ln_b, dst);
  };

  run_gcn_masked(e2t_row, e2t_col, e2t_val, cNNZ_E2T, cNN_E2T, entity, type_e, cNE, 0, S1);
  run_gcn_masked(e2c_row, e2c_col, e2c_val, cNNZ_E2C, cNN_E2C, entity, cluster, cNE, 3, S2);

  // ---- t2c: tiny, both layers full ----
  {
    int nn = cNN_T2C, nb = (nn + 255) / 256, gEdge = (cNNZ_T2C + 255) / 256;
    hipMemsetAsync(FILL, 0, (size_t)nn * sizeof(int), stream);
    k_hist<<<gEdge, 256, 0, stream>>>(t2c_row, cNNZ_T2C, nullptr, FILL);
    k_scan_block<<<nb, 256, 0, stream>>>(FILL, nn, RP, BSUM);
    k_bsum_scan<<<1, 512, 0, stream>>>(BSUM, nb, RP, nn);
    k_scan_add<<<nb, 256, 0, stream>>>(RP, BSUM, nn, FILL);
    k_fill<<<gEdge, 256, 0, stream>>>(t2c_row, cNNZ_T2C, nullptr, FILL, EIDX);
    k_gather<<<(nn + 3) / 4, 256, 0, stream>>>(RP, EIDX, t2c_col, t2c_val,
                                               type_e, cluster, cNT, nn, nullptr, X1T);
    k_gather<<<(nn + 3) / 4, 256, 0, stream>>>(RP, EIDX, t2c_col, t2c_val,
                                               X1T, X1T, 1 << 30, nn, nullptr, X2T);
    gather_ln<<<cNSRC, 128, 0, stream>>>(src_ids, 1, type_e, cluster, cNT, X1T, X2T, nullptr,
                                         ln_g, ln_b, S1);
    gather_ln<<<cNSRC, 128, 0, stream>>>(src_ids, 2, type_e, cluster, cNT, X1T, X2T, nullptr,
                                         ln_g, ln_b, S2);
  }

  // ================= contrastive loss (bf16 MFMA path) =================
  ushort* W1T = WBT;             // [128][128]
  ushort* W2T = WBT + 16384;
  k_wt_bt<<<dim3(4, 4), 256, 0, stream>>>(cl_w1, W1T, cD, cD);
  k_wt_bt<<<dim3(4, 4), 256, 0, stream>>>(cl_w2, W2T, cD, cD);
  s_to_bf<<<4096, 256, 0, stream>>>(S1, S2, SBbf);
  gemm_bf<<<dim3(1, 64), 256, 0, stream>>>(SBbf, W1T, cD, cD, cl_b1, P1bf, 1);
  gemm_bf<<<dim3(1, 64), 256, 0, stream>>>(P1bf, W2T, cD, cD, cl_b2, Wbf, 0);
  rownorm_bf2<<<2 * cNSRC, 128, 0, stream>>>(Wbf);
  gram_sym<<<2080, 256, 0, stream>>>(Wbf, RS, D11, D12, D22);
  cl_row<<<16, 256, 0, stream>>>(RS, D11, D12, D22, SCAL);
  emb_sum_k<<<cNSRC, 256, 0, stream>>>(S1, S2, relation, etype, SCAL + 1);

  // ================= message + predict =================
  msg_build<<<cNSRC, 256, 0, stream>>>(S1, S2, relation, etype, MSGbf);
  k_wt_bt<<<dim3(cT / 32, 256 / 32), 256, 0, stream>>>(fc_w, WBT, 256, cT);
  gemm_bf<<<dim3(cT / 128, cNSRC / 128), 256, 0, stream>>>(MSGbf, WBT, cT, 256, fc_b, PB, 0);

  // ================= MHA: fused QKV =================
  k_wt_bt<<<dim3(32, 32), 256, 0, stream>>>(wq, WBT, cT, cT);
  k_wt_bt<<<dim3(32, 32), 256, 0, stream>>>(wk, WBT + 1048576, cT, cT);
  k_wt_bt<<<dim3(32, 32), 256, 0, stream>>>(wv, WBT + 2 * 1048576, cT, cT);
  hipMemcpyAsync(BQKV,        bq, cT * sizeof(float), hipMemcpyDeviceToDevice, stream);
  hipMemcpyAsync(BQKV + 1024, bk, cT * sizeof(float), hipMemcpyDeviceToDevice, stream);
  hipMemcpyAsync(BQKV + 2048, bv, cT * sizeof(float), hipMemcpyDeviceToDevice, stream);
  gemm_bf<<<dim3(3072 / 128, cNSRC / 128), 256, 0, stream>>>(PB, WBT, 3072, cT, BQKV, QKV, 0);
  mha_attn<<<cB * 8, 64, 0, stream>>>(QKV, PB);                 // attn-out -> A_U0
  k_wt_bt<<<dim3(32, 32), 256, 0, stream>>>(wo, WBT, cT, cT);
  gemm_bf<<<dim3(cT / 128, cNSRC / 128), 256, 0, stream>>>(PB, WBT, cT, cT, bo, OB, 0);

  // ================= fused MoE + mean + sigmoid =================
  gate_k<<<cNSRC, 64, 0, stream>>>(OB, gate_w, GATE);
  for (int e = 0; e < cE; ++e)
    k_wt_bt<<<dim3(32, 32), 256, 0, stream>>>(exp_w + (size_t)e * cT * cT,
                                              WBT + (size_t)e * 1048576, cT, cT);
  gemm_moe_out<<<dim3(8, 32), 256, 0, stream>>>(OB, WBT, exp_b, GATE, (float*)d_out);

  finalize_k<<<1, 1, 0, stream>>>(SCAL, (float*)d_out + (size_t)cB * cT);
}

// Round 6
// 621.326 us; speedup vs baseline: 8.8276x; 1.0104x over previous
//
#include <hip/hip_runtime.h>
#include <hip/hip_bf16.h>
#include <cmath>

// ---------------------------------------------------------------------------
// Problem constants (fixed shapes)
// ---------------------------------------------------------------------------
constexpr int cNE = 100000, cNT = 1024, cNC = 128, cD = 128, cNR = 500;
constexpr int cB = 512, cNSRC = 4096, cT = 1024, cE = 4;
constexpr int cNNZ_E2T = 1000000, cNNZ_T2C = 50000, cNNZ_E2C = 500000;
constexpr float cDECAY = 1e-4f, cCLW = 0.1f;
constexpr int cNN_E2T = cNE + cNT;     // 101024
constexpr int cNN_E2C = cNE + cNC;     // 100128
constexpr int cNN_T2C = cNT + cNC;     // 1152

// ---------------------------------------------------------------------------
// Workspace layout (FLOAT units)
// ---------------------------------------------------------------------------
constexpr size_t F_S1   = 0;                          // f32 4096x128
constexpr size_t F_S2   = F_S1 + 524288;
constexpr size_t F_PT   = F_S2 + 524288;              // bf16 W [8192][128] (Z/normed)
constexpr size_t F_Z1   = F_PT + 524288;              // bf16 P1 [8192][128]
constexpr size_t F_Z2   = F_Z1 + 524288;              // bf16 SB [8192][128]
constexpr size_t F_MSG  = F_Z2 + 524288;              // bf16 4096x256
constexpr size_t F_GATE = F_MSG + 524288;             // f32 GSUM [512][4]
constexpr size_t F_SCAL = F_GATE + 16384;
constexpr size_t F_RS   = F_SCAL + 64;                // f32 [2][8192] gram sums; later bias_qkv
constexpr size_t F_D11  = F_RS + 16384;               // f32 [4096]
constexpr size_t F_D12  = F_D11 + 4096;
constexpr size_t F_D22  = F_D12 + 4096;
constexpr size_t F_U    = F_D22 + 4096;               // union base
// --- GCN phase ---
constexpr size_t G_X1F  = F_U;                        // f32 101024x128
constexpr size_t G_X2C  = G_X1F + 12931072;           // f32 4096x128 (also MARK)
constexpr size_t G_SLOT = G_X2C + 524288;
constexpr size_t G_REP  = G_SLOT + 101376;
constexpr size_t G_RP   = G_REP + 4096;
constexpr size_t G_FILL = G_RP + 101376;
constexpr size_t G_EIDX = G_FILL + 101376;
constexpr size_t G_X1T  = G_EIDX + 1000000;
constexpr size_t G_X2T  = G_X1T + 147456;
constexpr size_t G_BSUM = G_X2T + 147456;
// --- activation phase ---
constexpr size_t A_U0  = F_U;                 // predict bf16; attn-out; then AE bf16 [4][512][1024]
constexpr size_t A_U1  = F_U + 2097152;       // QKV bf16 [4096][3072] spans U1..U3; then O
constexpr size_t A_WBT = F_U + 4 * 2097152;   // bf16 weight^T scratch

typedef __attribute__((ext_vector_type(8))) short short8v;
typedef __attribute__((ext_vector_type(4))) float f32x4;

// ---------------------------------------------------------------------------
// Helpers
// ---------------------------------------------------------------------------
__device__ __forceinline__ void atomAdd(float* p, float v) {
  __hip_atomic_fetch_add(p, v, __ATOMIC_RELAXED, __HIP_MEMORY_SCOPE_AGENT);
}
__device__ __forceinline__ ushort f2bf(float f) {
  __hip_bfloat16 h = __float2bfloat16(f);
  return *reinterpret_cast<ushort*>(&h);
}
__device__ __forceinline__ float bf2f(ushort u) {
  __hip_bfloat16 h; *reinterpret_cast<ushort*>(&h) = u;
  return __bfloat162float(h);
}

__device__ __forceinline__ int mapNode(int mode, int id) {
  switch (mode) {
    case 0:  return (id < cNE + cNT) ? id : -1;
    case 1:  return (id >= cNE + cNT) ? (id - cNE) : -1;
    case 2:  return (id >= cNE && id < cNE + cNT) ? (id - cNE) : -1;
    default: return (id < cNE) ? id
                   : ((id >= cNE + cNT) ? (id - cNT) : -1);
  }
}

__device__ __forceinline__ float blockReduce128(float v, float* sh, int tid) {
  sh[tid] = v; __syncthreads();
  if (tid < 64) sh[tid] += sh[tid + 64]; __syncthreads();
  if (tid < 32) sh[tid] += sh[tid + 32]; __syncthreads();
  if (tid < 16) sh[tid] += sh[tid + 16]; __syncthreads();
  if (tid < 8)  sh[tid] += sh[tid + 8];  __syncthreads();
  if (tid < 4)  sh[tid] += sh[tid + 4];  __syncthreads();
  if (tid < 2)  sh[tid] += sh[tid + 2];  __syncthreads();
  if (tid < 1)  sh[tid] += sh[tid + 1];  __syncthreads();
  float r = sh[0]; __syncthreads();
  return r;
}
__device__ __forceinline__ float blockReduce256(float v, float* sh, int tid) {
  sh[tid] = v; __syncthreads();
  for (int s = 128; s > 0; s >>= 1) {
    if (tid < s) sh[tid] += sh[tid + s];
    __syncthreads();
  }
  float r = sh[0]; __syncthreads();
  return r;
}

// ---------------------------------------------------------------------------
// mask + CSR build
// ---------------------------------------------------------------------------
__global__ __launch_bounds__(256) void slot_build(const int* __restrict__ ids,
                                                  int* __restrict__ slot, int mode) {
  int i = blockIdx.x * 256 + threadIdx.x;
  if (i >= cNSRC) return;
  int node = mapNode(mode, ids[i]);
  if (node >= 0) atomicMin(&slot[node], i);
}

__global__ __launch_bounds__(256) void k_mark_nodes(const int* __restrict__ ids,
                                                    int* __restrict__ mark, int mode) {
  int i = blockIdx.x * 256 + threadIdx.x;
  if (i >= cNSRC) return;
  int node = mapNode(mode, ids[i]);
  if (node >= 0) mark[node] = 1;
}

__global__ __launch_bounds__(256) void k_mark_edges(const int* __restrict__ row,
                                                    const int* __restrict__ col, int nnz,
                                                    const int* __restrict__ slot,
                                                    int* __restrict__ mark) {
  int e = blockIdx.x * 256 + threadIdx.x;
  if (e >= nnz) return;
  int r = row[e];
  if (slot[r] < cNSRC) mark[col[e]] = 1;
}

__global__ __launch_bounds__(256) void k_hist(const int* __restrict__ row, int nnz,
                                              const int* __restrict__ mark,
                                              int* __restrict__ cnt) {
  int e = blockIdx.x * 256 + threadIdx.x;
  if (e >= nnz) return;
  int r = row[e];
  if (mark && !mark[r]) return;
  atomicAdd(&cnt[r], 1);
}

__global__ __launch_bounds__(256) void k_scan_block(const int* __restrict__ cnt, int n,
                                                    int* __restrict__ excl, int* __restrict__ bsum) {
  __shared__ int sh[256];
  int tid = threadIdx.x;
  int i = blockIdx.x * 256 + tid;
  int v = (i < n) ? cnt[i] : 0;
  sh[tid] = v; __syncthreads();
  for (int off = 1; off < 256; off <<= 1) {
    int t = (tid >= off) ? sh[tid - off] : 0;
    __syncthreads();
    sh[tid] += t;
    __syncthreads();
  }
  if (i < n) excl[i] = sh[tid] - v;
  if (tid == 255) bsum[blockIdx.x] = sh[255];
}

__global__ __launch_bounds__(512) void k_bsum_scan(int* __restrict__ bsum, int nb,
                                                   int* __restrict__ rowptr, int n) {
  __shared__ int sh[512];
  int tid = threadIdx.x;
  int v = (tid < nb) ? bsum[tid] : 0;
  sh[tid] = v; __syncthreads();
  for (int off = 1; off < 512; off <<= 1) {
    int t = (tid >= off) ? sh[tid - off] : 0;
    __syncthreads();
    sh[tid] += t;
    __syncthreads();
  }
  if (tid < nb) bsum[tid] = sh[tid] - v;
  if (tid == 511) rowptr[n] = sh[511];
}

__global__ __launch_bounds__(256) void k_scan_add(int* __restrict__ rowptr,
                                                  const int* __restrict__ bsum, int n,
                                                  int* __restrict__ fill) {
  int i = blockIdx.x * 256 + threadIdx.x;
  if (i < n) {
    int r = rowptr[i] + bsum[blockIdx.x];
    rowptr[i] = r;
    fill[i] = r;
  }
}

__global__ __launch_bounds__(256) void k_fill(const int* __restrict__ row, int nnz,
                                              const int* __restrict__ mark,
                                              int* __restrict__ fill, int* __restrict__ eidx) {
  int e = blockIdx.x * 256 + threadIdx.x;
  if (e >= nnz) return;
  int r = row[e];
  if (mark && !mark[r]) return;
  int pos = atomicAdd(&fill[r], 1);
  eidx[pos] = e;
}

// wave-per-row gather (2-wide unrolled)
__global__ __launch_bounds__(256) void k_gather(
    const int* __restrict__ rowptr, const int* __restrict__ eidx,
    const int* __restrict__ col, const float* __restrict__ val,
    const float* __restrict__ ea, const float* __restrict__ eb, int na,
    int nrows, const int* __restrict__ mark, float* __restrict__ out) {
  int r = blockIdx.x * 4 + (threadIdx.x >> 6);
  if (r >= nrows) return;
  if (mark && !mark[r]) return;
  int lane = threadIdx.x & 63;
  int p0 = rowptr[r], p1 = rowptr[r + 1];
  float ax = 0.f, ay = 0.f;
  int p = p0;
  for (; p + 2 <= p1; p += 2) {
    int e0 = eidx[p], e1 = eidx[p + 1];
    int c0 = col[e0], c1 = col[e1];
    float v0 = val[e0], v1 = val[e1];
    const float* s0 = (c0 < na) ? (ea + (size_t)c0 * cD) : (eb + (size_t)(c0 - na) * cD);
    const float* s1 = (c1 < na) ? (ea + (size_t)c1 * cD) : (eb + (size_t)(c1 - na) * cD);
    float2 x0 = *reinterpret_cast<const float2*>(s0 + lane * 2);
    float2 x1 = *reinterpret_cast<const float2*>(s1 + lane * 2);
    ax += v0 * x0.x + v1 * x1.x;
    ay += v0 * x0.y + v1 * x1.y;
  }
  if (p < p1) {
    int e = eidx[p];
    int c = col[e];
    float v = val[e];
    const float* s = (c < na) ? (ea + (size_t)c * cD) : (eb + (size_t)(c - na) * cD);
    float2 x = *reinterpret_cast<const float2*>(s + lane * 2);
    ax += v * x.x; ay += v * x.y;
  }
  float2 o; o.x = ax; o.y = ay;
  *reinterpret_cast<float2*>(out + (size_t)r * cD + lane * 2) = o;
}

__global__ __launch_bounds__(256) void k_rep(const int* __restrict__ ids,
                                             const int* __restrict__ slot, int mode,
                                             int* __restrict__ rep) {
  int i = blockIdx.x * 256 + threadIdx.x;
  if (i >= cNSRC) return;
  int node = mapNode(mode, ids[i]);
  rep[i] = (node >= 0 && slot[node] == i) ? node : -1;
}

__global__ __launch_bounds__(256) void k_gather_slot(
    const int* __restrict__ rowptr, const int* __restrict__ eidx,
    const int* __restrict__ col, const float* __restrict__ val,
    const float* __restrict__ x1, const int* __restrict__ rep,
    float* __restrict__ outc) {
  int i = blockIdx.x * 4 + (threadIdx.x >> 6);
  if (i >= cNSRC) return;
  int r = rep[i];
  if (r < 0) return;
  int lane = threadIdx.x & 63;
  int p0 = rowptr[r], p1 = rowptr[r + 1];
  float ax = 0.f, ay = 0.f;
  int p = p0;
  for (; p + 2 <= p1; p += 2) {
    int e0 = eidx[p], e1 = eidx[p + 1];
    int c0 = col[e0], c1 = col[e1];
    float v0 = val[e0], v1 = val[e1];
    float2 x0 = *reinterpret_cast<const float2*>(x1 + (size_t)c0 * cD + lane * 2);
    float2 x1v = *reinterpret_cast<const float2*>(x1 + (size_t)c1 * cD + lane * 2);
    ax += v0 * x0.x + v1 * x1v.x;
    ay += v0 * x0.y + v1 * x1v.y;
  }
  if (p < p1) {
    int e = eidx[p];
    int c = col[e];
    float v = val[e];
    float2 x = *reinterpret_cast<const float2*>(x1 + (size_t)c * cD + lane * 2);
    ax += v * x.x; ay += v * x.y;
  }
  float2 o; o.x = ax; o.y = ay;
  *reinterpret_cast<float2*>(outc + (size_t)i * cD + lane * 2) = o;
}

__global__ __launch_bounds__(128) void gather_ln(
    const int* __restrict__ ids, int mode,
    const float* __restrict__ ea, const float* __restrict__ eb, int na,
    const float* __restrict__ x1, const float* __restrict__ x2, const int* __restrict__ slot,
    const float* __restrict__ g, const float* __restrict__ bia, float* __restrict__ dst) {
  __shared__ float sh[128];
  int i = blockIdx.x;
  int tid = threadIdx.x;
  int id = ids[i];
  int node = mapNode(mode, id);
  if (node < 0) return;
  const float* x0 = (node < na) ? (ea + (size_t)node * cD) : (eb + (size_t)(node - na) * cD);
  int xi2 = slot ? slot[node] : node;
  float a = (x0[tid] + x1[(size_t)node * cD + tid] + x2[(size_t)xi2 * cD + tid]) * (1.0f / 3.0f);
  float s  = blockReduce128(a, sh, tid);
  float ss = blockReduce128(a * a, sh, tid);
  float mu = s * (1.0f / 128.0f);
  float var = ss * (1.0f / 128.0f) - mu * mu;
  float y = (a - mu) * rsqrtf(var + 1e-5f) * g[tid] + bia[tid];
  dst[(size_t)i * cD + tid] = y;
}

// ---------------------------------------------------------------------------
// bf16 MFMA GEMM: C[M,N] = A[M,K] @ Bt[N,K]^T, 128x128 tile, 4 waves
// epi 0: store bf16(acc+bias); epi 1: store bf16(ELU(acc+bias))
// ---------------------------------------------------------------------------
__global__ __launch_bounds__(256) void gemm_bf(
    const ushort* __restrict__ A, const ushort* __restrict__ Bt,
    int N, int K, const float* __restrict__ bias, ushort* __restrict__ Cbf, int epi) {
  __shared__ ushort As[128 * 40];
  __shared__ ushort Bs[128 * 40];
  const int bx = blockIdx.x, by = blockIdx.y;
  const int t = threadIdx.x;
  const int wv = t >> 6, lane = t & 63;
  const int wr = (wv >> 1) * 64, wc = (wv & 1) * 64;
  const int srow = t >> 1, shalf = t & 1;
  const ushort* Ag = A + (size_t)(by * 128 + srow) * K + shalf * 16;
  const ushort* Bg = Bt + (size_t)(bx * 128 + srow) * K + shalf * 16;
  uint4 ra0 = *reinterpret_cast<const uint4*>(Ag);
  uint4 ra1 = *reinterpret_cast<const uint4*>(Ag + 8);
  uint4 rb0 = *reinterpret_cast<const uint4*>(Bg);
  uint4 rb1 = *reinterpret_cast<const uint4*>(Bg + 8);
  f32x4 acc[4][4];
  const f32x4 z4 = {0.f, 0.f, 0.f, 0.f};
#pragma unroll
  for (int i = 0; i < 4; ++i)
#pragma unroll
    for (int j = 0; j < 4; ++j) acc[i][j] = z4;
  const int la = lane & 15, lk = (lane >> 4) * 8;
  const int sdst = srow * 40 + shalf * 16;
  for (int kt = 0; kt < K; kt += 32) {
    __syncthreads();
    *reinterpret_cast<uint4*>(&As[sdst])     = ra0;
    *reinterpret_cast<uint4*>(&As[sdst + 8]) = ra1;
    *reinterpret_cast<uint4*>(&Bs[sdst])     = rb0;
    *reinterpret_cast<uint4*>(&Bs[sdst + 8]) = rb1;
    __syncthreads();
    if (kt + 32 < K) {
      ra0 = *reinterpret_cast<const uint4*>(Ag + kt + 32);
      ra1 = *reinterpret_cast<const uint4*>(Ag + kt + 40);
      rb0 = *reinterpret_cast<const uint4*>(Bg + kt + 32);
      rb1 = *reinterpret_cast<const uint4*>(Bg + kt + 40);
    }
    short8v af[4], bfr[4];
#pragma unroll
    for (int i = 0; i < 4; ++i)
      af[i] = *reinterpret_cast<const short8v*>(&As[(wr + i * 16 + la) * 40 + lk]);
#pragma unroll
    for (int j = 0; j < 4; ++j)
      bfr[j] = *reinterpret_cast<const short8v*>(&Bs[(wc + j * 16 + la) * 40 + lk]);
#pragma unroll
    for (int i = 0; i < 4; ++i)
#pragma unroll
      for (int j = 0; j < 4; ++j)
        acc[i][j] = __builtin_amdgcn_mfma_f32_16x16x32_bf16(af[i], bfr[j], acc[i][j], 0, 0, 0);
  }
  const int r0 = by * 128 + wr + (lane >> 4) * 4;
  const int c0 = bx * 128 + wc + la;
#pragma unroll
  for (int i = 0; i < 4; ++i)
#pragma unroll
    for (int j = 0; j < 4; ++j) {
      int c = c0 + j * 16;
      float bv = bias[c];
#pragma unroll
      for (int q = 0; q < 4; ++q) {
        int r = r0 + i * 16 + q;
        float v = acc[i][j][q] + bv;
        if (epi == 1) v = (v > 0.0f) ? v : expm1f(v);
        Cbf[(size_t)r * N + c] = f2bf(v);
      }
    }
}

// ---------------------------------------------------------------------------
// Fused gate + pooling: per mailbox b (512 blocks):
//   logits[l,e] = o[b*8+l] . gate_w[:,e]; gate = softmax_e
//   ae[e][b,:]  = sum_l gate[l,e] * o[b*8+l]   (bf16)
//   gsum[b,e]   = sum_l gate[l,e]
// ---------------------------------------------------------------------------
__global__ __launch_bounds__(256) void k_gate_pool(
    const ushort* __restrict__ o, const float* __restrict__ gw,
    ushort* __restrict__ ae, float* __restrict__ gsum) {
  __shared__ float os[8][1024];
  __shared__ float lg[8][4];
  __shared__ float gs[8][4];
  const int b = blockIdx.x, t = threadIdx.x;
  for (int u = t; u < 8192; u += 256) {
    int l = u >> 10, d = u & 1023;
    os[l][d] = bf2f(o[(size_t)(b * 8 + l) * 1024 + d]);
  }
  __syncthreads();
  {
    int p = t >> 3, sub = t & 7;    // 32 (l,e) pairs x 8 threads
    int l = p >> 2, e = p & 3;
    float s = 0;
    for (int d = sub; d < 1024; d += 8) s += os[l][d] * gw[d * 4 + e];
    s += __shfl_down(s, 4, 8);
    s += __shfl_down(s, 2, 8);
    s += __shfl_down(s, 1, 8);
    if (sub == 0) lg[l][e] = s;
  }
  __syncthreads();
  if (t < 8) {
    float m = fmaxf(fmaxf(lg[t][0], lg[t][1]), fmaxf(lg[t][2], lg[t][3]));
    float e0 = expf(lg[t][0] - m), e1 = expf(lg[t][1] - m);
    float e2 = expf(lg[t][2] - m), e3 = expf(lg[t][3] - m);
    float inv = 1.0f / (e0 + e1 + e2 + e3);
    gs[t][0] = e0 * inv; gs[t][1] = e1 * inv;
    gs[t][2] = e2 * inv; gs[t][3] = e3 * inv;
  }
  __syncthreads();
  if (t < 4) {
    float g = 0;
#pragma unroll
    for (int l = 0; l < 8; ++l) g += gs[l][t];
    gsum[b * 4 + t] = g;
  }
#pragma unroll
  for (int rep = 0; rep < 4; ++rep) {
    int d = t + rep * 256;
    float a0 = 0, a1 = 0, a2 = 0, a3 = 0;
#pragma unroll
    for (int l = 0; l < 8; ++l) {
      float ov = os[l][d];
      a0 += gs[l][0] * ov; a1 += gs[l][1] * ov;
      a2 += gs[l][2] * ov; a3 += gs[l][3] * ov;
    }
    ae[(size_t)0 * 524288 + b * 1024 + d] = f2bf(a0);
    ae[(size_t)1 * 524288 + b * 1024 + d] = f2bf(a1);
    ae[(size_t)2 * 524288 + b * 1024 + d] = f2bf(a2);
    ae[(size_t)3 * 524288 + b * 1024 + d] = f2bf(a3);
  }
}

// ---------------------------------------------------------------------------
// Pooled MoE GEMM: out[b,t] = sigmoid(0.125*(sum_e Ae_e@W_e^T + sum_e gsum*b_e))
// 64x64 tiles, M=512, N=1024, experts folded into K-accumulation. 128 blocks.
// ---------------------------------------------------------------------------
__global__ __launch_bounds__(256) void gemm_moe2(
    const ushort* __restrict__ AE, const ushort* __restrict__ Bt4,
    const float* __restrict__ expb, const float* __restrict__ gsum,
    float* __restrict__ out) {
  __shared__ ushort As[64 * 40];
  __shared__ ushort Bs[64 * 40];
  const int bx = blockIdx.x, by = blockIdx.y;
  const int t = threadIdx.x;
  const int wv = t >> 6, lane = t & 63;
  const int wr = (wv >> 1) * 32, wc = (wv & 1) * 32;
  const int srow = t >> 2, sq = t & 3;
  const int la = lane & 15, lk = (lane >> 4) * 8;
  const int sdst = srow * 40 + sq * 8;
  f32x4 acc[2][2];
  const f32x4 z4 = {0.f, 0.f, 0.f, 0.f};
  acc[0][0] = z4; acc[0][1] = z4; acc[1][0] = z4; acc[1][1] = z4;
  for (int e = 0; e < 4; ++e) {
    const ushort* Ag = AE + (size_t)e * 524288 + (size_t)(by * 64 + srow) * 1024 + sq * 8;
    const ushort* Bg = Bt4 + (size_t)e * 1048576 + (size_t)(bx * 64 + srow) * 1024 + sq * 8;
    uint4 ra = *reinterpret_cast<const uint4*>(Ag);
    uint4 rb = *reinterpret_cast<const uint4*>(Bg);
    for (int kt = 0; kt < 1024; kt += 32) {
      __syncthreads();
      *reinterpret_cast<uint4*>(&As[sdst]) = ra;
      *reinterpret_cast<uint4*>(&Bs[sdst]) = rb;
      __syncthreads();
      if (kt + 32 < 1024) {
        ra = *reinterpret_cast<const uint4*>(Ag + kt + 32);
        rb = *reinterpret_cast<const uint4*>(Bg + kt + 32);
      }
      short8v af[2], bfr[2];
#pragma unroll
      for (int i = 0; i < 2; ++i)
        af[i] = *reinterpret_cast<const short8v*>(&As[(wr + i * 16 + la) * 40 + lk]);
#pragma unroll
      for (int j = 0; j < 2; ++j)
        bfr[j] = *reinterpret_cast<const short8v*>(&Bs[(wc + j * 16 + la) * 40 + lk]);
#pragma unroll
      for (int i = 0; i < 2; ++i)
#pragma unroll
        for (int j = 0; j < 2; ++j)
          acc[i][j] = __builtin_amdgcn_mfma_f32_16x16x32_bf16(af[i], bfr[j], acc[i][j], 0, 0, 0);
    }
  }
  const int r0 = by * 64 + wr + (lane >> 4) * 4;
  const int c0 = bx * 64 + wc + la;
#pragma unroll
  for (int i = 0; i < 2; ++i)
#pragma unroll
    for (int q = 0; q < 4; ++q) {
      int r = r0 + i * 16 + q;
      float4 gv = *reinterpret_cast<const float4*>(gsum + r * 4);
#pragma unroll
      for (int j = 0; j < 2; ++j) {
        int c = c0 + j * 16;
        float bias = gv.x * expb[c] + gv.y * expb[1024 + c] +
                     gv.z * expb[2048 + c] + gv.w * expb[3072 + c];
        float s = (acc[i][j][q] + bias) * 0.125f;
        out[(size_t)r * 1024 + c] = 1.0f / (1.0f + expf(-s));
      }
    }
}

// ---------------------------------------------------------------------------
// Symmetric Gram contrastive kernel (2080 triangular tiles)
// ---------------------------------------------------------------------------
__global__ __launch_bounds__(256) void gram_sym(
    const ushort* __restrict__ W, float* __restrict__ rsum,
    float* __restrict__ d11, float* __restrict__ d12, float* __restrict__ d22) {
  __shared__ ushort As[128 * 40];
  __shared__ ushort Bs[128 * 40];
  int tt = blockIdx.x, bi = 0, cnt = 64;
  while (tt >= cnt) { tt -= cnt; ++bi; --cnt; }
  int bj = bi + tt;
  const bool diag = (bi == bj);
  const int t = threadIdx.x;
  const int wv = t >> 6, lane = t & 63;
  const int wr = (wv >> 1) * 64, wc = (wv & 1) * 64;
  const int srow = t >> 1, shalf = t & 1;
  const ushort* Ag = W + (size_t)(bi * 128 + srow) * 128 + shalf * 16;
  const ushort* Bg = W + (size_t)(bj * 128 + srow) * 128 + shalf * 16;
  uint4 ra0 = *reinterpret_cast<const uint4*>(Ag);
  uint4 ra1 = *reinterpret_cast<const uint4*>(Ag + 8);
  uint4 rb0 = *reinterpret_cast<const uint4*>(Bg);
  uint4 rb1 = *reinterpret_cast<const uint4*>(Bg + 8);
  f32x4 acc[4][4];
  const f32x4 z4 = {0.f, 0.f, 0.f, 0.f};
#pragma unroll
  for (int i = 0; i < 4; ++i)
#pragma unroll
    for (int j = 0; j < 4; ++j) acc[i][j] = z4;
  const int la = lane & 15, lk = (lane >> 4) * 8;
  const int sdst = srow * 40 + shalf * 16;
  for (int kt = 0; kt < 128; kt += 32) {
    __syncthreads();
    *reinterpret_cast<uint4*>(&As[sdst])     = ra0;
    *reinterpret_cast<uint4*>(&As[sdst + 8]) = ra1;
    *reinterpret_cast<uint4*>(&Bs[sdst])     = rb0;
    *reinterpret_cast<uint4*>(&Bs[sdst + 8]) = rb1;
    __syncthreads();
    if (kt + 32 < 128) {
      ra0 = *reinterpret_cast<const uint4*>(Ag + kt + 32);
      ra1 = *reinterpret_cast<const uint4*>(Ag + kt + 40);
      rb0 = *reinterpret_cast<const uint4*>(Bg + kt + 32);
      rb1 = *reinterpret_cast<const uint4*>(Bg + kt + 40);
    }
    short8v af[4], bfr[4];
#pragma unroll
    for (int i = 0; i < 4; ++i)
      af[i] = *reinterpret_cast<const short8v*>(&As[(wr + i * 16 + la) * 40 + lk]);
#pragma unroll
    for (int j = 0; j < 4; ++j)
      bfr[j] = *reinterpret_cast<const short8v*>(&Bs[(wc + j * 16 + la) * 40 + lk]);
#pragma unroll
    for (int i = 0; i < 4; ++i)
#pragma unroll
      for (int j = 0; j < 4; ++j)
        acc[i][j] = __builtin_amdgcn_mfma_f32_16x16x32_bf16(af[i], bfr[j], acc[i][j], 0, 0, 0);
  }
  const int r0 = bi * 128 + wr + (lane >> 4) * 4;
  const int c0 = bj * 128 + wc + la;
  constexpr float K2 = 2.8853900817779268f;   // 2 / ln(2)
  float rs[4][4];
  float cs[4] = {0.f, 0.f, 0.f, 0.f};
#pragma unroll
  for (int i = 0; i < 4; ++i)
#pragma unroll
    for (int q = 0; q < 4; ++q) rs[i][q] = 0.f;
#pragma unroll
  for (int i = 0; i < 4; ++i)
#pragma unroll
    for (int j = 0; j < 4; ++j)
#pragma unroll
      for (int q = 0; q < 4; ++q) {
        int r = r0 + i * 16 + q;
        int c = c0 + j * 16;
        float e = exp2f(K2 * acc[i][j][q]);
        rs[i][q] += e;
        cs[j] += e;
        if (c == r)        { if (r < 4096) d11[r] = e; else d22[r - 4096] = e; }
        if (c == r + 4096) d12[r] = e;
      }
#pragma unroll
  for (int m = 1; m < 16; m <<= 1)
#pragma unroll
    for (int i = 0; i < 4; ++i)
#pragma unroll
      for (int q = 0; q < 4; ++q) rs[i][q] += __shfl_xor(rs[i][q], m);
  float* rowdst = rsum + ((bj >= 32) ? 8192 : 0);
  if (la == 0) {
#pragma unroll
    for (int i = 0; i < 4; ++i)
#pragma unroll
      for (int q = 0; q < 4; ++q) atomAdd(&rowdst[r0 + i * 16 + q], rs[i][q]);
  }
  if (!diag) {
#pragma unroll
    for (int j = 0; j < 4; ++j) {
      cs[j] += __shfl_xor(cs[j], 16);
      cs[j] += __shfl_xor(cs[j], 32);
    }
    float* coldst = rsum + ((bi >= 32) ? 8192 : 0);
    if ((lane >> 4) == 0) {
#pragma unroll
      for (int j = 0; j < 4; ++j) atomAdd(&coldst[c0 + j * 16], cs[j]);
    }
  }
}

__global__ __launch_bounds__(256) void cl_row(
    const float* __restrict__ rsum, const float* __restrict__ d11,
    const float* __restrict__ d12, const float* __restrict__ d22,
    float* __restrict__ cl_sum) {
  __shared__ float sh[256];
  int i = blockIdx.x * 256 + threadIdx.x;
  float denA = rsum[i] + rsum[8192 + i] - d11[i];
  float denB = rsum[8192 + 4096 + i] + rsum[4096 + i] - d22[i];
  float l = 0.5f * (logf(denA) + logf(denB)) - logf(d12[i]);
  float s = blockReduce256(l, sh, threadIdx.x);
  if (threadIdx.x == 0) atomAdd(cl_sum, s);
}

// weight transpose + bf16 convert: Bt[n*K+k] = bf16(W[k*N+n])
__global__ __launch_bounds__(256) void k_wt_bt(const float* __restrict__ W,
                                               ushort* __restrict__ Bt, int K, int N) {
  __shared__ float tile[32][33];
  int n0 = blockIdx.x * 32, k0 = blockIdx.y * 32;
  int tx = threadIdx.x & 31, ty = threadIdx.x >> 5;
#pragma unroll
  for (int i = 0; i < 4; ++i)
    tile[ty + 8 * i][tx] = W[(size_t)(k0 + ty + 8 * i) * N + n0 + tx];
  __syncthreads();
#pragma unroll
  for (int i = 0; i < 4; ++i)
    Bt[(size_t)(n0 + ty + 8 * i) * K + k0 + tx] = f2bf(tile[tx][ty + 8 * i]);
}

// S1|S2 (f32) -> SB bf16 [8192][128]
__global__ __launch_bounds__(256) void s_to_bf(const float* __restrict__ s1,
                                               const float* __restrict__ s2,
                                               ushort* __restrict__ sb) {
  int idx = blockIdx.x * 256 + threadIdx.x;
  float v = (idx < 524288) ? s1[idx] : s2[idx - 524288];
  sb[idx] = f2bf(v);
}

// in-place bf16 row normalize
__global__ __launch_bounds__(128) void rownorm_bf2(ushort* __restrict__ w) {
  __shared__ float sh[128];
  int i = blockIdx.x, tid = threadIdx.x;
  float v = bf2f(w[(size_t)i * cD + tid]);
  float ss = blockReduce128(v * v, sh, tid);
  float n = fmaxf(sqrtf(ss), 1e-12f);
  w[(size_t)i * cD + tid] = f2bf(v / n);
}

// ---------------------------------------------------------------------------
// message / losses / MHA
// ---------------------------------------------------------------------------
__global__ __launch_bounds__(256) void emb_sum_k(
    const float* __restrict__ s1, const float* __restrict__ s2,
    const float* __restrict__ relation, const int* __restrict__ etype, float* __restrict__ out) {
  __shared__ float sh[256];
  int idx = blockIdx.x * 256 + threadIdx.x;
  int i = idx >> 8, j = idx & 255;
  float a = (j < 128) ? s1[(size_t)i * 128 + j] : s2[(size_t)i * 128 + j - 128];
  int et = etype[i];
  float r = relation[(size_t)(et % cNR) * 256 + j];
  float t = blockReduce256(a * a + r * r, sh, threadIdx.x);
  if (threadIdx.x == 0) atomAdd(out, t);
}

__global__ __launch_bounds__(256) void msg_build(
    const float* __restrict__ s1, const float* __restrict__ s2,
    const float* __restrict__ relation, const int* __restrict__ etype,
    ushort* __restrict__ msg) {
  int idx = blockIdx.x * 256 + threadIdx.x;
  int i = idx >> 8, j = idx & 255;
  int et = etype[i];
  float sign = (et >= cNR) ? -1.0f : 1.0f;
  float r = relation[(size_t)(et % cNR) * 256 + j] * sign;
  float s = (j < 128) ? s1[(size_t)i * 128 + j] : s2[(size_t)i * 128 + j - 128];
  msg[idx] = f2bf(fmaxf(s + r, 0.0f));
}

// fused-QKV attention: qkv [4096][3072] (Q|K|V per row), o [4096][1024] bf16
__global__ __launch_bounds__(64) void mha_attn(
    const ushort* __restrict__ qkv, ushort* __restrict__ o) {
  __shared__ float qs[8][132], ks[8][132], vs[8][132];
  __shared__ float att[8][8];
  int bh = blockIdx.x;
  int b = bh >> 3, h = bh & 7;
  int tid = threadIdx.x;
  for (int u = tid; u < 256; u += 64) {
    int l = u >> 5;
    int d4 = (u & 31) * 4;
    size_t base = (size_t)(b * 8 + l) * 3072 + h * 128 + d4;
    ushort4 qv = *reinterpret_cast<const ushort4*>(qkv + base);
    ushort4 kv = *reinterpret_cast<const ushort4*>(qkv + base + 1024);
    ushort4 vv = *reinterpret_cast<const ushort4*>(qkv + base + 2048);
    qs[l][d4] = bf2f(qv.x); qs[l][d4 + 1] = bf2f(qv.y);
    qs[l][d4 + 2] = bf2f(qv.z); qs[l][d4 + 3] = bf2f(qv.w);
    ks[l][d4] = bf2f(kv.x); ks[l][d4 + 1] = bf2f(kv.y);
    ks[l][d4 + 2] = bf2f(kv.z); ks[l][d4 + 3] = bf2f(kv.w);
    vs[l][d4] = bf2f(vv.x); vs[l][d4 + 1] = bf2f(vv.y);
    vs[l][d4 + 2] = bf2f(vv.z); vs[l][d4 + 3] = bf2f(vv.w);
  }
  __syncthreads();
  int l = tid >> 3, m = tid & 7;
  const float4* qp = reinterpret_cast<const float4*>(&qs[l][0]);
  const float4* kp = reinterpret_cast<const float4*>(&ks[m][0]);
  float s = 0;
#pragma unroll
  for (int d4 = 0; d4 < 32; ++d4) {
    float4 a = qp[d4], bb = kp[d4];
    s += a.x * bb.x + a.y * bb.y + a.z * bb.z + a.w * bb.w;
  }
  s *= 0.08838834764831845f;
  float mx = s;
  for (int off = 1; off < 8; off <<= 1) mx = fmaxf(mx, __shfl_xor(mx, off, 8));
  float p = expf(s - mx);
  float sum = p;
  for (int off = 1; off < 8; off <<= 1) sum += __shfl_xor(sum, off, 8);
  att[l][m] = p / sum;
  __syncthreads();
  for (int u = tid; u < 1024; u += 64) {
    int ll = u >> 7, d = u & 127;
    float acc = 0;
#pragma unroll
    for (int mm = 0; mm < 8; ++mm) acc += att[ll][mm] * vs[mm][d];
    o[(size_t)(b * 8 + ll) * 1024 + h * 128 + d] = f2bf(acc);
  }
}

__global__ void finalize_k(const float* __restrict__ scal, float* __restrict__ out_aux) {
  float cl = scal[0] * (1.0f / cNSRC);
  float emb = cDECAY * 0.5f * scal[1] * (1.0f / cNSRC);
  out_aux[0] = cCLW * cl + emb;
}

// ---------------------------------------------------------------------------
// Launch
// ---------------------------------------------------------------------------
extern "C" void kernel_launch(void* const* d_in, const int* in_sizes, int n_in,
                              void* d_out, int out_size, void* d_ws, size_t ws_size,
                              hipStream_t stream) {
  (void)in_sizes; (void)n_in; (void)out_size; (void)ws_size;
  const float* entity   = (const float*)d_in[0];
  const float* type_e   = (const float*)d_in[1];
  const float* cluster  = (const float*)d_in[2];
  const float* relation = (const float*)d_in[3];
  const float* ln_g  = (const float*)d_in[4];
  const float* ln_b  = (const float*)d_in[5];
  const float* cl_w1 = (const float*)d_in[6];
  const float* cl_b1 = (const float*)d_in[7];
  const float* cl_w2 = (const float*)d_in[8];
  const float* cl_b2 = (const float*)d_in[9];
  const float* fc_w  = (const float*)d_in[10];
  const float* fc_b  = (const float*)d_in[11];
  const float* wq = (const float*)d_in[12];
  const float* bq = (const float*)d_in[13];
  const float* wk = (const float*)d_in[14];
  const float* bk = (const float*)d_in[15];
  const float* wv = (const float*)d_in[16];
  const float* bv = (const float*)d_in[17];
  const float* wo = (const float*)d_in[18];
  const float* bo = (const float*)d_in[19];
  const float* gate_w = (const float*)d_in[20];
  const float* exp_w  = (const float*)d_in[21];
  const float* exp_b  = (const float*)d_in[22];
  const float* e2t_val = (const float*)d_in[23];
  const float* t2c_val = (const float*)d_in[24];
  const float* e2c_val = (const float*)d_in[25];
  const int* e2t_row = (const int*)d_in[26];
  const int* e2t_col = (const int*)d_in[27];
  const int* t2c_row = (const int*)d_in[28];
  const int* t2c_col = (const int*)d_in[29];
  const int* e2c_row = (const int*)d_in[30];
  const int* e2c_col = (const int*)d_in[31];
  const int* src_ids = (const int*)d_in[32];
  const int* etype   = (const int*)d_in[33];

  float* ws = (float*)d_ws;
  float* S1 = ws + F_S1;
  float* S2 = ws + F_S2;
  ushort* Wbf = (ushort*)(ws + F_PT);
  ushort* P1bf = (ushort*)(ws + F_Z1);
  ushort* SBbf = (ushort*)(ws + F_Z2);
  ushort* MSGbf = (ushort*)(ws + F_MSG);
  float* GSUM = ws + F_GATE;
  float* SCAL = ws + F_SCAL;
  float* RS   = ws + F_RS;
  float* BQKV = ws + F_RS;
  float* D11  = ws + F_D11;
  float* D12  = ws + F_D12;
  float* D22  = ws + F_D22;
  float* X1F  = ws + G_X1F;
  float* X2C  = ws + G_X2C;
  int*   MARK = (int*)(ws + G_X2C);
  int*   SLOT = (int*)(ws + G_SLOT);
  int*   REP  = (int*)(ws + G_REP);
  int*   RP   = (int*)(ws + G_RP);
  int*   FILL = (int*)(ws + G_FILL);
  int*   EIDX = (int*)(ws + G_EIDX);
  float* X1T  = ws + G_X1T;
  float* X2T  = ws + G_X2T;
  int*   BSUM = (int*)(ws + G_BSUM);
  ushort* PB   = (ushort*)(ws + A_U0);   // predict; later attn-out; later AE
  ushort* AE   = (ushort*)(ws + A_U0);
  ushort* QKV  = (ushort*)(ws + A_U1);
  ushort* OB   = (ushort*)(ws + A_U1);
  ushort* WBT  = (ushort*)(ws + A_WBT);

  hipMemsetAsync(SCAL, 0, 2 * sizeof(float), stream);
  hipMemsetAsync(RS, 0, (16384 + 3 * 4096) * sizeof(float), stream);

  // masked GCN
  auto run_gcn_masked = [&](const int* row, const int* col, const float* val, int nnz, int nn,
                            const float* ea, const float* eb, int na, int mode,
                            float* dst) {
    int nb = (nn + 255) / 256;
    int gEdge = (nnz + 255) / 256;
    hipMemsetAsync(SLOT, 0x7F, (size_t)nn * sizeof(int), stream);
    slot_build<<<16, 256, 0, stream>>>(src_ids, SLOT, mode);
    hipMemsetAsync(MARK, 0, (size_t)nn * sizeof(int), stream);
    k_mark_nodes<<<16, 256, 0, stream>>>(src_ids, MARK, mode);
    k_mark_edges<<<gEdge, 256, 0, stream>>>(row, col, nnz, SLOT, MARK);
    hipMemsetAsync(FILL, 0, (size_t)nn * sizeof(int), stream);
    k_hist<<<gEdge, 256, 0, stream>>>(row, nnz, MARK, FILL);
    k_scan_block<<<nb, 256, 0, stream>>>(FILL, nn, RP, BSUM);
    k_bsum_scan<<<1, 512, 0, stream>>>(BSUM, nb, RP, nn);
    k_scan_add<<<nb, 256, 0, stream>>>(RP, BSUM, nn, FILL);
    k_fill<<<gEdge, 256, 0, stream>>>(row, nnz, MARK, FILL, EIDX);
    k_rep<<<16, 256, 0, stream>>>(src_ids, SLOT, mode, REP);
    k_gather<<<(nn + 3) / 4, 256, 0, stream>>>(RP, EIDX, col, val, ea, eb, na, nn, MARK, X1F);
    k_gather_slot<<<cNSRC / 4, 256, 0, stream>>>(RP, EIDX, col, val, X1F, REP, X2C);
    gather_ln<<<cNSRC, 128, 0, stream>>>(src_ids, mode, ea, eb, na, X1F, X2C, SLOT,
                                         ln_g, ln_b, dst);
  };

  run_gcn_masked(e2t_row, e2t_col, e2t_val, cNNZ_E2T, cNN_E2T, entity, type_e, cNE, 0, S1);
  run_gcn_masked(e2c_row, e2c_col, e2c_val, cNNZ_E2C, cNN_E2C, entity, cluster, cNE, 3, S2);

  // ---- t2c: tiny, both layers full ----
  {
    int nn = cNN_T2C, nb = (nn + 255) / 256, gEdge = (cNNZ_T2C + 255) / 256;
    hipMemsetAsync(FILL, 0, (size_t)nn * sizeof(int), stream);
    k_hist<<<gEdge, 256, 0, stream>>>(t2c_row, cNNZ_T2C, nullptr, FILL);
    k_scan_block<<<nb, 256, 0, stream>>>(FILL, nn, RP, BSUM);
    k_bsum_scan<<<1, 512, 0, stream>>>(BSUM, nb, RP, nn);
    k_scan_add<<<nb, 256, 0, stream>>>(RP, BSUM, nn, FILL);
    k_fill<<<gEdge, 256, 0, stream>>>(t2c_row, cNNZ_T2C, nullptr, FILL, EIDX);
    k_gather<<<(nn + 3) / 4, 256, 0, stream>>>(RP, EIDX, t2c_col, t2c_val,
                                               type_e, cluster, cNT, nn, nullptr, X1T);
    k_gather<<<(nn + 3) / 4, 256, 0, stream>>>(RP, EIDX, t2c_col, t2c_val,
                                               X1T, X1T, 1 << 30, nn, nullptr, X2T);
    gather_ln<<<cNSRC, 128, 0, stream>>>(src_ids, 1, type_e, cluster, cNT, X1T, X2T, nullptr,
                                         ln_g, ln_b, S1);
    gather_ln<<<cNSRC, 128, 0, stream>>>(src_ids, 2, type_e, cluster, cNT, X1T, X2T, nullptr,
                                         ln_g, ln_b, S2);
  }

  // ================= contrastive loss =================
  ushort* W1T = WBT;
  ushort* W2T = WBT + 16384;
  k_wt_bt<<<dim3(4, 4), 256, 0, stream>>>(cl_w1, W1T, cD, cD);
  k_wt_bt<<<dim3(4, 4), 256, 0, stream>>>(cl_w2, W2T, cD, cD);
  s_to_bf<<<4096, 256, 0, stream>>>(S1, S2, SBbf);
  gemm_bf<<<dim3(1, 64), 256, 0, stream>>>(SBbf, W1T, cD, cD, cl_b1, P1bf, 1);
  gemm_bf<<<dim3(1, 64), 256, 0, stream>>>(P1bf, W2T, cD, cD, cl_b2, Wbf, 0);
  rownorm_bf2<<<2 * cNSRC, 128, 0, stream>>>(Wbf);
  gram_sym<<<2080, 256, 0, stream>>>(Wbf, RS, D11, D12, D22);
  cl_row<<<16, 256, 0, stream>>>(RS, D11, D12, D22, SCAL);
  emb_sum_k<<<cNSRC, 256, 0, stream>>>(S1, S2, relation, etype, SCAL + 1);

  // ================= message + predict =================
  msg_build<<<cNSRC, 256, 0, stream>>>(S1, S2, relation, etype, MSGbf);
  k_wt_bt<<<dim3(cT / 32, 256 / 32), 256, 0, stream>>>(fc_w, WBT, 256, cT);
  gemm_bf<<<dim3(cT / 128, cNSRC / 128), 256, 0, stream>>>(MSGbf, WBT, cT, 256, fc_b, PB, 0);

  // ================= MHA: fused QKV =================
  k_wt_bt<<<dim3(32, 32), 256, 0, stream>>>(wq, WBT, cT, cT);
  k_wt_bt<<<dim3(32, 32), 256, 0, stream>>>(wk, WBT + 1048576, cT, cT);
  k_wt_bt<<<dim3(32, 32), 256, 0, stream>>>(wv, WBT + 2 * 1048576, cT, cT);
  hipMemcpyAsync(BQKV,        bq, cT * sizeof(float), hipMemcpyDeviceToDevice, stream);
  hipMemcpyAsync(BQKV + 1024, bk, cT * sizeof(float), hipMemcpyDeviceToDevice, stream);
  hipMemcpyAsync(BQKV + 2048, bv, cT * sizeof(float), hipMemcpyDeviceToDevice, stream);
  gemm_bf<<<dim3(3072 / 128, cNSRC / 128), 256, 0, stream>>>(PB, WBT, 3072, cT, BQKV, QKV, 0);
  mha_attn<<<cB * 8, 64, 0, stream>>>(QKV, PB);                 // attn-out -> A_U0
  k_wt_bt<<<dim3(32, 32), 256, 0, stream>>>(wo, WBT, cT, cT);
  gemm_bf<<<dim3(cT / 128, cNSRC / 128), 256, 0, stream>>>(PB, WBT, cT, cT, bo, OB, 0);

  // ================= pooled MoE =================
  k_gate_pool<<<cB, 256, 0, stream>>>(OB, gate_w, AE, GSUM);    // AE overwrites PB (dead)
  for (int e = 0; e < cE; ++e)
    k_wt_bt<<<dim3(32, 32), 256, 0, stream>>>(exp_w + (size_t)e * cT * cT,
                                              WBT + (size_t)e * 1048576, cT, cT);
  gemm_moe2<<<dim3(16, 8), 256, 0, stream>>>(AE, WBT, exp_b, GSUM, (float*)d_out);

  finalize_k<<<1, 1, 0, stream>>>(SCAL, (float*)d_out + (size_t)cB * cT);
}

// Round 7
// 576.091 us; speedup vs baseline: 9.5208x; 1.0785x over previous
//
#include <hip/hip_runtime.h>
#include <hip/hip_bf16.h>
#include <cmath>

// ---------------------------------------------------------------------------
// Problem constants (fixed shapes)
// ---------------------------------------------------------------------------
constexpr int cNE = 100000, cNT = 1024, cNC = 128, cD = 128, cNR = 500;
constexpr int cB = 512, cNSRC = 4096, cT = 1024, cE = 4;
constexpr int cNNZ_E2T = 1000000, cNNZ_T2C = 50000, cNNZ_E2C = 500000;
constexpr float cDECAY = 1e-4f, cCLW = 0.1f;
constexpr int cNN_E2T = cNE + cNT;     // 101024
constexpr int cNN_E2C = cNE + cNC;     // 100128
constexpr int cNN_T2C = cNT + cNC;     // 1152

// ---------------------------------------------------------------------------
// Workspace layout (FLOAT units)
// ---------------------------------------------------------------------------
constexpr size_t F_S1   = 0;                          // f32 4096x128
constexpr size_t F_S2   = F_S1 + 524288;
constexpr size_t F_PT   = F_S2 + 524288;              // bf16 W [8192][128] (Z/normed)
constexpr size_t F_Z1   = F_PT + 524288;              // bf16 P1 [8192][128]
constexpr size_t F_Z2   = F_Z1 + 524288;              // bf16 SB [8192][128]
constexpr size_t F_MSG  = F_Z2 + 524288;              // bf16 4096x256
constexpr size_t F_GATE = F_MSG + 524288;             // f32 GSUM [512][4]
constexpr size_t F_SCAL = F_GATE + 16384;
constexpr size_t F_RS   = F_SCAL + 64;                // f32 [2][8192] gram sums; later bias_qkv
constexpr size_t F_D11  = F_RS + 16384;               // f32 [4096]
constexpr size_t F_D12  = F_D11 + 4096;
constexpr size_t F_D22  = F_D12 + 4096;
constexpr size_t F_U    = F_D22 + 4096;               // union base
// --- GCN phase (X1/X2 now bf16) ---
constexpr size_t G_X1F  = F_U;                        // ushort[101024*128] = 6,465,536 fl
constexpr size_t G_X2C  = G_X1F + 6465536;            // ushort[4096*128] (also MARK int[101376])
constexpr size_t G_SLOT = G_X2C + 262144;             // int[101376]
constexpr size_t G_REP  = G_SLOT + 101376;            // int[4096]
constexpr size_t G_RP   = G_REP + 4096;               // int[101376]
constexpr size_t G_FILL = G_RP + 101376;              // int[101376]
constexpr size_t G_COLS = G_FILL + 101376;            // int[1000000]
constexpr size_t G_VALS = G_COLS + 1000000;           // f32[1000000]
constexpr size_t G_X1T  = G_VALS + 1000000;           // ushort[1152*128] = 73728 fl
constexpr size_t G_X2T  = G_X1T + 73728;
constexpr size_t G_BSUM = G_X2T + 73728;              // int[512]
// --- activation phase ---
constexpr size_t A_U0  = F_U;                 // predict bf16; attn-out; then AE bf16 [4][512][1024]
constexpr size_t A_U1  = F_U + 2097152;       // QKV bf16 [4096][3072] spans U1..U3; then O
constexpr size_t A_WBT = F_U + 4 * 2097152;   // bf16 weight^T scratch

typedef __attribute__((ext_vector_type(8))) short short8v;
typedef __attribute__((ext_vector_type(4))) float f32x4;

// ---------------------------------------------------------------------------
// Helpers
// ---------------------------------------------------------------------------
__device__ __forceinline__ void atomAdd(float* p, float v) {
  __hip_atomic_fetch_add(p, v, __ATOMIC_RELAXED, __HIP_MEMORY_SCOPE_AGENT);
}
__device__ __forceinline__ ushort f2bf(float f) {
  __hip_bfloat16 h = __float2bfloat16(f);
  return *reinterpret_cast<ushort*>(&h);
}
__device__ __forceinline__ float bf2f(ushort u) {
  __hip_bfloat16 h; *reinterpret_cast<ushort*>(&h) = u;
  return __bfloat162float(h);
}

__device__ __forceinline__ int mapNode(int mode, int id) {
  switch (mode) {
    case 0:  return (id < cNE + cNT) ? id : -1;
    case 1:  return (id >= cNE + cNT) ? (id - cNE) : -1;
    case 2:  return (id >= cNE && id < cNE + cNT) ? (id - cNE) : -1;
    default: return (id < cNE) ? id
                   : ((id >= cNE + cNT) ? (id - cNT) : -1);
  }
}

__device__ __forceinline__ float blockReduce128(float v, float* sh, int tid) {
  sh[tid] = v; __syncthreads();
  if (tid < 64) sh[tid] += sh[tid + 64]; __syncthreads();
  if (tid < 32) sh[tid] += sh[tid + 32]; __syncthreads();
  if (tid < 16) sh[tid] += sh[tid + 16]; __syncthreads();
  if (tid < 8)  sh[tid] += sh[tid + 8];  __syncthreads();
  if (tid < 4)  sh[tid] += sh[tid + 4];  __syncthreads();
  if (tid < 2)  sh[tid] += sh[tid + 2];  __syncthreads();
  if (tid < 1)  sh[tid] += sh[tid + 1];  __syncthreads();
  float r = sh[0]; __syncthreads();
  return r;
}
__device__ __forceinline__ float blockReduce256(float v, float* sh, int tid) {
  sh[tid] = v; __syncthreads();
  for (int s = 128; s > 0; s >>= 1) {
    if (tid < s) sh[tid] += sh[tid + s];
    __syncthreads();
  }
  float r = sh[0]; __syncthreads();
  return r;
}

// ---------------------------------------------------------------------------
// init + mask + CSR build
// ---------------------------------------------------------------------------
__global__ __launch_bounds__(256) void k_init3(int* __restrict__ slot, int* __restrict__ mark,
                                               int* __restrict__ fill, int n) {
  int i = blockIdx.x * 256 + threadIdx.x;
  if (i < n) { slot[i] = 0x7f7f7f7f; mark[i] = 0; fill[i] = 0; }
}

__global__ __launch_bounds__(256) void k_slot_mark(const int* __restrict__ ids,
                                                   int* __restrict__ slot,
                                                   int* __restrict__ mark, int mode) {
  int i = blockIdx.x * 256 + threadIdx.x;
  if (i >= cNSRC) return;
  int node = mapNode(mode, ids[i]);
  if (node >= 0) { atomicMin(&slot[node], i); mark[node] = 1; }
}

__global__ __launch_bounds__(256) void k_mark_edges(const int* __restrict__ row,
                                                    const int* __restrict__ col, int nnz,
                                                    const int* __restrict__ slot,
                                                    int* __restrict__ mark) {
  int e = blockIdx.x * 256 + threadIdx.x;
  if (e >= nnz) return;
  int r = row[e];
  if (slot[r] < cNSRC) mark[col[e]] = 1;
}

__global__ __launch_bounds__(256) void k_hist(const int* __restrict__ row, int nnz,
                                              const int* __restrict__ mark,
                                              int* __restrict__ cnt) {
  int e = blockIdx.x * 256 + threadIdx.x;
  if (e >= nnz) return;
  int r = row[e];
  if (mark && !mark[r]) return;
  atomicAdd(&cnt[r], 1);
}

__global__ __launch_bounds__(256) void k_scan_block(const int* __restrict__ cnt, int n,
                                                    int* __restrict__ excl, int* __restrict__ bsum) {
  __shared__ int sh[256];
  int tid = threadIdx.x;
  int i = blockIdx.x * 256 + tid;
  int v = (i < n) ? cnt[i] : 0;
  sh[tid] = v; __syncthreads();
  for (int off = 1; off < 256; off <<= 1) {
    int t = (tid >= off) ? sh[tid - off] : 0;
    __syncthreads();
    sh[tid] += t;
    __syncthreads();
  }
  if (i < n) excl[i] = sh[tid] - v;
  if (tid == 255) bsum[blockIdx.x] = sh[255];
}

__global__ __launch_bounds__(512) void k_bsum_scan(int* __restrict__ bsum, int nb,
                                                   int* __restrict__ rowptr, int n) {
  __shared__ int sh[512];
  int tid = threadIdx.x;
  int v = (tid < nb) ? bsum[tid] : 0;
  sh[tid] = v; __syncthreads();
  for (int off = 1; off < 512; off <<= 1) {
    int t = (tid >= off) ? sh[tid - off] : 0;
    __syncthreads();
    sh[tid] += t;
    __syncthreads();
  }
  if (tid < nb) bsum[tid] = sh[tid] - v;
  if (tid == 511) rowptr[n] = sh[511];
}

__global__ __launch_bounds__(256) void k_scan_add(int* __restrict__ rowptr,
                                                  const int* __restrict__ bsum, int n,
                                                  int* __restrict__ fill) {
  int i = blockIdx.x * 256 + threadIdx.x;
  if (i < n) {
    int r = rowptr[i] + bsum[blockIdx.x];
    rowptr[i] = r;
    fill[i] = r;
  }
}

// fill writes CSR-ordered (col,val) payload: removes eidx indirection at gather
__global__ __launch_bounds__(256) void k_fill(const int* __restrict__ row,
                                              const int* __restrict__ col,
                                              const float* __restrict__ val, int nnz,
                                              const int* __restrict__ mark,
                                              int* __restrict__ fill,
                                              int* __restrict__ cols, float* __restrict__ vals) {
  int e = blockIdx.x * 256 + threadIdx.x;
  if (e >= nnz) return;
  int r = row[e];
  if (mark && !mark[r]) return;
  int pos = atomicAdd(&fill[r], 1);
  cols[pos] = col[e];
  vals[pos] = val[e];
}

// wave-per-row gather, f32 embeddings in -> bf16 out
__global__ __launch_bounds__(256) void k_gather(
    const int* __restrict__ rowptr, const int* __restrict__ cols, const float* __restrict__ vals,
    const float* __restrict__ ea, const float* __restrict__ eb, int na,
    int nrows, const int* __restrict__ mark, ushort* __restrict__ out) {
  int r = blockIdx.x * 4 + (threadIdx.x >> 6);
  if (r >= nrows) return;
  if (mark && !mark[r]) return;
  int lane = threadIdx.x & 63;
  int p0 = rowptr[r], p1 = rowptr[r + 1];
  float ax = 0.f, ay = 0.f;
  int p = p0;
  for (; p + 2 <= p1; p += 2) {
    int c0 = cols[p], c1 = cols[p + 1];
    float v0 = vals[p], v1 = vals[p + 1];
    const float* s0 = (c0 < na) ? (ea + (size_t)c0 * cD) : (eb + (size_t)(c0 - na) * cD);
    const float* s1 = (c1 < na) ? (ea + (size_t)c1 * cD) : (eb + (size_t)(c1 - na) * cD);
    float2 x0 = *reinterpret_cast<const float2*>(s0 + lane * 2);
    float2 x1 = *reinterpret_cast<const float2*>(s1 + lane * 2);
    ax += v0 * x0.x + v1 * x1.x;
    ay += v0 * x0.y + v1 * x1.y;
  }
  if (p < p1) {
    int c = cols[p];
    float v = vals[p];
    const float* s = (c < na) ? (ea + (size_t)c * cD) : (eb + (size_t)(c - na) * cD);
    float2 x = *reinterpret_cast<const float2*>(s + lane * 2);
    ax += v * x.x; ay += v * x.y;
  }
  ushort2 o; o.x = f2bf(ax); o.y = f2bf(ay);
  *reinterpret_cast<ushort2*>(out + (size_t)r * cD + lane * 2) = o;
}

__global__ __launch_bounds__(256) void k_rep(const int* __restrict__ ids,
                                             const int* __restrict__ slot, int mode,
                                             int* __restrict__ rep) {
  int i = blockIdx.x * 256 + threadIdx.x;
  if (i >= cNSRC) return;
  int node = mapNode(mode, ids[i]);
  rep[i] = (node >= 0 && slot[node] == i) ? node : -1;
}

// layer-2 gather at representative slots: bf16 x1 in -> bf16 out
__global__ __launch_bounds__(256) void k_gather_slot(
    const int* __restrict__ rowptr, const int* __restrict__ cols, const float* __restrict__ vals,
    const ushort* __restrict__ x1, const int* __restrict__ rep,
    ushort* __restrict__ outc) {
  int i = blockIdx.x * 4 + (threadIdx.x >> 6);
  if (i >= cNSRC) return;
  int r = rep[i];
  if (r < 0) return;
  int lane = threadIdx.x & 63;
  int p0 = rowptr[r], p1 = rowptr[r + 1];
  float ax = 0.f, ay = 0.f;
  int p = p0;
  for (; p + 2 <= p1; p += 2) {
    int c0 = cols[p], c1 = cols[p + 1];
    float v0 = vals[p], v1 = vals[p + 1];
    ushort2 x0 = *reinterpret_cast<const ushort2*>(x1 + (size_t)c0 * cD + lane * 2);
    ushort2 x1v = *reinterpret_cast<const ushort2*>(x1 + (size_t)c1 * cD + lane * 2);
    ax += v0 * bf2f(x0.x) + v1 * bf2f(x1v.x);
    ay += v0 * bf2f(x0.y) + v1 * bf2f(x1v.y);
  }
  if (p < p1) {
    int c = cols[p];
    float v = vals[p];
    ushort2 x = *reinterpret_cast<const ushort2*>(x1 + (size_t)c * cD + lane * 2);
    ax += v * bf2f(x.x); ay += v * bf2f(x.y);
  }
  ushort2 o; o.x = f2bf(ax); o.y = f2bf(ay);
  *reinterpret_cast<ushort2*>(outc + (size_t)i * cD + lane * 2) = o;
}

// full-row gather, bf16 in -> bf16 out (t2c layer 2)
__global__ __launch_bounds__(256) void k_gather_bf(
    const int* __restrict__ rowptr, const int* __restrict__ cols, const float* __restrict__ vals,
    const ushort* __restrict__ x1, int nrows, ushort* __restrict__ out) {
  int r = blockIdx.x * 4 + (threadIdx.x >> 6);
  if (r >= nrows) return;
  int lane = threadIdx.x & 63;
  int p0 = rowptr[r], p1 = rowptr[r + 1];
  float ax = 0.f, ay = 0.f;
  for (int p = p0; p < p1; ++p) {
    int c = cols[p];
    float v = vals[p];
    ushort2 x = *reinterpret_cast<const ushort2*>(x1 + (size_t)c * cD + lane * 2);
    ax += v * bf2f(x.x); ay += v * bf2f(x.y);
  }
  ushort2 o; o.x = f2bf(ax); o.y = f2bf(ay);
  *reinterpret_cast<ushort2*>(out + (size_t)r * cD + lane * 2) = o;
}

// (x0 + x1 + x2)/3 at gathered rows -> LayerNorm -> dst (x1,x2 bf16)
__global__ __launch_bounds__(128) void gather_ln(
    const int* __restrict__ ids, int mode,
    const float* __restrict__ ea, const float* __restrict__ eb, int na,
    const ushort* __restrict__ x1, const ushort* __restrict__ x2, const int* __restrict__ slot,
    const float* __restrict__ g, const float* __restrict__ bia, float* __restrict__ dst) {
  __shared__ float sh[128];
  int i = blockIdx.x;
  int tid = threadIdx.x;
  int id = ids[i];
  int node = mapNode(mode, id);
  if (node < 0) return;
  const float* x0 = (node < na) ? (ea + (size_t)node * cD) : (eb + (size_t)(node - na) * cD);
  int xi2 = slot ? slot[node] : node;
  float a = (x0[tid] + bf2f(x1[(size_t)node * cD + tid]) + bf2f(x2[(size_t)xi2 * cD + tid]))
            * (1.0f / 3.0f);
  float s  = blockReduce128(a, sh, tid);
  float ss = blockReduce128(a * a, sh, tid);
  float mu = s * (1.0f / 128.0f);
  float var = ss * (1.0f / 128.0f) - mu * mu;
  float y = (a - mu) * rsqrtf(var + 1e-5f) * g[tid] + bia[tid];
  dst[(size_t)i * cD + tid] = y;
}

// ---------------------------------------------------------------------------
// bf16 MFMA GEMM: C[M,N] = A[M,K] @ Bt[N,K]^T, 128x128 tile, 4 waves
// epi 0: store bf16(acc+bias); epi 1: store bf16(ELU(acc+bias))
// ---------------------------------------------------------------------------
__global__ __launch_bounds__(256) void gemm_bf(
    const ushort* __restrict__ A, const ushort* __restrict__ Bt,
    int N, int K, const float* __restrict__ bias, ushort* __restrict__ Cbf, int epi) {
  __shared__ ushort As[128 * 40];
  __shared__ ushort Bs[128 * 40];
  const int bx = blockIdx.x, by = blockIdx.y;
  const int t = threadIdx.x;
  const int wv = t >> 6, lane = t & 63;
  const int wr = (wv >> 1) * 64, wc = (wv & 1) * 64;
  const int srow = t >> 1, shalf = t & 1;
  const ushort* Ag = A + (size_t)(by * 128 + srow) * K + shalf * 16;
  const ushort* Bg = Bt + (size_t)(bx * 128 + srow) * K + shalf * 16;
  uint4 ra0 = *reinterpret_cast<const uint4*>(Ag);
  uint4 ra1 = *reinterpret_cast<const uint4*>(Ag + 8);
  uint4 rb0 = *reinterpret_cast<const uint4*>(Bg);
  uint4 rb1 = *reinterpret_cast<const uint4*>(Bg + 8);
  f32x4 acc[4][4];
  const f32x4 z4 = {0.f, 0.f, 0.f, 0.f};
#pragma unroll
  for (int i = 0; i < 4; ++i)
#pragma unroll
    for (int j = 0; j < 4; ++j) acc[i][j] = z4;
  const int la = lane & 15, lk = (lane >> 4) * 8;
  const int sdst = srow * 40 + shalf * 16;
  for (int kt = 0; kt < K; kt += 32) {
    __syncthreads();
    *reinterpret_cast<uint4*>(&As[sdst])     = ra0;
    *reinterpret_cast<uint4*>(&As[sdst + 8]) = ra1;
    *reinterpret_cast<uint4*>(&Bs[sdst])     = rb0;
    *reinterpret_cast<uint4*>(&Bs[sdst + 8]) = rb1;
    __syncthreads();
    if (kt + 32 < K) {
      ra0 = *reinterpret_cast<const uint4*>(Ag + kt + 32);
      ra1 = *reinterpret_cast<const uint4*>(Ag + kt + 40);
      rb0 = *reinterpret_cast<const uint4*>(Bg + kt + 32);
      rb1 = *reinterpret_cast<const uint4*>(Bg + kt + 40);
    }
    short8v af[4], bfr[4];
#pragma unroll
    for (int i = 0; i < 4; ++i)
      af[i] = *reinterpret_cast<const short8v*>(&As[(wr + i * 16 + la) * 40 + lk]);
#pragma unroll
    for (int j = 0; j < 4; ++j)
      bfr[j] = *reinterpret_cast<const short8v*>(&Bs[(wc + j * 16 + la) * 40 + lk]);
#pragma unroll
    for (int i = 0; i < 4; ++i)
#pragma unroll
      for (int j = 0; j < 4; ++j)
        acc[i][j] = __builtin_amdgcn_mfma_f32_16x16x32_bf16(af[i], bfr[j], acc[i][j], 0, 0, 0);
  }
  const int r0 = by * 128 + wr + (lane >> 4) * 4;
  const int c0 = bx * 128 + wc + la;
#pragma unroll
  for (int i = 0; i < 4; ++i)
#pragma unroll
    for (int j = 0; j < 4; ++j) {
      int c = c0 + j * 16;
      float bv = bias[c];
#pragma unroll
      for (int q = 0; q < 4; ++q) {
        int r = r0 + i * 16 + q;
        float v = acc[i][j][q] + bv;
        if (epi == 1) v = (v > 0.0f) ? v : expm1f(v);
        Cbf[(size_t)r * N + c] = f2bf(v);
      }
    }
}

// ---------------------------------------------------------------------------
// Fused gate + pooling (per mailbox)
// ---------------------------------------------------------------------------
__global__ __launch_bounds__(256) void k_gate_pool(
    const ushort* __restrict__ o, const float* __restrict__ gw,
    ushort* __restrict__ ae, float* __restrict__ gsum) {
  __shared__ float os[8][1024];
  __shared__ float lg[8][4];
  __shared__ float gs[8][4];
  const int b = blockIdx.x, t = threadIdx.x;
  for (int u = t; u < 8192; u += 256) {
    int l = u >> 10, d = u & 1023;
    os[l][d] = bf2f(o[(size_t)(b * 8 + l) * 1024 + d]);
  }
  __syncthreads();
  {
    int p = t >> 3, sub = t & 7;
    int l = p >> 2, e = p & 3;
    float s = 0;
    for (int d = sub; d < 1024; d += 8) s += os[l][d] * gw[d * 4 + e];
    s += __shfl_down(s, 4, 8);
    s += __shfl_down(s, 2, 8);
    s += __shfl_down(s, 1, 8);
    if (sub == 0) lg[l][e] = s;
  }
  __syncthreads();
  if (t < 8) {
    float m = fmaxf(fmaxf(lg[t][0], lg[t][1]), fmaxf(lg[t][2], lg[t][3]));
    float e0 = expf(lg[t][0] - m), e1 = expf(lg[t][1] - m);
    float e2 = expf(lg[t][2] - m), e3 = expf(lg[t][3] - m);
    float inv = 1.0f / (e0 + e1 + e2 + e3);
    gs[t][0] = e0 * inv; gs[t][1] = e1 * inv;
    gs[t][2] = e2 * inv; gs[t][3] = e3 * inv;
  }
  __syncthreads();
  if (t < 4) {
    float g = 0;
#pragma unroll
    for (int l = 0; l < 8; ++l) g += gs[l][t];
    gsum[b * 4 + t] = g;
  }
#pragma unroll
  for (int rep = 0; rep < 4; ++rep) {
    int d = t + rep * 256;
    float a0 = 0, a1 = 0, a2 = 0, a3 = 0;
#pragma unroll
    for (int l = 0; l < 8; ++l) {
      float ov = os[l][d];
      a0 += gs[l][0] * ov; a1 += gs[l][1] * ov;
      a2 += gs[l][2] * ov; a3 += gs[l][3] * ov;
    }
    ae[(size_t)0 * 524288 + b * 1024 + d] = f2bf(a0);
    ae[(size_t)1 * 524288 + b * 1024 + d] = f2bf(a1);
    ae[(size_t)2 * 524288 + b * 1024 + d] = f2bf(a2);
    ae[(size_t)3 * 524288 + b * 1024 + d] = f2bf(a3);
  }
}

// ---------------------------------------------------------------------------
// Pooled MoE GEMM (experts folded into K-accumulation)
// ---------------------------------------------------------------------------
__global__ __launch_bounds__(256) void gemm_moe2(
    const ushort* __restrict__ AE, const ushort* __restrict__ Bt4,
    const float* __restrict__ expb, const float* __restrict__ gsum,
    float* __restrict__ out) {
  __shared__ ushort As[64 * 40];
  __shared__ ushort Bs[64 * 40];
  const int bx = blockIdx.x, by = blockIdx.y;
  const int t = threadIdx.x;
  const int wv = t >> 6, lane = t & 63;
  const int wr = (wv >> 1) * 32, wc = (wv & 1) * 32;
  const int srow = t >> 2, sq = t & 3;
  const int la = lane & 15, lk = (lane >> 4) * 8;
  const int sdst = srow * 40 + sq * 8;
  f32x4 acc[2][2];
  const f32x4 z4 = {0.f, 0.f, 0.f, 0.f};
  acc[0][0] = z4; acc[0][1] = z4; acc[1][0] = z4; acc[1][1] = z4;
  for (int e = 0; e < 4; ++e) {
    const ushort* Ag = AE + (size_t)e * 524288 + (size_t)(by * 64 + srow) * 1024 + sq * 8;
    const ushort* Bg = Bt4 + (size_t)e * 1048576 + (size_t)(bx * 64 + srow) * 1024 + sq * 8;
    uint4 ra = *reinterpret_cast<const uint4*>(Ag);
    uint4 rb = *reinterpret_cast<const uint4*>(Bg);
    for (int kt = 0; kt < 1024; kt += 32) {
      __syncthreads();
      *reinterpret_cast<uint4*>(&As[sdst]) = ra;
      *reinterpret_cast<uint4*>(&Bs[sdst]) = rb;
      __syncthreads();
      if (kt + 32 < 1024) {
        ra = *reinterpret_cast<const uint4*>(Ag + kt + 32);
        rb = *reinterpret_cast<const uint4*>(Bg + kt + 32);
      }
      short8v af[2], bfr[2];
#pragma unroll
      for (int i = 0; i < 2; ++i)
        af[i] = *reinterpret_cast<const short8v*>(&As[(wr + i * 16 + la) * 40 + lk]);
#pragma unroll
      for (int j = 0; j < 2; ++j)
        bfr[j] = *reinterpret_cast<const short8v*>(&Bs[(wc + j * 16 + la) * 40 + lk]);
#pragma unroll
      for (int i = 0; i < 2; ++i)
#pragma unroll
        for (int j = 0; j < 2; ++j)
          acc[i][j] = __builtin_amdgcn_mfma_f32_16x16x32_bf16(af[i], bfr[j], acc[i][j], 0, 0, 0);
    }
  }
  const int r0 = by * 64 + wr + (lane >> 4) * 4;
  const int c0 = bx * 64 + wc + la;
#pragma unroll
  for (int i = 0; i < 2; ++i)
#pragma unroll
    for (int q = 0; q < 4; ++q) {
      int r = r0 + i * 16 + q;
      float4 gv = *reinterpret_cast<const float4*>(gsum + r * 4);
#pragma unroll
      for (int j = 0; j < 2; ++j) {
        int c = c0 + j * 16;
        float bias = gv.x * expb[c] + gv.y * expb[1024 + c] +
                     gv.z * expb[2048 + c] + gv.w * expb[3072 + c];
        float s = (acc[i][j][q] + bias) * 0.125f;
        out[(size_t)r * 1024 + c] = 1.0f / (1.0f + expf(-s));
      }
    }
}

// ---------------------------------------------------------------------------
// Symmetric Gram contrastive kernel (2080 triangular tiles)
// ---------------------------------------------------------------------------
__global__ __launch_bounds__(256) void gram_sym(
    const ushort* __restrict__ W, float* __restrict__ rsum,
    float* __restrict__ d11, float* __restrict__ d12, float* __restrict__ d22) {
  __shared__ ushort As[128 * 40];
  __shared__ ushort Bs[128 * 40];
  int tt = blockIdx.x, bi = 0, cnt = 64;
  while (tt >= cnt) { tt -= cnt; ++bi; --cnt; }
  int bj = bi + tt;
  const bool diag = (bi == bj);
  const int t = threadIdx.x;
  const int wv = t >> 6, lane = t & 63;
  const int wr = (wv >> 1) * 64, wc = (wv & 1) * 64;
  const int srow = t >> 1, shalf = t & 1;
  const ushort* Ag = W + (size_t)(bi * 128 + srow) * 128 + shalf * 16;
  const ushort* Bg = W + (size_t)(bj * 128 + srow) * 128 + shalf * 16;
  uint4 ra0 = *reinterpret_cast<const uint4*>(Ag);
  uint4 ra1 = *reinterpret_cast<const uint4*>(Ag + 8);
  uint4 rb0 = *reinterpret_cast<const uint4*>(Bg);
  uint4 rb1 = *reinterpret_cast<const uint4*>(Bg + 8);
  f32x4 acc[4][4];
  const f32x4 z4 = {0.f, 0.f, 0.f, 0.f};
#pragma unroll
  for (int i = 0; i < 4; ++i)
#pragma unroll
    for (int j = 0; j < 4; ++j) acc[i][j] = z4;
  const int la = lane & 15, lk = (lane >> 4) * 8;
  const int sdst = srow * 40 + shalf * 16;
  for (int kt = 0; kt < 128; kt += 32) {
    __syncthreads();
    *reinterpret_cast<uint4*>(&As[sdst])     = ra0;
    *reinterpret_cast<uint4*>(&As[sdst + 8]) = ra1;
    *reinterpret_cast<uint4*>(&Bs[sdst])     = rb0;
    *reinterpret_cast<uint4*>(&Bs[sdst + 8]) = rb1;
    __syncthreads();
    if (kt + 32 < 128) {
      ra0 = *reinterpret_cast<const uint4*>(Ag + kt + 32);
      ra1 = *reinterpret_cast<const uint4*>(Ag + kt + 40);
      rb0 = *reinterpret_cast<const uint4*>(Bg + kt + 32);
      rb1 = *reinterpret_cast<const uint4*>(Bg + kt + 40);
    }
    short8v af[4], bfr[4];
#pragma unroll
    for (int i = 0; i < 4; ++i)
      af[i] = *reinterpret_cast<const short8v*>(&As[(wr + i * 16 + la) * 40 + lk]);
#pragma unroll
    for (int j = 0; j < 4; ++j)
      bfr[j] = *reinterpret_cast<const short8v*>(&Bs[(wc + j * 16 + la) * 40 + lk]);
#pragma unroll
    for (int i = 0; i < 4; ++i)
#pragma unroll
      for (int j = 0; j < 4; ++j)
        acc[i][j] = __builtin_amdgcn_mfma_f32_16x16x32_bf16(af[i], bfr[j], acc[i][j], 0, 0, 0);
  }
  const int r0 = bi * 128 + wr + (lane >> 4) * 4;
  const int c0 = bj * 128 + wc + la;
  constexpr float K2 = 2.8853900817779268f;   // 2 / ln(2)
  float rs[4][4];
  float cs[4] = {0.f, 0.f, 0.f, 0.f};
#pragma unroll
  for (int i = 0; i < 4; ++i)
#pragma unroll
    for (int q = 0; q < 4; ++q) rs[i][q] = 0.f;
#pragma unroll
  for (int i = 0; i < 4; ++i)
#pragma unroll
    for (int j = 0; j < 4; ++j)
#pragma unroll
      for (int q = 0; q < 4; ++q) {
        int r = r0 + i * 16 + q;
        int c = c0 + j * 16;
        float e = exp2f(K2 * acc[i][j][q]);
        rs[i][q] += e;
        cs[j] += e;
        if (c == r)        { if (r < 4096) d11[r] = e; else d22[r - 4096] = e; }
        if (c == r + 4096) d12[r] = e;
      }
#pragma unroll
  for (int m = 1; m < 16; m <<= 1)
#pragma unroll
    for (int i = 0; i < 4; ++i)
#pragma unroll
      for (int q = 0; q < 4; ++q) rs[i][q] += __shfl_xor(rs[i][q], m);
  float* rowdst = rsum + ((bj >= 32) ? 8192 : 0);
  if (la == 0) {
#pragma unroll
    for (int i = 0; i < 4; ++i)
#pragma unroll
      for (int q = 0; q < 4; ++q) atomAdd(&rowdst[r0 + i * 16 + q], rs[i][q]);
  }
  if (!diag) {
#pragma unroll
    for (int j = 0; j < 4; ++j) {
      cs[j] += __shfl_xor(cs[j], 16);
      cs[j] += __shfl_xor(cs[j], 32);
    }
    float* coldst = rsum + ((bi >= 32) ? 8192 : 0);
    if ((lane >> 4) == 0) {
#pragma unroll
      for (int j = 0; j < 4; ++j) atomAdd(&coldst[c0 + j * 16], cs[j]);
    }
  }
}

__global__ __launch_bounds__(256) void cl_row(
    const float* __restrict__ rsum, const float* __restrict__ d11,
    const float* __restrict__ d12, const float* __restrict__ d22,
    float* __restrict__ cl_sum) {
  __shared__ float sh[256];
  int i = blockIdx.x * 256 + threadIdx.x;
  float denA = rsum[i] + rsum[8192 + i] - d11[i];
  float denB = rsum[8192 + 4096 + i] + rsum[4096 + i] - d22[i];
  float l = 0.5f * (logf(denA) + logf(denB)) - logf(d12[i]);
  float s = blockReduce256(l, sh, threadIdx.x);
  if (threadIdx.x == 0) atomAdd(cl_sum, s);
}

// weight transpose + bf16 convert: Bt[n*K+k] = bf16(W[k*N+n])
__global__ __launch_bounds__(256) void k_wt_bt(const float* __restrict__ W,
                                               ushort* __restrict__ Bt, int K, int N) {
  __shared__ float tile[32][33];
  int n0 = blockIdx.x * 32, k0 = blockIdx.y * 32;
  int tx = threadIdx.x & 31, ty = threadIdx.x >> 5;
#pragma unroll
  for (int i = 0; i < 4; ++i)
    tile[ty + 8 * i][tx] = W[(size_t)(k0 + ty + 8 * i) * N + n0 + tx];
  __syncthreads();
#pragma unroll
  for (int i = 0; i < 4; ++i)
    Bt[(size_t)(n0 + ty + 8 * i) * K + k0 + tx] = f2bf(tile[tx][ty + 8 * i]);
}

// batched transpose: W strided by z (contiguous weights, e.g. experts)
__global__ __launch_bounds__(256) void k_wt_bt_s(const float* __restrict__ Wbase,
                                                 ushort* __restrict__ Btbase, int K, int N) {
  __shared__ float tile[32][33];
  const float* W = Wbase + (size_t)blockIdx.z * K * N;
  ushort* Bt = Btbase + (size_t)blockIdx.z * K * N;
  int n0 = blockIdx.x * 32, k0 = blockIdx.y * 32;
  int tx = threadIdx.x & 31, ty = threadIdx.x >> 5;
#pragma unroll
  for (int i = 0; i < 4; ++i)
    tile[ty + 8 * i][tx] = W[(size_t)(k0 + ty + 8 * i) * N + n0 + tx];
  __syncthreads();
#pragma unroll
  for (int i = 0; i < 4; ++i)
    Bt[(size_t)(n0 + ty + 8 * i) * K + k0 + tx] = f2bf(tile[tx][ty + 8 * i]);
}

// batched transpose for 3 separate weight pointers (QKV)
__global__ __launch_bounds__(256) void k_wt_bt3(const float* __restrict__ w0,
                                                const float* __restrict__ w1,
                                                const float* __restrict__ w2,
                                                ushort* __restrict__ Btbase, int K, int N) {
  __shared__ float tile[32][33];
  const float* W = (blockIdx.z == 0) ? w0 : (blockIdx.z == 1) ? w1 : w2;
  ushort* Bt = Btbase + (size_t)blockIdx.z * K * N;
  int n0 = blockIdx.x * 32, k0 = blockIdx.y * 32;
  int tx = threadIdx.x & 31, ty = threadIdx.x >> 5;
#pragma unroll
  for (int i = 0; i < 4; ++i)
    tile[ty + 8 * i][tx] = W[(size_t)(k0 + ty + 8 * i) * N + n0 + tx];
  __syncthreads();
#pragma unroll
  for (int i = 0; i < 4; ++i)
    Bt[(size_t)(n0 + ty + 8 * i) * K + k0 + tx] = f2bf(tile[tx][ty + 8 * i]);
}

// S1|S2 (f32) -> SB bf16 [8192][128]
__global__ __launch_bounds__(256) void s_to_bf(const float* __restrict__ s1,
                                               const float* __restrict__ s2,
                                               ushort* __restrict__ sb) {
  int idx = blockIdx.x * 256 + threadIdx.x;
  float v = (idx < 524288) ? s1[idx] : s2[idx - 524288];
  sb[idx] = f2bf(v);
}

// in-place bf16 row normalize
__global__ __launch_bounds__(128) void rownorm_bf2(ushort* __restrict__ w) {
  __shared__ float sh[128];
  int i = blockIdx.x, tid = threadIdx.x;
  float v = bf2f(w[(size_t)i * cD + tid]);
  float ss = blockReduce128(v * v, sh, tid);
  float n = fmaxf(sqrtf(ss), 1e-12f);
  w[(size_t)i * cD + tid] = f2bf(v / n);
}

// ---------------------------------------------------------------------------
// message / losses / MHA
// ---------------------------------------------------------------------------
__global__ __launch_bounds__(256) void emb_sum_k(
    const float* __restrict__ s1, const float* __restrict__ s2,
    const float* __restrict__ relation, const int* __restrict__ etype, float* __restrict__ out) {
  __shared__ float sh[256];
  int idx = blockIdx.x * 256 + threadIdx.x;
  int i = idx >> 8, j = idx & 255;
  float a = (j < 128) ? s1[(size_t)i * 128 + j] : s2[(size_t)i * 128 + j - 128];
  int et = etype[i];
  float r = relation[(size_t)(et % cNR) * 256 + j];
  float t = blockReduce256(a * a + r * r, sh, threadIdx.x);
  if (threadIdx.x == 0) atomAdd(out, t);
}

__global__ __launch_bounds__(256) void msg_build(
    const float* __restrict__ s1, const float* __restrict__ s2,
    const float* __restrict__ relation, const int* __restrict__ etype,
    ushort* __restrict__ msg) {
  int idx = blockIdx.x * 256 + threadIdx.x;
  int i = idx >> 8, j = idx & 255;
  int et = etype[i];
  float sign = (et >= cNR) ? -1.0f : 1.0f;
  float r = relation[(size_t)(et % cNR) * 256 + j] * sign;
  float s = (j < 128) ? s1[(size_t)i * 128 + j] : s2[(size_t)i * 128 + j - 128];
  msg[idx] = f2bf(fmaxf(s + r, 0.0f));
}

// fused-QKV attention: qkv [4096][3072] (Q|K|V per row), o [4096][1024] bf16
__global__ __launch_bounds__(64) void mha_attn(
    const ushort* __restrict__ qkv, ushort* __restrict__ o) {
  __shared__ float qs[8][132], ks[8][132], vs[8][132];
  __shared__ float att[8][8];
  int bh = blockIdx.x;
  int b = bh >> 3, h = bh & 7;
  int tid = threadIdx.x;
  for (int u = tid; u < 256; u += 64) {
    int l = u >> 5;
    int d4 = (u & 31) * 4;
    size_t base = (size_t)(b * 8 + l) * 3072 + h * 128 + d4;
    ushort4 qv = *reinterpret_cast<const ushort4*>(qkv + base);
    ushort4 kv = *reinterpret_cast<const ushort4*>(qkv + base + 1024);
    ushort4 vv = *reinterpret_cast<const ushort4*>(qkv + base + 2048);
    qs[l][d4] = bf2f(qv.x); qs[l][d4 + 1] = bf2f(qv.y);
    qs[l][d4 + 2] = bf2f(qv.z); qs[l][d4 + 3] = bf2f(qv.w);
    ks[l][d4] = bf2f(kv.x); ks[l][d4 + 1] = bf2f(kv.y);
    ks[l][d4 + 2] = bf2f(kv.z); ks[l][d4 + 3] = bf2f(kv.w);
    vs[l][d4] = bf2f(vv.x); vs[l][d4 + 1] = bf2f(vv.y);
    vs[l][d4 + 2] = bf2f(vv.z); vs[l][d4 + 3] = bf2f(vv.w);
  }
  __syncthreads();
  int l = tid >> 3, m = tid & 7;
  const float4* qp = reinterpret_cast<const float4*>(&qs[l][0]);
  const float4* kp = reinterpret_cast<const float4*>(&ks[m][0]);
  float s = 0;
#pragma unroll
  for (int d4 = 0; d4 < 32; ++d4) {
    float4 a = qp[d4], bb = kp[d4];
    s += a.x * bb.x + a.y * bb.y + a.z * bb.z + a.w * bb.w;
  }
  s *= 0.08838834764831845f;
  float mx = s;
  for (int off = 1; off < 8; off <<= 1) mx = fmaxf(mx, __shfl_xor(mx, off, 8));
  float p = expf(s - mx);
  float sum = p;
  for (int off = 1; off < 8; off <<= 1) sum += __shfl_xor(sum, off, 8);
  att[l][m] = p / sum;
  __syncthreads();
  for (int u = tid; u < 1024; u += 64) {
    int ll = u >> 7, d = u & 127;
    float acc = 0;
#pragma unroll
    for (int mm = 0; mm < 8; ++mm) acc += att[ll][mm] * vs[mm][d];
    o[(size_t)(b * 8 + ll) * 1024 + h * 128 + d] = f2bf(acc);
  }
}

__global__ void finalize_k(const float* __restrict__ scal, float* __restrict__ out_aux) {
  float cl = scal[0] * (1.0f / cNSRC);
  float emb = cDECAY * 0.5f * scal[1] * (1.0f / cNSRC);
  out_aux[0] = cCLW * cl + emb;
}

// ---------------------------------------------------------------------------
// Launch
// ---------------------------------------------------------------------------
extern "C" void kernel_launch(void* const* d_in, const int* in_sizes, int n_in,
                              void* d_out, int out_size, void* d_ws, size_t ws_size,
                              hipStream_t stream) {
  (void)in_sizes; (void)n_in; (void)out_size; (void)ws_size;
  const float* entity   = (const float*)d_in[0];
  const float* type_e   = (const float*)d_in[1];
  const float* cluster  = (const float*)d_in[2];
  const float* relation = (const float*)d_in[3];
  const float* ln_g  = (const float*)d_in[4];
  const float* ln_b  = (const float*)d_in[5];
  const float* cl_w1 = (const float*)d_in[6];
  const float* cl_b1 = (const float*)d_in[7];
  const float* cl_w2 = (const float*)d_in[8];
  const float* cl_b2 = (const float*)d_in[9];
  const float* fc_w  = (const float*)d_in[10];
  const float* fc_b  = (const float*)d_in[11];
  const float* wq = (const float*)d_in[12];
  const float* bq = (const float*)d_in[13];
  const float* wk = (const float*)d_in[14];
  const float* bk = (const float*)d_in[15];
  const float* wv = (const float*)d_in[16];
  const float* bv = (const float*)d_in[17];
  const float* wo = (const float*)d_in[18];
  const float* bo = (const float*)d_in[19];
  const float* gate_w = (const float*)d_in[20];
  const float* exp_w  = (const float*)d_in[21];
  const float* exp_b  = (const float*)d_in[22];
  const float* e2t_val = (const float*)d_in[23];
  const float* t2c_val = (const float*)d_in[24];
  const float* e2c_val = (const float*)d_in[25];
  const int* e2t_row = (const int*)d_in[26];
  const int* e2t_col = (const int*)d_in[27];
  const int* t2c_row = (const int*)d_in[28];
  const int* t2c_col = (const int*)d_in[29];
  const int* e2c_row = (const int*)d_in[30];
  const int* e2c_col = (const int*)d_in[31];
  const int* src_ids = (const int*)d_in[32];
  const int* etype   = (const int*)d_in[33];

  float* ws = (float*)d_ws;
  float* S1 = ws + F_S1;
  float* S2 = ws + F_S2;
  ushort* Wbf = (ushort*)(ws + F_PT);
  ushort* P1bf = (ushort*)(ws + F_Z1);
  ushort* SBbf = (ushort*)(ws + F_Z2);
  ushort* MSGbf = (ushort*)(ws + F_MSG);
  float* GSUM = ws + F_GATE;
  float* SCAL = ws + F_SCAL;
  float* RS   = ws + F_RS;
  float* BQKV = ws + F_RS;
  float* D11  = ws + F_D11;
  float* D12  = ws + F_D12;
  float* D22  = ws + F_D22;
  ushort* X1F = (ushort*)(ws + G_X1F);
  ushort* X2C = (ushort*)(ws + G_X2C);
  int*   MARK = (int*)(ws + G_X2C);     // aliased: dead before X2C written
  int*   SLOT = (int*)(ws + G_SLOT);
  int*   REP  = (int*)(ws + G_REP);
  int*   RP   = (int*)(ws + G_RP);
  int*   FILL = (int*)(ws + G_FILL);
  int*   COLS = (int*)(ws + G_COLS);
  float* VALS = ws + G_VALS;
  ushort* X1T = (ushort*)(ws + G_X1T);
  ushort* X2T = (ushort*)(ws + G_X2T);
  int*   BSUM = (int*)(ws + G_BSUM);
  ushort* PB   = (ushort*)(ws + A_U0);
  ushort* AE   = (ushort*)(ws + A_U0);
  ushort* QKV  = (ushort*)(ws + A_U1);
  ushort* OB   = (ushort*)(ws + A_U1);
  ushort* WBT  = (ushort*)(ws + A_WBT);

  hipMemsetAsync(SCAL, 0, 2 * sizeof(float), stream);
  hipMemsetAsync(RS, 0, (16384 + 3 * 4096) * sizeof(float), stream);

  // masked GCN
  auto run_gcn_masked = [&](const int* row, const int* col, const float* val, int nnz, int nn,
                            const float* ea, const float* eb, int na, int mode,
                            float* dst) {
    int nb = (nn + 255) / 256;
    int gEdge = (nnz + 255) / 256;
    k_init3<<<nb, 256, 0, stream>>>(SLOT, MARK, FILL, nn);
    k_slot_mark<<<16, 256, 0, stream>>>(src_ids, SLOT, MARK, mode);
    k_mark_edges<<<gEdge, 256, 0, stream>>>(row, col, nnz, SLOT, MARK);
    k_hist<<<gEdge, 256, 0, stream>>>(row, nnz, MARK, FILL);
    k_scan_block<<<nb, 256, 0, stream>>>(FILL, nn, RP, BSUM);
    k_bsum_scan<<<1, 512, 0, stream>>>(BSUM, nb, RP, nn);
    k_scan_add<<<nb, 256, 0, stream>>>(RP, BSUM, nn, FILL);
    k_fill<<<gEdge, 256, 0, stream>>>(row, col, val, nnz, MARK, FILL, COLS, VALS);
    k_rep<<<16, 256, 0, stream>>>(src_ids, SLOT, mode, REP);
    k_gather<<<(nn + 3) / 4, 256, 0, stream>>>(RP, COLS, VALS, ea, eb, na, nn, MARK, X1F);
    k_gather_slot<<<cNSRC / 4, 256, 0, stream>>>(RP, COLS, VALS, X1F, REP, X2C);
    gather_ln<<<cNSRC, 128, 0, stream>>>(src_ids, mode, ea, eb, na, X1F, X2C, SLOT,
                                         ln_g, ln_b, dst);
  };

  run_gcn_masked(e2t_row, e2t_col, e2t_val, cNNZ_E2T, cNN_E2T, entity, type_e, cNE, 0, S1);
  run_gcn_masked(e2c_row, e2c_col, e2c_val, cNNZ_E2C, cNN_E2C, entity, cluster, cNE, 3, S2);

  // ---- t2c: tiny, both layers full ----
  {
    int nn = cNN_T2C, nb = (nn + 255) / 256, gEdge = (cNNZ_T2C + 255) / 256;
    hipMemsetAsync(FILL, 0, (size_t)nn * sizeof(int), stream);
    k_hist<<<gEdge, 256, 0, stream>>>(t2c_row, cNNZ_T2C, nullptr, FILL);
    k_scan_block<<<nb, 256, 0, stream>>>(FILL, nn, RP, BSUM);
    k_bsum_scan<<<1, 512, 0, stream>>>(BSUM, nb, RP, nn);
    k_scan_add<<<nb, 256, 0, stream>>>(RP, BSUM, nn, FILL);
    k_fill<<<gEdge, 256, 0, stream>>>(t2c_row, t2c_col, t2c_val, cNNZ_T2C, nullptr,
                                      FILL, COLS, VALS);
    k_gather<<<(nn + 3) / 4, 256, 0, stream>>>(RP, COLS, VALS, type_e, cluster, cNT,
                                               nn, nullptr, X1T);
    k_gather_bf<<<(nn + 3) / 4, 256, 0, stream>>>(RP, COLS, VALS, X1T, nn, X2T);
    gather_ln<<<cNSRC, 128, 0, stream>>>(src_ids, 1, type_e, cluster, cNT, X1T, X2T, nullptr,
                                         ln_g, ln_b, S1);
    gather_ln<<<cNSRC, 128, 0, stream>>>(src_ids, 2, type_e, cluster, cNT, X1T, X2T, nullptr,
                                         ln_g, ln_b, S2);
  }

  // ================= contrastive loss =================
  ushort* W1T = WBT;
  ushort* W2T = WBT + 16384;
  k_wt_bt<<<dim3(4, 4), 256, 0, stream>>>(cl_w1, W1T, cD, cD);
  k_wt_bt<<<dim3(4, 4), 256, 0, stream>>>(cl_w2, W2T, cD, cD);
  s_to_bf<<<4096, 256, 0, stream>>>(S1, S2, SBbf);
  gemm_bf<<<dim3(1, 64), 256, 0, stream>>>(SBbf, W1T, cD, cD, cl_b1, P1bf, 1);
  gemm_bf<<<dim3(1, 64), 256, 0, stream>>>(P1bf, W2T, cD, cD, cl_b2, Wbf, 0);
  rownorm_bf2<<<2 * cNSRC, 128, 0, stream>>>(Wbf);
  gram_sym<<<2080, 256, 0, stream>>>(Wbf, RS, D11, D12, D22);
  cl_row<<<16, 256, 0, stream>>>(RS, D11, D12, D22, SCAL);
  emb_sum_k<<<cNSRC, 256, 0, stream>>>(S1, S2, relation, etype, SCAL + 1);

  // ================= message + predict =================
  msg_build<<<cNSRC, 256, 0, stream>>>(S1, S2, relation, etype, MSGbf);
  k_wt_bt<<<dim3(cT / 32, 256 / 32), 256, 0, stream>>>(fc_w, WBT, 256, cT);
  gemm_bf<<<dim3(cT / 128, cNSRC / 128), 256, 0, stream>>>(MSGbf, WBT, cT, 256, fc_b, PB, 0);

  // ================= MHA: fused QKV =================
  k_wt_bt3<<<dim3(32, 32, 3), 256, 0, stream>>>(wq, wk, wv, WBT, cT, cT);
  hipMemcpyAsync(BQKV,        bq, cT * sizeof(float), hipMemcpyDeviceToDevice, stream);
  hipMemcpyAsync(BQKV + 1024, bk, cT * sizeof(float), hipMemcpyDeviceToDevice, stream);
  hipMemcpyAsync(BQKV + 2048, bv, cT * sizeof(float), hipMemcpyDeviceToDevice, stream);
  gemm_bf<<<dim3(3072 / 128, cNSRC / 128), 256, 0, stream>>>(PB, WBT, 3072, cT, BQKV, QKV, 0);
  mha_attn<<<cB * 8, 64, 0, stream>>>(QKV, PB);                 // attn-out -> A_U0
  k_wt_bt<<<dim3(32, 32), 256, 0, stream>>>(wo, WBT, cT, cT);
  gemm_bf<<<dim3(cT / 128, cNSRC / 128), 256, 0, stream>>>(PB, WBT, cT, cT, bo, OB, 0);

  // ================= pooled MoE =================
  k_gate_pool<<<cB, 256, 0, stream>>>(OB, gate_w, AE, GSUM);
  k_wt_bt_s<<<dim3(32, 32, 4), 256, 0, stream>>>(exp_w, WBT, cT, cT);
  gemm_moe2<<<dim3(16, 8), 256, 0, stream>>>(AE, WBT, exp_b, GSUM, (float*)d_out);

  finalize_k<<<1, 1, 0, stream>>>(SCAL, (float*)d_out + (size_t)cB * cT);
}

// Round 8
// 535.392 us; speedup vs baseline: 10.2445x; 1.0760x over previous
//
#include <hip/hip_runtime.h>
#include <hip/hip_bf16.h>
#include <cmath>

// ---------------------------------------------------------------------------
// Problem constants (fixed shapes)
// ---------------------------------------------------------------------------
constexpr int cNE = 100000, cNT = 1024, cNC = 128, cD = 128, cNR = 500;
constexpr int cB = 512, cNSRC = 4096, cT = 1024, cE = 4;
constexpr int cNNZ_E2T = 1000000, cNNZ_T2C = 50000, cNNZ_E2C = 500000;
constexpr float cDECAY = 1e-4f, cCLW = 0.1f;
constexpr int cNN_E2T = cNE + cNT;     // 101024
constexpr int cNN_E2C = cNE + cNC;     // 100128
constexpr int cNN_T2C = cNT + cNC;     // 1152

// ---------------------------------------------------------------------------
// Workspace layout (FLOAT units)
// ---------------------------------------------------------------------------
constexpr size_t F_S1   = 0;                          // f32 4096x128
constexpr size_t F_S2   = F_S1 + 524288;
constexpr size_t F_PT   = F_S2 + 524288;              // bf16 W [8192][128] (Z/normed)
constexpr size_t F_Z1   = F_PT + 524288;              // bf16 P1 [8192][128]
constexpr size_t F_Z2   = F_Z1 + 524288;              // bf16 SB [8192][128]
constexpr size_t F_MSG  = F_Z2 + 524288;              // bf16 4096x256
constexpr size_t F_GATE = F_MSG + 524288;             // f32 GSUM [512][4]
constexpr size_t F_SCAL = F_GATE + 16384;
constexpr size_t F_RS   = F_SCAL + 64;                // f32 [2][8192] gram sums; later bias_qkv
constexpr size_t F_D11  = F_RS + 16384;               // f32 [4096]
constexpr size_t F_D12  = F_D11 + 4096;
constexpr size_t F_D22  = F_D12 + 4096;
constexpr size_t F_U    = F_D22 + 4096;               // union base
// --- GCN phase (X1/X2 bf16) ---
constexpr size_t G_X1F  = F_U;                        // ushort[101024*128] = 6,465,536 fl
constexpr size_t G_X2C  = G_X1F + 6465536;            // ushort[4096*128] (also MARK int[101376])
constexpr size_t G_SLOT = G_X2C + 262144;             // int[101376]
constexpr size_t G_REP  = G_SLOT + 101376;            // int[4096]
constexpr size_t G_RP   = G_REP + 4096;               // int[101376]
constexpr size_t G_FILL = G_RP + 101376;              // int[101376]
constexpr size_t G_COLS = G_FILL + 101376;            // int[1000000]
constexpr size_t G_VALS = G_COLS + 1000000;           // f32[1000000]
constexpr size_t G_X1T  = G_VALS + 1000000;           // ushort[1152*128] = 73728 fl
constexpr size_t G_X2T  = G_X1T + 73728;
constexpr size_t G_BSUM = G_X2T + 73728;              // int[512]
// --- activation phase ---
constexpr size_t A_U0  = F_U;                 // predict bf16; attn-out; then AE bf16 [4][512][1024]
constexpr size_t A_U1  = F_U + 2097152;       // QKV bf16 [4096][3072] spans U1..U3; then O
constexpr size_t A_WBT = F_U + 4 * 2097152;   // bf16 weight^T scratch

typedef __attribute__((ext_vector_type(8))) short short8v;
typedef __attribute__((ext_vector_type(4))) float f32x4;

// ---------------------------------------------------------------------------
// Helpers
// ---------------------------------------------------------------------------
__device__ __forceinline__ void atomAdd(float* p, float v) {
  __hip_atomic_fetch_add(p, v, __ATOMIC_RELAXED, __HIP_MEMORY_SCOPE_AGENT);
}
__device__ __forceinline__ ushort f2bf(float f) {
  __hip_bfloat16 h = __float2bfloat16(f);
  return *reinterpret_cast<ushort*>(&h);
}
__device__ __forceinline__ float bf2f(ushort u) {
  __hip_bfloat16 h; *reinterpret_cast<ushort*>(&h) = u;
  return __bfloat162float(h);
}

__device__ __forceinline__ int mapNode(int mode, int id) {
  switch (mode) {
    case 0:  return (id < cNE + cNT) ? id : -1;
    case 1:  return (id >= cNE + cNT) ? (id - cNE) : -1;
    case 2:  return (id >= cNE && id < cNE + cNT) ? (id - cNE) : -1;
    default: return (id < cNE) ? id
                   : ((id >= cNE + cNT) ? (id - cNT) : -1);
  }
}

__device__ __forceinline__ float blockReduce256(float v, float* sh, int tid) {
  sh[tid] = v; __syncthreads();
  for (int s = 128; s > 0; s >>= 1) {
    if (tid < s) sh[tid] += sh[tid + s];
    __syncthreads();
  }
  float r = sh[0]; __syncthreads();
  return r;
}

// ---------------------------------------------------------------------------
// init + mask + CSR build
// ---------------------------------------------------------------------------
__global__ __launch_bounds__(256) void k_init3(int* __restrict__ slot, int* __restrict__ mark,
                                               int* __restrict__ fill, int n) {
  int i = blockIdx.x * 256 + threadIdx.x;
  if (i < n) { slot[i] = 0x7f7f7f7f; mark[i] = 0; fill[i] = 0; }
}

__global__ __launch_bounds__(256) void k_slot_mark(const int* __restrict__ ids,
                                                   int* __restrict__ slot,
                                                   int* __restrict__ mark, int mode) {
  int i = blockIdx.x * 256 + threadIdx.x;
  if (i >= cNSRC) return;
  int node = mapNode(mode, ids[i]);
  if (node >= 0) { atomicMin(&slot[node], i); mark[node] = 1; }
}

__global__ __launch_bounds__(256) void k_mark_edges(const int* __restrict__ row,
                                                    const int* __restrict__ col, int nnz,
                                                    const int* __restrict__ slot,
                                                    int* __restrict__ mark) {
  int e = blockIdx.x * 256 + threadIdx.x;
  if (e >= nnz) return;
  int r = row[e];
  if (slot[r] < cNSRC) mark[col[e]] = 1;
}

__global__ __launch_bounds__(256) void k_hist(const int* __restrict__ row, int nnz,
                                              const int* __restrict__ mark,
                                              int* __restrict__ cnt) {
  int e = blockIdx.x * 256 + threadIdx.x;
  if (e >= nnz) return;
  int r = row[e];
  if (mark && !mark[r]) return;
  atomicAdd(&cnt[r], 1);
}

__global__ __launch_bounds__(256) void k_scan_block(const int* __restrict__ cnt, int n,
                                                    int* __restrict__ excl, int* __restrict__ bsum) {
  __shared__ int sh[256];
  int tid = threadIdx.x;
  int i = blockIdx.x * 256 + tid;
  int v = (i < n) ? cnt[i] : 0;
  sh[tid] = v; __syncthreads();
  for (int off = 1; off < 256; off <<= 1) {
    int t = (tid >= off) ? sh[tid - off] : 0;
    __syncthreads();
    sh[tid] += t;
    __syncthreads();
  }
  if (i < n) excl[i] = sh[tid] - v;
  if (tid == 255) bsum[blockIdx.x] = sh[255];
}

__global__ __launch_bounds__(512) void k_bsum_scan(int* __restrict__ bsum, int nb,
                                                   int* __restrict__ rowptr, int n) {
  __shared__ int sh[512];
  int tid = threadIdx.x;
  int v = (tid < nb) ? bsum[tid] : 0;
  sh[tid] = v; __syncthreads();
  for (int off = 1; off < 512; off <<= 1) {
    int t = (tid >= off) ? sh[tid - off] : 0;
    __syncthreads();
    sh[tid] += t;
    __syncthreads();
  }
  if (tid < nb) bsum[tid] = sh[tid] - v;
  if (tid == 511) rowptr[n] = sh[511];
}

__global__ __launch_bounds__(256) void k_scan_add(int* __restrict__ rowptr,
                                                  const int* __restrict__ bsum, int n,
                                                  int* __restrict__ fill) {
  int i = blockIdx.x * 256 + threadIdx.x;
  if (i < n) {
    int r = rowptr[i] + bsum[blockIdx.x];
    rowptr[i] = r;
    fill[i] = r;
  }
}

// fill writes CSR-ordered (col,val) payload: removes eidx indirection at gather
__global__ __launch_bounds__(256) void k_fill(const int* __restrict__ row,
                                              const int* __restrict__ col,
                                              const float* __restrict__ val, int nnz,
                                              const int* __restrict__ mark,
                                              int* __restrict__ fill,
                                              int* __restrict__ cols, float* __restrict__ vals) {
  int e = blockIdx.x * 256 + threadIdx.x;
  if (e >= nnz) return;
  int r = row[e];
  if (mark && !mark[r]) return;
  int pos = atomicAdd(&fill[r], 1);
  cols[pos] = col[e];
  vals[pos] = val[e];
}

// wave-per-row gather, f32 embeddings in -> bf16 out
__global__ __launch_bounds__(256) void k_gather(
    const int* __restrict__ rowptr, const int* __restrict__ cols, const float* __restrict__ vals,
    const float* __restrict__ ea, const float* __restrict__ eb, int na,
    int nrows, const int* __restrict__ mark, ushort* __restrict__ out) {
  int r = blockIdx.x * 4 + (threadIdx.x >> 6);
  if (r >= nrows) return;
  if (mark && !mark[r]) return;
  int lane = threadIdx.x & 63;
  int p0 = rowptr[r], p1 = rowptr[r + 1];
  float ax = 0.f, ay = 0.f;
  int p = p0;
  for (; p + 2 <= p1; p += 2) {
    int c0 = cols[p], c1 = cols[p + 1];
    float v0 = vals[p], v1 = vals[p + 1];
    const float* s0 = (c0 < na) ? (ea + (size_t)c0 * cD) : (eb + (size_t)(c0 - na) * cD);
    const float* s1 = (c1 < na) ? (ea + (size_t)c1 * cD) : (eb + (size_t)(c1 - na) * cD);
    float2 x0 = *reinterpret_cast<const float2*>(s0 + lane * 2);
    float2 x1 = *reinterpret_cast<const float2*>(s1 + lane * 2);
    ax += v0 * x0.x + v1 * x1.x;
    ay += v0 * x0.y + v1 * x1.y;
  }
  if (p < p1) {
    int c = cols[p];
    float v = vals[p];
    const float* s = (c < na) ? (ea + (size_t)c * cD) : (eb + (size_t)(c - na) * cD);
    float2 x = *reinterpret_cast<const float2*>(s + lane * 2);
    ax += v * x.x; ay += v * x.y;
  }
  ushort2 o; o.x = f2bf(ax); o.y = f2bf(ay);
  *reinterpret_cast<ushort2*>(out + (size_t)r * cD + lane * 2) = o;
}

__global__ __launch_bounds__(256) void k_rep(const int* __restrict__ ids,
                                             const int* __restrict__ slot, int mode,
                                             int* __restrict__ rep) {
  int i = blockIdx.x * 256 + threadIdx.x;
  if (i >= cNSRC) return;
  int node = mapNode(mode, ids[i]);
  rep[i] = (node >= 0 && slot[node] == i) ? node : -1;
}

// layer-2 gather at representative slots: bf16 x1 in -> bf16 out
__global__ __launch_bounds__(256) void k_gather_slot(
    const int* __restrict__ rowptr, const int* __restrict__ cols, const float* __restrict__ vals,
    const ushort* __restrict__ x1, const int* __restrict__ rep,
    ushort* __restrict__ outc) {
  int i = blockIdx.x * 4 + (threadIdx.x >> 6);
  if (i >= cNSRC) return;
  int r = rep[i];
  if (r < 0) return;
  int lane = threadIdx.x & 63;
  int p0 = rowptr[r], p1 = rowptr[r + 1];
  float ax = 0.f, ay = 0.f;
  int p = p0;
  for (; p + 2 <= p1; p += 2) {
    int c0 = cols[p], c1 = cols[p + 1];
    float v0 = vals[p], v1 = vals[p + 1];
    ushort2 x0 = *reinterpret_cast<const ushort2*>(x1 + (size_t)c0 * cD + lane * 2);
    ushort2 x1v = *reinterpret_cast<const ushort2*>(x1 + (size_t)c1 * cD + lane * 2);
    ax += v0 * bf2f(x0.x) + v1 * bf2f(x1v.x);
    ay += v0 * bf2f(x0.y) + v1 * bf2f(x1v.y);
  }
  if (p < p1) {
    int c = cols[p];
    float v = vals[p];
    ushort2 x = *reinterpret_cast<const ushort2*>(x1 + (size_t)c * cD + lane * 2);
    ax += v * bf2f(x.x); ay += v * bf2f(x.y);
  }
  ushort2 o; o.x = f2bf(ax); o.y = f2bf(ay);
  *reinterpret_cast<ushort2*>(outc + (size_t)i * cD + lane * 2) = o;
}

// full-row gather, bf16 in -> bf16 out (t2c layer 2)
__global__ __launch_bounds__(256) void k_gather_bf(
    const int* __restrict__ rowptr, const int* __restrict__ cols, const float* __restrict__ vals,
    const ushort* __restrict__ x1, int nrows, ushort* __restrict__ out) {
  int r = blockIdx.x * 4 + (threadIdx.x >> 6);
  if (r >= nrows) return;
  int lane = threadIdx.x & 63;
  int p0 = rowptr[r], p1 = rowptr[r + 1];
  float ax = 0.f, ay = 0.f;
  for (int p = p0; p < p1; ++p) {
    int c = cols[p];
    float v = vals[p];
    ushort2 x = *reinterpret_cast<const ushort2*>(x1 + (size_t)c * cD + lane * 2);
    ax += v * bf2f(x.x); ay += v * bf2f(x.y);
  }
  ushort2 o; o.x = f2bf(ax); o.y = f2bf(ay);
  *reinterpret_cast<ushort2*>(out + (size_t)r * cD + lane * 2) = o;
}

// (x0 + x1 + x2)/3 at gathered rows -> LayerNorm -> dst (x1,x2 bf16)
// wave-level dual reduction: 2 waves, 1 syncthreads
__global__ __launch_bounds__(128) void gather_ln(
    const int* __restrict__ ids, int mode,
    const float* __restrict__ ea, const float* __restrict__ eb, int na,
    const ushort* __restrict__ x1, const ushort* __restrict__ x2, const int* __restrict__ slot,
    const float* __restrict__ g, const float* __restrict__ bia, float* __restrict__ dst) {
  __shared__ float shx[2], shy[2];
  int i = blockIdx.x;
  int tid = threadIdx.x;
  int id = ids[i];
  int node = mapNode(mode, id);
  if (node < 0) return;
  const float* x0 = (node < na) ? (ea + (size_t)node * cD) : (eb + (size_t)(node - na) * cD);
  int xi2 = slot ? slot[node] : node;
  float a = (x0[tid] + bf2f(x1[(size_t)node * cD + tid]) + bf2f(x2[(size_t)xi2 * cD + tid]))
            * (1.0f / 3.0f);
  float sx = a, sy = a * a;
#pragma unroll
  for (int off = 32; off > 0; off >>= 1) {
    sx += __shfl_xor(sx, off);
    sy += __shfl_xor(sy, off);
  }
  if ((tid & 63) == 0) { shx[tid >> 6] = sx; shy[tid >> 6] = sy; }
  __syncthreads();
  float s  = shx[0] + shx[1];
  float ss = shy[0] + shy[1];
  float mu = s * (1.0f / 128.0f);
  float var = ss * (1.0f / 128.0f) - mu * mu;
  float y = (a - mu) * rsqrtf(var + 1e-5f) * g[tid] + bia[tid];
  dst[(size_t)i * cD + tid] = y;
}

// ---------------------------------------------------------------------------
// bf16 MFMA GEMM: C[M,N] = A[M,K] @ Bt[N,K]^T, 128x128 tile, 4 waves
// epi 0: store bf16(acc+bias); epi 1: store bf16(ELU(acc+bias))
// ---------------------------------------------------------------------------
__global__ __launch_bounds__(256) void gemm_bf(
    const ushort* __restrict__ A, const ushort* __restrict__ Bt,
    int N, int K, const float* __restrict__ bias, ushort* __restrict__ Cbf, int epi) {
  __shared__ ushort As[128 * 40];
  __shared__ ushort Bs[128 * 40];
  const int bx = blockIdx.x, by = blockIdx.y;
  const int t = threadIdx.x;
  const int wv = t >> 6, lane = t & 63;
  const int wr = (wv >> 1) * 64, wc = (wv & 1) * 64;
  const int srow = t >> 1, shalf = t & 1;
  const ushort* Ag = A + (size_t)(by * 128 + srow) * K + shalf * 16;
  const ushort* Bg = Bt + (size_t)(bx * 128 + srow) * K + shalf * 16;
  uint4 ra0 = *reinterpret_cast<const uint4*>(Ag);
  uint4 ra1 = *reinterpret_cast<const uint4*>(Ag + 8);
  uint4 rb0 = *reinterpret_cast<const uint4*>(Bg);
  uint4 rb1 = *reinterpret_cast<const uint4*>(Bg + 8);
  f32x4 acc[4][4];
  const f32x4 z4 = {0.f, 0.f, 0.f, 0.f};
#pragma unroll
  for (int i = 0; i < 4; ++i)
#pragma unroll
    for (int j = 0; j < 4; ++j) acc[i][j] = z4;
  const int la = lane & 15, lk = (lane >> 4) * 8;
  const int sdst = srow * 40 + shalf * 16;
  for (int kt = 0; kt < K; kt += 32) {
    __syncthreads();
    *reinterpret_cast<uint4*>(&As[sdst])     = ra0;
    *reinterpret_cast<uint4*>(&As[sdst + 8]) = ra1;
    *reinterpret_cast<uint4*>(&Bs[sdst])     = rb0;
    *reinterpret_cast<uint4*>(&Bs[sdst + 8]) = rb1;
    __syncthreads();
    if (kt + 32 < K) {
      ra0 = *reinterpret_cast<const uint4*>(Ag + kt + 32);
      ra1 = *reinterpret_cast<const uint4*>(Ag + kt + 40);
      rb0 = *reinterpret_cast<const uint4*>(Bg + kt + 32);
      rb1 = *reinterpret_cast<const uint4*>(Bg + kt + 40);
    }
    short8v af[4], bfr[4];
#pragma unroll
    for (int i = 0; i < 4; ++i)
      af[i] = *reinterpret_cast<const short8v*>(&As[(wr + i * 16 + la) * 40 + lk]);
#pragma unroll
    for (int j = 0; j < 4; ++j)
      bfr[j] = *reinterpret_cast<const short8v*>(&Bs[(wc + j * 16 + la) * 40 + lk]);
#pragma unroll
    for (int i = 0; i < 4; ++i)
#pragma unroll
      for (int j = 0; j < 4; ++j)
        acc[i][j] = __builtin_amdgcn_mfma_f32_16x16x32_bf16(af[i], bfr[j], acc[i][j], 0, 0, 0);
  }
  const int r0 = by * 128 + wr + (lane >> 4) * 4;
  const int c0 = bx * 128 + wc + la;
#pragma unroll
  for (int i = 0; i < 4; ++i)
#pragma unroll
    for (int j = 0; j < 4; ++j) {
      int c = c0 + j * 16;
      float bv = bias[c];
#pragma unroll
      for (int q = 0; q < 4; ++q) {
        int r = r0 + i * 16 + q;
        float v = acc[i][j][q] + bv;
        if (epi == 1) v = (v > 0.0f) ? v : expm1f(v);
        Cbf[(size_t)r * N + c] = f2bf(v);
      }
    }
}

// ---------------------------------------------------------------------------
// Fused gate + pooling (per mailbox)
// ---------------------------------------------------------------------------
__global__ __launch_bounds__(256) void k_gate_pool(
    const ushort* __restrict__ o, const float* __restrict__ gw,
    ushort* __restrict__ ae, float* __restrict__ gsum) {
  __shared__ float os[8][1024];
  __shared__ float lg[8][4];
  __shared__ float gs[8][4];
  const int b = blockIdx.x, t = threadIdx.x;
  for (int u = t; u < 8192; u += 256) {
    int l = u >> 10, d = u & 1023;
    os[l][d] = bf2f(o[(size_t)(b * 8 + l) * 1024 + d]);
  }
  __syncthreads();
  {
    int p = t >> 3, sub = t & 7;
    int l = p >> 2, e = p & 3;
    float s = 0;
    for (int d = sub; d < 1024; d += 8) s += os[l][d] * gw[d * 4 + e];
    s += __shfl_down(s, 4, 8);
    s += __shfl_down(s, 2, 8);
    s += __shfl_down(s, 1, 8);
    if (sub == 0) lg[l][e] = s;
  }
  __syncthreads();
  if (t < 8) {
    float m = fmaxf(fmaxf(lg[t][0], lg[t][1]), fmaxf(lg[t][2], lg[t][3]));
    float e0 = expf(lg[t][0] - m), e1 = expf(lg[t][1] - m);
    float e2 = expf(lg[t][2] - m), e3 = expf(lg[t][3] - m);
    float inv = 1.0f / (e0 + e1 + e2 + e3);
    gs[t][0] = e0 * inv; gs[t][1] = e1 * inv;
    gs[t][2] = e2 * inv; gs[t][3] = e3 * inv;
  }
  __syncthreads();
  if (t < 4) {
    float g = 0;
#pragma unroll
    for (int l = 0; l < 8; ++l) g += gs[l][t];
    gsum[b * 4 + t] = g;
  }
#pragma unroll
  for (int rep = 0; rep < 4; ++rep) {
    int d = t + rep * 256;
    float a0 = 0, a1 = 0, a2 = 0, a3 = 0;
#pragma unroll
    for (int l = 0; l < 8; ++l) {
      float ov = os[l][d];
      a0 += gs[l][0] * ov; a1 += gs[l][1] * ov;
      a2 += gs[l][2] * ov; a3 += gs[l][3] * ov;
    }
    ae[(size_t)0 * 524288 + b * 1024 + d] = f2bf(a0);
    ae[(size_t)1 * 524288 + b * 1024 + d] = f2bf(a1);
    ae[(size_t)2 * 524288 + b * 1024 + d] = f2bf(a2);
    ae[(size_t)3 * 524288 + b * 1024 + d] = f2bf(a3);
  }
}

// ---------------------------------------------------------------------------
// Pooled MoE GEMM (experts folded into K-accumulation)
// ---------------------------------------------------------------------------
__global__ __launch_bounds__(256) void gemm_moe2(
    const ushort* __restrict__ AE, const ushort* __restrict__ Bt4,
    const float* __restrict__ expb, const float* __restrict__ gsum,
    float* __restrict__ out) {
  __shared__ ushort As[64 * 40];
  __shared__ ushort Bs[64 * 40];
  const int bx = blockIdx.x, by = blockIdx.y;
  const int t = threadIdx.x;
  const int wv = t >> 6, lane = t & 63;
  const int wr = (wv >> 1) * 32, wc = (wv & 1) * 32;
  const int srow = t >> 2, sq = t & 3;
  const int la = lane & 15, lk = (lane >> 4) * 8;
  const int sdst = srow * 40 + sq * 8;
  f32x4 acc[2][2];
  const f32x4 z4 = {0.f, 0.f, 0.f, 0.f};
  acc[0][0] = z4; acc[0][1] = z4; acc[1][0] = z4; acc[1][1] = z4;
  for (int e = 0; e < 4; ++e) {
    const ushort* Ag = AE + (size_t)e * 524288 + (size_t)(by * 64 + srow) * 1024 + sq * 8;
    const ushort* Bg = Bt4 + (size_t)e * 1048576 + (size_t)(bx * 64 + srow) * 1024 + sq * 8;
    uint4 ra = *reinterpret_cast<const uint4*>(Ag);
    uint4 rb = *reinterpret_cast<const uint4*>(Bg);
    for (int kt = 0; kt < 1024; kt += 32) {
      __syncthreads();
      *reinterpret_cast<uint4*>(&As[sdst]) = ra;
      *reinterpret_cast<uint4*>(&Bs[sdst]) = rb;
      __syncthreads();
      if (kt + 32 < 1024) {
        ra = *reinterpret_cast<const uint4*>(Ag + kt + 32);
        rb = *reinterpret_cast<const uint4*>(Bg + kt + 32);
      }
      short8v af[2], bfr[2];
#pragma unroll
      for (int i = 0; i < 2; ++i)
        af[i] = *reinterpret_cast<const short8v*>(&As[(wr + i * 16 + la) * 40 + lk]);
#pragma unroll
      for (int j = 0; j < 2; ++j)
        bfr[j] = *reinterpret_cast<const short8v*>(&Bs[(wc + j * 16 + la) * 40 + lk]);
#pragma unroll
      for (int i = 0; i < 2; ++i)
#pragma unroll
        for (int j = 0; j < 2; ++j)
          acc[i][j] = __builtin_amdgcn_mfma_f32_16x16x32_bf16(af[i], bfr[j], acc[i][j], 0, 0, 0);
    }
  }
  const int r0 = by * 64 + wr + (lane >> 4) * 4;
  const int c0 = bx * 64 + wc + la;
#pragma unroll
  for (int i = 0; i < 2; ++i)
#pragma unroll
    for (int q = 0; q < 4; ++q) {
      int r = r0 + i * 16 + q;
      float4 gv = *reinterpret_cast<const float4*>(gsum + r * 4);
#pragma unroll
      for (int j = 0; j < 2; ++j) {
        int c = c0 + j * 16;
        float bias = gv.x * expb[c] + gv.y * expb[1024 + c] +
                     gv.z * expb[2048 + c] + gv.w * expb[3072 + c];
        float s = (acc[i][j][q] + bias) * 0.125f;
        out[(size_t)r * 1024 + c] = 1.0f / (1.0f + expf(-s));
      }
    }
}

// ---------------------------------------------------------------------------
// Symmetric Gram contrastive kernel (2080 triangular tiles)
// ---------------------------------------------------------------------------
__global__ __launch_bounds__(256) void gram_sym(
    const ushort* __restrict__ W, float* __restrict__ rsum,
    float* __restrict__ d11, float* __restrict__ d12, float* __restrict__ d22) {
  __shared__ ushort As[128 * 40];
  __shared__ ushort Bs[128 * 40];
  int tt = blockIdx.x, bi = 0, cnt = 64;
  while (tt >= cnt) { tt -= cnt; ++bi; --cnt; }
  int bj = bi + tt;
  const bool diag = (bi == bj);
  const int t = threadIdx.x;
  const int wv = t >> 6, lane = t & 63;
  const int wr = (wv >> 1) * 64, wc = (wv & 1) * 64;
  const int srow = t >> 1, shalf = t & 1;
  const ushort* Ag = W + (size_t)(bi * 128 + srow) * 128 + shalf * 16;
  const ushort* Bg = W + (size_t)(bj * 128 + srow) * 128 + shalf * 16;
  uint4 ra0 = *reinterpret_cast<const uint4*>(Ag);
  uint4 ra1 = *reinterpret_cast<const uint4*>(Ag + 8);
  uint4 rb0 = *reinterpret_cast<const uint4*>(Bg);
  uint4 rb1 = *reinterpret_cast<const uint4*>(Bg + 8);
  f32x4 acc[4][4];
  const f32x4 z4 = {0.f, 0.f, 0.f, 0.f};
#pragma unroll
  for (int i = 0; i < 4; ++i)
#pragma unroll
    for (int j = 0; j < 4; ++j) acc[i][j] = z4;
  const int la = lane & 15, lk = (lane >> 4) * 8;
  const int sdst = srow * 40 + shalf * 16;
  for (int kt = 0; kt < 128; kt += 32) {
    __syncthreads();
    *reinterpret_cast<uint4*>(&As[sdst])     = ra0;
    *reinterpret_cast<uint4*>(&As[sdst + 8]) = ra1;
    *reinterpret_cast<uint4*>(&Bs[sdst])     = rb0;
    *reinterpret_cast<uint4*>(&Bs[sdst + 8]) = rb1;
    __syncthreads();
    if (kt + 32 < 128) {
      ra0 = *reinterpret_cast<const uint4*>(Ag + kt + 32);
      ra1 = *reinterpret_cast<const uint4*>(Ag + kt + 40);
      rb0 = *reinterpret_cast<const uint4*>(Bg + kt + 32);
      rb1 = *reinterpret_cast<const uint4*>(Bg + kt + 40);
    }
    short8v af[4], bfr[4];
#pragma unroll
    for (int i = 0; i < 4; ++i)
      af[i] = *reinterpret_cast<const short8v*>(&As[(wr + i * 16 + la) * 40 + lk]);
#pragma unroll
    for (int j = 0; j < 4; ++j)
      bfr[j] = *reinterpret_cast<const short8v*>(&Bs[(wc + j * 16 + la) * 40 + lk]);
#pragma unroll
    for (int i = 0; i < 4; ++i)
#pragma unroll
      for (int j = 0; j < 4; ++j)
        acc[i][j] = __builtin_amdgcn_mfma_f32_16x16x32_bf16(af[i], bfr[j], acc[i][j], 0, 0, 0);
  }
  const int r0 = bi * 128 + wr + (lane >> 4) * 4;
  const int c0 = bj * 128 + wc + la;
  constexpr float K2 = 2.8853900817779268f;   // 2 / ln(2)
  float rs[4][4];
  float cs[4] = {0.f, 0.f, 0.f, 0.f};
#pragma unroll
  for (int i = 0; i < 4; ++i)
#pragma unroll
    for (int q = 0; q < 4; ++q) rs[i][q] = 0.f;
#pragma unroll
  for (int i = 0; i < 4; ++i)
#pragma unroll
    for (int j = 0; j < 4; ++j)
#pragma unroll
      for (int q = 0; q < 4; ++q) {
        int r = r0 + i * 16 + q;
        int c = c0 + j * 16;
        float e = exp2f(K2 * acc[i][j][q]);
        rs[i][q] += e;
        cs[j] += e;
        if (c == r)        { if (r < 4096) d11[r] = e; else d22[r - 4096] = e; }
        if (c == r + 4096) d12[r] = e;
      }
#pragma unroll
  for (int m = 1; m < 16; m <<= 1)
#pragma unroll
    for (int i = 0; i < 4; ++i)
#pragma unroll
      for (int q = 0; q < 4; ++q) rs[i][q] += __shfl_xor(rs[i][q], m);
  float* rowdst = rsum + ((bj >= 32) ? 8192 : 0);
  if (la == 0) {
#pragma unroll
    for (int i = 0; i < 4; ++i)
#pragma unroll
      for (int q = 0; q < 4; ++q) atomAdd(&rowdst[r0 + i * 16 + q], rs[i][q]);
  }
  if (!diag) {
#pragma unroll
    for (int j = 0; j < 4; ++j) {
      cs[j] += __shfl_xor(cs[j], 16);
      cs[j] += __shfl_xor(cs[j], 32);
    }
    float* coldst = rsum + ((bi >= 32) ? 8192 : 0);
    if ((lane >> 4) == 0) {
#pragma unroll
      for (int j = 0; j < 4; ++j) atomAdd(&coldst[c0 + j * 16], cs[j]);
    }
  }
}

__global__ __launch_bounds__(256) void cl_row(
    const float* __restrict__ rsum, const float* __restrict__ d11,
    const float* __restrict__ d12, const float* __restrict__ d22,
    float* __restrict__ cl_sum) {
  __shared__ float sh[256];
  int i = blockIdx.x * 256 + threadIdx.x;
  float denA = rsum[i] + rsum[8192 + i] - d11[i];
  float denB = rsum[8192 + 4096 + i] + rsum[4096 + i] - d22[i];
  float l = 0.5f * (logf(denA) + logf(denB)) - logf(d12[i]);
  float s = blockReduce256(l, sh, threadIdx.x);
  if (threadIdx.x == 0) atomAdd(cl_sum, s);
}

// weight transpose + bf16 convert: Bt[n*K+k] = bf16(W[k*N+n])
__global__ __launch_bounds__(256) void k_wt_bt(const float* __restrict__ W,
                                               ushort* __restrict__ Bt, int K, int N) {
  __shared__ float tile[32][33];
  int n0 = blockIdx.x * 32, k0 = blockIdx.y * 32;
  int tx = threadIdx.x & 31, ty = threadIdx.x >> 5;
#pragma unroll
  for (int i = 0; i < 4; ++i)
    tile[ty + 8 * i][tx] = W[(size_t)(k0 + ty + 8 * i) * N + n0 + tx];
  __syncthreads();
#pragma unroll
  for (int i = 0; i < 4; ++i)
    Bt[(size_t)(n0 + ty + 8 * i) * K + k0 + tx] = f2bf(tile[tx][ty + 8 * i]);
}

// batched transpose: W strided by z (contiguous weights, e.g. experts)
__global__ __launch_bounds__(256) void k_wt_bt_s(const float* __restrict__ Wbase,
                                                 ushort* __restrict__ Btbase, int K, int N) {
  __shared__ float tile[32][33];
  const float* W = Wbase + (size_t)blockIdx.z * K * N;
  ushort* Bt = Btbase + (size_t)blockIdx.z * K * N;
  int n0 = blockIdx.x * 32, k0 = blockIdx.y * 32;
  int tx = threadIdx.x & 31, ty = threadIdx.x >> 5;
#pragma unroll
  for (int i = 0; i < 4; ++i)
    tile[ty + 8 * i][tx] = W[(size_t)(k0 + ty + 8 * i) * N + n0 + tx];
  __syncthreads();
#pragma unroll
  for (int i = 0; i < 4; ++i)
    Bt[(size_t)(n0 + ty + 8 * i) * K + k0 + tx] = f2bf(tile[tx][ty + 8 * i]);
}

// batched transpose for 3 separate weight pointers (QKV)
__global__ __launch_bounds__(256) void k_wt_bt3(const float* __restrict__ w0,
                                                const float* __restrict__ w1,
                                                const float* __restrict__ w2,
                                                ushort* __restrict__ Btbase, int K, int N) {
  __shared__ float tile[32][33];
  const float* W = (blockIdx.z == 0) ? w0 : (blockIdx.z == 1) ? w1 : w2;
  ushort* Bt = Btbase + (size_t)blockIdx.z * K * N;
  int n0 = blockIdx.x * 32, k0 = blockIdx.y * 32;
  int tx = threadIdx.x & 31, ty = threadIdx.x >> 5;
#pragma unroll
  for (int i = 0; i < 4; ++i)
    tile[ty + 8 * i][tx] = W[(size_t)(k0 + ty + 8 * i) * N + n0 + tx];
  __syncthreads();
#pragma unroll
  for (int i = 0; i < 4; ++i)
    Bt[(size_t)(n0 + ty + 8 * i) * K + k0 + tx] = f2bf(tile[tx][ty + 8 * i]);
}

// ---------------------------------------------------------------------------
// Fused S post-process: SB bf16 write + MSG build + emb_sum partial.
// 128 blocks x 256 threads, grid-stride over 1,048,576 elements; 128 atomics.
// ---------------------------------------------------------------------------
__global__ __launch_bounds__(256) void k_post_s(
    const float* __restrict__ s1, const float* __restrict__ s2,
    const float* __restrict__ relation, const int* __restrict__ etype,
    ushort* __restrict__ sb, ushort* __restrict__ msg, float* __restrict__ emb_out) {
  __shared__ float sh[256];
  float part = 0.f;
  for (int idx = blockIdx.x * 256 + threadIdx.x; idx < 1048576; idx += 128 * 256) {
    // SB mapping: [8192][128] = S1 then S2 flat
    float vs = (idx < 524288) ? s1[idx] : s2[idx - 524288];
    sb[idx] = f2bf(vs);
    // MSG mapping: [4096][256] = concat(S1_row, S2_row) + rel*sign, relu
    int i = idx >> 8, j = idx & 255;
    int et = etype[i];
    float sign = (et >= cNR) ? -1.0f : 1.0f;
    float r = relation[(size_t)(et % cNR) * 256 + j];
    float s = (j < 128) ? s1[(size_t)i * 128 + j] : s2[(size_t)i * 128 + j - 128];
    msg[idx] = f2bf(fmaxf(s + r * sign, 0.0f));
    part += s * s + r * r;
  }
  float tot = blockReduce256(part, sh, threadIdx.x);
  if (threadIdx.x == 0) atomAdd(emb_out, tot);
}

// in-place bf16 row normalize (wave reduction, 1 sync)
__global__ __launch_bounds__(128) void rownorm_bf2(ushort* __restrict__ w) {
  __shared__ float sh[2];
  int i = blockIdx.x, tid = threadIdx.x;
  float v = bf2f(w[(size_t)i * cD + tid]);
  float ss = v * v;
#pragma unroll
  for (int off = 32; off > 0; off >>= 1) ss += __shfl_xor(ss, off);
  if ((tid & 63) == 0) sh[tid >> 6] = ss;
  __syncthreads();
  float n = fmaxf(sqrtf(sh[0] + sh[1]), 1e-12f);
  w[(size_t)i * cD + tid] = f2bf(v / n);
}

// fused-QKV attention: qkv [4096][3072] (Q|K|V per row), o [4096][1024] bf16
__global__ __launch_bounds__(64) void mha_attn(
    const ushort* __restrict__ qkv, ushort* __restrict__ o) {
  __shared__ float qs[8][132], ks[8][132], vs[8][132];
  __shared__ float att[8][8];
  int bh = blockIdx.x;
  int b = bh >> 3, h = bh & 7;
  int tid = threadIdx.x;
  for (int u = tid; u < 256; u += 64) {
    int l = u >> 5;
    int d4 = (u & 31) * 4;
    size_t base = (size_t)(b * 8 + l) * 3072 + h * 128 + d4;
    ushort4 qv = *reinterpret_cast<const ushort4*>(qkv + base);
    ushort4 kv = *reinterpret_cast<const ushort4*>(qkv + base + 1024);
    ushort4 vv = *reinterpret_cast<const ushort4*>(qkv + base + 2048);
    qs[l][d4] = bf2f(qv.x); qs[l][d4 + 1] = bf2f(qv.y);
    qs[l][d4 + 2] = bf2f(qv.z); qs[l][d4 + 3] = bf2f(qv.w);
    ks[l][d4] = bf2f(kv.x); ks[l][d4 + 1] = bf2f(kv.y);
    ks[l][d4 + 2] = bf2f(kv.z); ks[l][d4 + 3] = bf2f(kv.w);
    vs[l][d4] = bf2f(vv.x); vs[l][d4 + 1] = bf2f(vv.y);
    vs[l][d4 + 2] = bf2f(vv.z); vs[l][d4 + 3] = bf2f(vv.w);
  }
  __syncthreads();
  int l = tid >> 3, m = tid & 7;
  const float4* qp = reinterpret_cast<const float4*>(&qs[l][0]);
  const float4* kp = reinterpret_cast<const float4*>(&ks[m][0]);
  float s = 0;
#pragma unroll
  for (int d4 = 0; d4 < 32; ++d4) {
    float4 a = qp[d4], bb = kp[d4];
    s += a.x * bb.x + a.y * bb.y + a.z * bb.z + a.w * bb.w;
  }
  s *= 0.08838834764831845f;
  float mx = s;
  for (int off = 1; off < 8; off <<= 1) mx = fmaxf(mx, __shfl_xor(mx, off, 8));
  float p = expf(s - mx);
  float sum = p;
  for (int off = 1; off < 8; off <<= 1) sum += __shfl_xor(sum, off, 8);
  att[l][m] = p / sum;
  __syncthreads();
  for (int u = tid; u < 1024; u += 64) {
    int ll = u >> 7, d = u & 127;
    float acc = 0;
#pragma unroll
    for (int mm = 0; mm < 8; ++mm) acc += att[ll][mm] * vs[mm][d];
    o[(size_t)(b * 8 + ll) * 1024 + h * 128 + d] = f2bf(acc);
  }
}

__global__ void finalize_k(const float* __restrict__ scal, float* __restrict__ out_aux) {
  float cl = scal[0] * (1.0f / cNSRC);
  float emb = cDECAY * 0.5f * scal[1] * (1.0f / cNSRC);
  out_aux[0] = cCLW * cl + emb;
}

// ---------------------------------------------------------------------------
// Launch
// ---------------------------------------------------------------------------
extern "C" void kernel_launch(void* const* d_in, const int* in_sizes, int n_in,
                              void* d_out, int out_size, void* d_ws, size_t ws_size,
                              hipStream_t stream) {
  (void)in_sizes; (void)n_in; (void)out_size; (void)ws_size;
  const float* entity   = (const float*)d_in[0];
  const float* type_e   = (const float*)d_in[1];
  const float* cluster  = (const float*)d_in[2];
  const float* relation = (const float*)d_in[3];
  const float* ln_g  = (const float*)d_in[4];
  const float* ln_b  = (const float*)d_in[5];
  const float* cl_w1 = (const float*)d_in[6];
  const float* cl_b1 = (const float*)d_in[7];
  const float* cl_w2 = (const float*)d_in[8];
  const float* cl_b2 = (const float*)d_in[9];
  const float* fc_w  = (const float*)d_in[10];
  const float* fc_b  = (const float*)d_in[11];
  const float* wq = (const float*)d_in[12];
  const float* bq = (const float*)d_in[13];
  const float* wk = (const float*)d_in[14];
  const float* bk = (const float*)d_in[15];
  const float* wv = (const float*)d_in[16];
  const float* bv = (const float*)d_in[17];
  const float* wo = (const float*)d_in[18];
  const float* bo = (const float*)d_in[19];
  const float* gate_w = (const float*)d_in[20];
  const float* exp_w  = (const float*)d_in[21];
  const float* exp_b  = (const float*)d_in[22];
  const float* e2t_val = (const float*)d_in[23];
  const float* t2c_val = (const float*)d_in[24];
  const float* e2c_val = (const float*)d_in[25];
  const int* e2t_row = (const int*)d_in[26];
  const int* e2t_col = (const int*)d_in[27];
  const int* t2c_row = (const int*)d_in[28];
  const int* t2c_col = (const int*)d_in[29];
  const int* e2c_row = (const int*)d_in[30];
  const int* e2c_col = (const int*)d_in[31];
  const int* src_ids = (const int*)d_in[32];
  const int* etype   = (const int*)d_in[33];

  float* ws = (float*)d_ws;
  float* S1 = ws + F_S1;
  float* S2 = ws + F_S2;
  ushort* Wbf = (ushort*)(ws + F_PT);
  ushort* P1bf = (ushort*)(ws + F_Z1);
  ushort* SBbf = (ushort*)(ws + F_Z2);
  ushort* MSGbf = (ushort*)(ws + F_MSG);
  float* GSUM = ws + F_GATE;
  float* SCAL = ws + F_SCAL;
  float* RS   = ws + F_RS;
  float* BQKV = ws + F_RS;
  float* D11  = ws + F_D11;
  float* D12  = ws + F_D12;
  float* D22  = ws + F_D22;
  ushort* X1F = (ushort*)(ws + G_X1F);
  ushort* X2C = (ushort*)(ws + G_X2C);
  int*   MARK = (int*)(ws + G_X2C);     // aliased: dead before X2C written
  int*   SLOT = (int*)(ws + G_SLOT);
  int*   REP  = (int*)(ws + G_REP);
  int*   RP   = (int*)(ws + G_RP);
  int*   FILL = (int*)(ws + G_FILL);
  int*   COLS = (int*)(ws + G_COLS);
  float* VALS = ws + G_VALS;
  ushort* X1T = (ushort*)(ws + G_X1T);
  ushort* X2T = (ushort*)(ws + G_X2T);
  int*   BSUM = (int*)(ws + G_BSUM);
  ushort* PB   = (ushort*)(ws + A_U0);
  ushort* AE   = (ushort*)(ws + A_U0);
  ushort* QKV  = (ushort*)(ws + A_U1);
  ushort* OB   = (ushort*)(ws + A_U1);
  ushort* WBT  = (ushort*)(ws + A_WBT);

  hipMemsetAsync(SCAL, 0, 2 * sizeof(float), stream);
  hipMemsetAsync(RS, 0, (16384 + 3 * 4096) * sizeof(float), stream);

  // masked GCN
  auto run_gcn_masked = [&](const int* row, const int* col, const float* val, int nnz, int nn,
                            const float* ea, const float* eb, int na, int mode,
                            float* dst) {
    int nb = (nn + 255) / 256;
    int gEdge = (nnz + 255) / 256;
    k_init3<<<nb, 256, 0, stream>>>(SLOT, MARK, FILL, nn);
    k_slot_mark<<<16, 256, 0, stream>>>(src_ids, SLOT, MARK, mode);
    k_mark_edges<<<gEdge, 256, 0, stream>>>(row, col, nnz, SLOT, MARK);
    k_hist<<<gEdge, 256, 0, stream>>>(row, nnz, MARK, FILL);
    k_scan_block<<<nb, 256, 0, stream>>>(FILL, nn, RP, BSUM);
    k_bsum_scan<<<1, 512, 0, stream>>>(BSUM, nb, RP, nn);
    k_scan_add<<<nb, 256, 0, stream>>>(RP, BSUM, nn, FILL);
    k_fill<<<gEdge, 256, 0, stream>>>(row, col, val, nnz, MARK, FILL, COLS, VALS);
    k_rep<<<16, 256, 0, stream>>>(src_ids, SLOT, mode, REP);
    k_gather<<<(nn + 3) / 4, 256, 0, stream>>>(RP, COLS, VALS, ea, eb, na, nn, MARK, X1F);
    k_gather_slot<<<cNSRC / 4, 256, 0, stream>>>(RP, COLS, VALS, X1F, REP, X2C);
    gather_ln<<<cNSRC, 128, 0, stream>>>(src_ids, mode, ea, eb, na, X1F, X2C, SLOT,
                                         ln_g, ln_b, dst);
  };

  run_gcn_masked(e2t_row, e2t_col, e2t_val, cNNZ_E2T, cNN_E2T, entity, type_e, cNE, 0, S1);
  run_gcn_masked(e2c_row, e2c_col, e2c_val, cNNZ_E2C, cNN_E2C, entity, cluster, cNE, 3, S2);

  // ---- t2c: tiny, both layers full ----
  {
    int nn = cNN_T2C, nb = (nn + 255) / 256, gEdge = (cNNZ_T2C + 255) / 256;
    hipMemsetAsync(FILL, 0, (size_t)nn * sizeof(int), stream);
    k_hist<<<gEdge, 256, 0, stream>>>(t2c_row, cNNZ_T2C, nullptr, FILL);
    k_scan_block<<<nb, 256, 0, stream>>>(FILL, nn, RP, BSUM);
    k_bsum_scan<<<1, 512, 0, stream>>>(BSUM, nb, RP, nn);
    k_scan_add<<<nb, 256, 0, stream>>>(RP, BSUM, nn, FILL);
    k_fill<<<gEdge, 256, 0, stream>>>(t2c_row, t2c_col, t2c_val, cNNZ_T2C, nullptr,
                                      FILL, COLS, VALS);
    k_gather<<<(nn + 3) / 4, 256, 0, stream>>>(RP, COLS, VALS, type_e, cluster, cNT,
                                               nn, nullptr, X1T);
    k_gather_bf<<<(nn + 3) / 4, 256, 0, stream>>>(RP, COLS, VALS, X1T, nn, X2T);
    gather_ln<<<cNSRC, 128, 0, stream>>>(src_ids, 1, type_e, cluster, cNT, X1T, X2T, nullptr,
                                         ln_g, ln_b, S1);
    gather_ln<<<cNSRC, 128, 0, stream>>>(src_ids, 2, type_e, cluster, cNT, X1T, X2T, nullptr,
                                         ln_g, ln_b, S2);
  }

  // ================= fused S post-process (SB + MSG + emb_sum) =================
  k_post_s<<<128, 256, 0, stream>>>(S1, S2, relation, etype, SBbf, MSGbf, SCAL + 1);

  // ================= contrastive loss =================
  ushort* W1T = WBT;
  ushort* W2T = WBT + 16384;
  k_wt_bt<<<dim3(4, 4), 256, 0, stream>>>(cl_w1, W1T, cD, cD);
  k_wt_bt<<<dim3(4, 4), 256, 0, stream>>>(cl_w2, W2T, cD, cD);
  gemm_bf<<<dim3(1, 64), 256, 0, stream>>>(SBbf, W1T, cD, cD, cl_b1, P1bf, 1);
  gemm_bf<<<dim3(1, 64), 256, 0, stream>>>(P1bf, W2T, cD, cD, cl_b2, Wbf, 0);
  rownorm_bf2<<<2 * cNSRC, 128, 0, stream>>>(Wbf);
  gram_sym<<<2080, 256, 0, stream>>>(Wbf, RS, D11, D12, D22);
  cl_row<<<16, 256, 0, stream>>>(RS, D11, D12, D22, SCAL);

  // ================= predict =================
  k_wt_bt<<<dim3(cT / 32, 256 / 32), 256, 0, stream>>>(fc_w, WBT, 256, cT);
  gemm_bf<<<dim3(cT / 128, cNSRC / 128), 256, 0, stream>>>(MSGbf, WBT, cT, 256, fc_b, PB, 0);

  // ================= MHA: fused QKV =================
  k_wt_bt3<<<dim3(32, 32, 3), 256, 0, stream>>>(wq, wk, wv, WBT, cT, cT);
  hipMemcpyAsync(BQKV,        bq, cT * sizeof(float), hipMemcpyDeviceToDevice, stream);
  hipMemcpyAsync(BQKV + 1024, bk, cT * sizeof(float), hipMemcpyDeviceToDevice, stream);
  hipMemcpyAsync(BQKV + 2048, bv, cT * sizeof(float), hipMemcpyDeviceToDevice, stream);
  gemm_bf<<<dim3(3072 / 128, cNSRC / 128), 256, 0, stream>>>(PB, WBT, 3072, cT, BQKV, QKV, 0);
  mha_attn<<<cB * 8, 64, 0, stream>>>(QKV, PB);                 // attn-out -> A_U0
  k_wt_bt<<<dim3(32, 32), 256, 0, stream>>>(wo, WBT, cT, cT);
  gemm_bf<<<dim3(cT / 128, cNSRC / 128), 256, 0, stream>>>(PB, WBT, cT, cT, bo, OB, 0);

  // ================= pooled MoE =================
  k_gate_pool<<<cB, 256, 0, stream>>>(OB, gate_w, AE, GSUM);
  k_wt_bt_s<<<dim3(32, 32, 4), 256, 0, stream>>>(exp_w, WBT, cT, cT);
  gemm_moe2<<<dim3(16, 8), 256, 0, stream>>>(AE, WBT, exp_b, GSUM, (float*)d_out);

  finalize_k<<<1, 1, 0, stream>>>(SCAL, (float*)d_out + (size_t)cB * cT);
}